// Round 7
// baseline (775.751 us; speedup 1.0000x reference)
//
#include <hip/hip_runtime.h>

// ---------------------------------------------------------------------------
// HierarchicalSparseLayer: top-2 MoE with block-sparse (64x64) masked weights
// B=8192 tokens, D=1024, H=4096, E=16 experts, K=2, + block-sparse cross proj.
// R7: A operands global->REG (no LDS, no DMA), two named reg sets ping-pong;
//     raw s_barrier + lgkmcnt(0) only (B LDS coherence) so global loads fly
//     across the barrier (T4); LDS = B double-buffer only; k_route 16 tok/blk.
// ---------------------------------------------------------------------------

#define NTOK 8192
#define DIM  1024
#define HID  4096
#define NEXP 16
#define BM   256
#define ROWS_CAP (NTOK*2 + NEXP*256)   // 20480

typedef __attribute__((ext_vector_type(4))) float fx4;
typedef __attribute__((ext_vector_type(4))) unsigned int ux4;
typedef __attribute__((ext_vector_type(2))) unsigned int ux2;
typedef __attribute__((ext_vector_type(8))) short s8v;
union V16 { ux4 u; s8v s; };

__device__ __forceinline__ unsigned int f2bf(float f) {
  unsigned int u = __float_as_uint(f);
  return (u + 0x7fffu + ((u >> 16) & 1u)) >> 16;   // RNE, inputs finite
}

__device__ __forceinline__ unsigned int cvt_pk(float lo, float hi) {
  unsigned int r;
  asm("v_cvt_pk_bf16_f32 %0, %1, %2" : "=v"(r) : "v"(lo), "v"(hi));
  return r;
}

// Raw barrier: drain LDS ops only; global loads stay in flight across it.
__device__ __forceinline__ void bar_lgkm() {
  __builtin_amdgcn_sched_barrier(0);
  asm volatile("s_waitcnt lgkmcnt(0)" ::: "memory");
  __builtin_amdgcn_s_barrier();
  __builtin_amdgcn_sched_barrier(0);
}

// Mask dtype detected at runtime: flag 0=u8, 1=i32, 2=f32
__device__ __forceinline__ bool mask_at(const void* m, int flag, size_t idx) {
  if (flag == 0) return ((const unsigned char*)m)[idx] != 0;
  if (flag == 1) return ((const int*)m)[idx] != 0;
  return ((const float*)m)[idx] != 0.0f;
}

__device__ __forceinline__ int flag_of(int ev) {
  return (ev & 2) ? 2 : ((ev & 1) ? 0 : 1);
}

// XCD-aware swizzle (grid % 8 == 0)
__device__ __forceinline__ int xcd_swz() {
  const int b = blockIdx.x, cpx = gridDim.x >> 3;
  return (b & 7) * cpx + (b >> 3);
}

// --------------------------- mask dtype detection ---------------------------
__global__ void k_detect(const unsigned int* __restrict__ m, int* __restrict__ meta) {
  int bits = 0;
  size_t base = (size_t)blockIdx.x * 4096 + threadIdx.x;
  for (int j = 0; j < 16; j++) {
    unsigned int v = m[base + 256 * j];
    if (v == 0x3f800000u) bits |= 2;
    else if (v > 1u)      bits |= 1;
  }
  if (bits) atomicOr(&meta[1], bits);
}

// --------------------------- routing ---------------------------------------
// meta: [1]=detect bits [8..23]=counts [32..47]=offsets [48]=total
//       [64..79]=slot counters [96..175]=expert_of_rt
__global__ void k_route(const float* __restrict__ x,
                        const float* __restrict__ gw,    // gate_w[-1] [16,1024]
                        const float* __restrict__ temp,
                        int* __restrict__ top2i, float* __restrict__ top2w,
                        int* __restrict__ meta)
{
  __shared__ float gwsh[NEXP * DIM];
  for (int i = threadIdx.x; i < NEXP * DIM; i += 256) gwsh[i] = gw[i];
  __syncthreads();

  const int wv = threadIdx.x >> 6;
  const int l = threadIdx.x & 63;
  #pragma unroll
  for (int tt = 0; tt < 4; tt++) {
    const int t = blockIdx.x * 16 + wv * 4 + tt;
    const float* xr = x + (size_t)t * DIM;
    float xv[16];
    #pragma unroll
    for (int j = 0; j < 16; j++) xv[j] = xr[l + 64 * j];
    float logit[16];
    #pragma unroll
    for (int e = 0; e < 16; e++) {
      const float* g = gwsh + e * DIM;
      float s = 0.f;
      #pragma unroll
      for (int j = 0; j < 16; j++) s += xv[j] * g[l + 64 * j];
      #pragma unroll
      for (int o = 32; o >= 1; o >>= 1) s += __shfl_xor(s, o);
      logit[e] = s;
    }
    if (l == 0) {
      const float tinv = 1.0f / temp[0];
      int i0 = 0; float v0 = logit[0] * tinv;
      #pragma unroll
      for (int e = 1; e < 16; e++) { float v = logit[e] * tinv; if (v > v0) { v0 = v; i0 = e; } }
      int i1 = -1; float v1 = 0.f; bool first = true;
      #pragma unroll
      for (int e = 0; e < 16; e++) {
        if (e == i0) continue;
        float v = logit[e] * tinv;
        if (first || v > v1) { v1 = v; i1 = e; first = false; }
      }
      float ex = expf(v1 - v0);
      float den = 1.0f + ex;
      top2i[2 * t] = i0; top2i[2 * t + 1] = i1;
      top2w[2 * t] = 1.0f / den; top2w[2 * t + 1] = ex / den;
      atomicAdd(&meta[8 + i0], 1);
      atomicAdd(&meta[8 + i1], 1);
    }
  }
}

__global__ void k_offsets(int* __restrict__ meta) {
  if (threadIdx.x == 0 && blockIdx.x == 0) {
    int o = 0;
    for (int e = 0; e < 16; e++) { meta[32 + e] = o; o += (meta[8 + e] + 255) & ~255; }
    meta[48] = o;
    for (int rt = 0; rt < ROWS_CAP / BM; rt++) {
      const int base = rt * BM;
      int e = 0;
      for (int i = 1; i < 16; i++) if (meta[32 + i] <= base) e = i;
      meta[96 + rt] = e;
    }
  }
}

__global__ void k_assign(const int* __restrict__ top2i,
                         const float* __restrict__ top2w,
                         int* __restrict__ meta, int* __restrict__ tok_of_row,
                         int* __restrict__ t2row)
{
  int t = blockIdx.x * 256 + threadIdx.x;
  if (t >= NTOK) return;
  #pragma unroll
  for (int k = 0; k < 2; k++) {
    int e = top2i[2 * t + k];
    int slot = atomicAdd(&meta[64 + e], 1);
    int row = meta[32 + e] + slot;
    tok_of_row[row] = t;
    t2row[2 * t + k] = row;
  }
}

// --------------------------- block-mask bitmaps ------------------------------
__global__ void k_bmask(const void* __restrict__ m1, const void* __restrict__ m2,
                        const void* __restrict__ mc, const int* __restrict__ meta,
                        unsigned int* __restrict__ bm1,
                        unsigned long long* __restrict__ bm2,
                        unsigned int* __restrict__ bmc)
{
  const int flag = flag_of(meta[1]);
  const int id = blockIdx.x * 256 + threadIdx.x;
  if (id < 1024) {
    int e = id >> 6, ct = id & 63;
    unsigned int bits = 0;
    size_t basei = (size_t)e * DIM * HID + (size_t)ct * 64;
    for (int db = 0; db < 16; db++)
      if (mask_at(m1, flag, basei + (size_t)db * 64 * HID)) bits |= 1u << db;
    bm1[id] = bits;
  }
  if (id < 256) {
    int e = id >> 4, ct = id & 15;
    unsigned long long bits = 0;
    size_t basei = (size_t)e * HID * DIM + (size_t)ct * 64;
    for (int db = 0; db < 64; db++)
      if (mask_at(m2, flag, basei + (size_t)db * 64 * DIM)) bits |= 1ull << db;
    bm2[id] = bits;
  }
  if (id < 16) {
    unsigned int bits = 0;
    for (int db = 0; db < 16; db++)
      if (mask_at(mc, flag, (size_t)db * 64 * DIM + (size_t)id * 64)) bits |= 1u << db;
    bmc[id] = bits;
  }
}

__global__ void k_xcast(const float* __restrict__ x, unsigned short* __restrict__ xb) {
  int i = blockIdx.x * 256 + threadIdx.x;
  const fx4* s = (const fx4*)x + (size_t)i * 2;
  fx4 a = s[0], b = s[1];
  ux4 o;
  o[0] = cvt_pk(a[0], a[1]);
  o[1] = cvt_pk(a[2], a[3]);
  o[2] = cvt_pk(b[0], b[1]);
  o[3] = cvt_pk(b[2], b[3]);
  ((ux4*)xb)[i] = o;
}

// --------------------------- GEMM 1: h = silu(x @ w1m + b1) -----------------
// A: global->reg per-lane (gathered rows), ping-pong a0/a1. B: f32 reg-staged
// issue-early/write-late into LDS dbuf. Raw lgkm-only barrier per iter.
__global__ __launch_bounds__(256, 2)
void k_gemm1(const unsigned short* __restrict__ xb,
             const float* __restrict__ w1, const float* __restrict__ b1,
             const unsigned int* __restrict__ bm1,
             const int* __restrict__ meta, const int* __restrict__ tok_of_row,
             unsigned short* __restrict__ h_c)
{
  __shared__ __align__(16) ux2 Bsh[2][1024];    // 2 x 8 KB
  __shared__ ux4 hs4[2048];                     // 32 KB epilogue tile

  const int bid = xcd_swz();
  const int rt = bid >> 6, ct = bid & 63;       // NCT = 64
  const int base = rt * BM;
  if (base >= meta[48]) return;
  const int e = meta[96 + rt];

  const int tid = threadIdx.x;
  const int wv = tid >> 6;
  const int jg0 = ct * 64;
  unsigned int bits = bm1[e * 64 + ct];

  const int l = tid & 63, l16 = l & 15, lhi = l >> 4;
  const int kb = tid >> 4, jb = tid & 15;

  // per-lane A row base pointers (gathered via tok_of_row; pads clamp to 0)
  const char* aptr[4];
  #pragma unroll
  for (int m = 0; m < 4; m++) {
    int tk = tok_of_row[base + wv * 64 + m * 16 + l16];
    if (tk < 0) tk = 0;
    aptr[m] = (const char*)xb + (size_t)tk * (DIM * 2);
  }

  fx4 acc[4][4] = {};
  s8v a0[4][2], a1[4][2];
  fx4 br[4];

  auto LOAD_A0 = [&](int d0) {
    #pragma unroll
    for (int m = 0; m < 4; m++)
      #pragma unroll
      for (int ks = 0; ks < 2; ks++)
        a0[m][ks] = *(const s8v*)(aptr[m] + d0 * 2 + (ks * 4 + lhi) * 16);
  };
  auto LOAD_A1 = [&](int d0) {
    #pragma unroll
    for (int m = 0; m < 4; m++)
      #pragma unroll
      for (int ks = 0; ks < 2; ks++)
        a1[m][ks] = *(const s8v*)(aptr[m] + d0 * 2 + (ks * 4 + lhi) * 16);
  };
  auto LOAD_B = [&](int d0) {
    const float* bp = w1 + ((size_t)e * DIM + d0 + kb * 4) * HID + jg0 + jb * 4;
    br[0] = *(const fx4*)bp;
    br[1] = *(const fx4*)(bp + HID);
    br[2] = *(const fx4*)(bp + 2 * HID);
    br[3] = *(const fx4*)(bp + 3 * HID);
  };
  auto WRITE_B = [&](int b) {
    #pragma unroll
    for (int jj = 0; jj < 4; jj++) {
      ux2 val;
      val[0] = cvt_pk(br[0][jj], br[1][jj]);
      val[1] = cvt_pk(br[2][jj], br[3][jj]);
      const int col = jb * 4 + jj;
      Bsh[b][(col * 8 + ((kb >> 1) ^ (col & 7))) * 2 + (kb & 1)] = val;
    }
  };
  auto COMPUTE0 = [&](int b) {
    #pragma unroll
    for (int ks = 0; ks < 2; ks++) {
      s8v bb[4];
      const int seg = ks * 4 + lhi;
      #pragma unroll
      for (int n = 0; n < 4; n++) {
        const int col = n * 16 + l16;
        V16 v; v.u = ((const ux4*)&Bsh[b][0])[col * 8 + (seg ^ (col & 7))]; bb[n] = v.s;
      }
      #pragma unroll
      for (int m = 0; m < 4; m++)
        #pragma unroll
        for (int n = 0; n < 4; n++)
          acc[m][n] = __builtin_amdgcn_mfma_f32_16x16x32_bf16(a0[m][ks], bb[n], acc[m][n], 0, 0, 0);
    }
  };
  auto COMPUTE1 = [&](int b) {
    #pragma unroll
    for (int ks = 0; ks < 2; ks++) {
      s8v bb[4];
      const int seg = ks * 4 + lhi;
      #pragma unroll
      for (int n = 0; n < 4; n++) {
        const int col = n * 16 + l16;
        V16 v; v.u = ((const ux4*)&Bsh[b][0])[col * 8 + (seg ^ (col & 7))]; bb[n] = v.s;
      }
      #pragma unroll
      for (int m = 0; m < 4; m++)
        #pragma unroll
        for (int n = 0; n < 4; n++)
          acc[m][n] = __builtin_amdgcn_mfma_f32_16x16x32_bf16(a1[m][ks], bb[n], acc[m][n], 0, 0, 0);
    }
  };

  if (bits) {
    int d0 = (__ffs(bits) - 1) << 6; bits &= bits - 1;
    LOAD_A0(d0); LOAD_B(d0); WRITE_B(0);
    bar_lgkm();
    int cur = 0; bool useA0 = true;
    for (;;) {
      int nd0 = -1;
      if (bits) { nd0 = (__ffs(bits) - 1) << 6; bits &= bits - 1; }
      if (useA0) {
        if (nd0 >= 0) { LOAD_A1(nd0); LOAD_B(nd0); }
        COMPUTE0(cur);
      } else {
        if (nd0 >= 0) { LOAD_A0(nd0); LOAD_B(nd0); }
        COMPUTE1(cur);
      }
      if (nd0 >= 0) WRITE_B(cur ^ 1);
      bar_lgkm();
      cur ^= 1; useA0 = !useA0;
      if (nd0 < 0) break;
    }
  }

  // epilogue: silu(acc + b1) -> LDS bf16 tile -> coalesced 16B dump
  unsigned short* hs = (unsigned short*)hs4;
  #pragma unroll
  for (int m = 0; m < 4; m++)
    #pragma unroll
    for (int n = 0; n < 4; n++) {
      const int gcol = jg0 + n * 16 + l16;
      const float bbv = b1[e * HID + gcol];
      #pragma unroll
      for (int i = 0; i < 4; i++) {
        const int row = wv * 64 + m * 16 + lhi * 4 + i;
        float v = acc[m][n][i] + bbv;
        float hval = v / (1.0f + expf(-v));
        hs[row * 64 + n * 16 + l16] = (unsigned short)f2bf(hval);
      }
    }
  bar_lgkm();
  {
    const ux4* s = (const ux4*)hs;
    #pragma unroll
    for (int j = 0; j < 8; j++) {
      const int c2 = j * 256 + tid;
      const int row = c2 >> 3;
      *(ux4*)(h_c + (size_t)(base + row) * HID + ct * 64 + (c2 & 7) * 8) = s[c2];
    }
  }
}

// --------------------------- GEMM 2: y = h @ w2m + b2 (pair rows) -----------
__global__ __launch_bounds__(256, 2)
void k_gemm2(const unsigned short* __restrict__ h_c,
             const float* __restrict__ w2, const float* __restrict__ b2,
             const unsigned long long* __restrict__ bm2,
             const int* __restrict__ meta, float* __restrict__ y)
{
  __shared__ __align__(16) ux2 Bsh[2][1024];    // 2 x 8 KB only

  const int bid = xcd_swz();
  const int rt = bid >> 4, ct = bid & 15;       // NCT = 16
  const int base = rt * BM;
  if (base >= meta[48]) return;
  const int e = meta[96 + rt];

  const int tid = threadIdx.x;
  const int wv = tid >> 6;
  const int jg0 = ct * 64;
  unsigned long long bits = bm2[e * 16 + ct];

  const int l = tid & 63, l16 = l & 15, lhi = l >> 4;
  const int kb = tid >> 4, jb = tid & 15;

  const char* aptr[4];
  #pragma unroll
  for (int m = 0; m < 4; m++)
    aptr[m] = (const char*)h_c + (size_t)(base + wv * 64 + m * 16 + l16) * (HID * 2);

  fx4 acc[4][4] = {};
  s8v a0[4][2], a1[4][2];
  fx4 br[4];

  auto LOAD_A0 = [&](int d0) {
    #pragma unroll
    for (int m = 0; m < 4; m++)
      #pragma unroll
      for (int ks = 0; ks < 2; ks++)
        a0[m][ks] = *(const s8v*)(aptr[m] + d0 * 2 + (ks * 4 + lhi) * 16);
  };
  auto LOAD_A1 = [&](int d0) {
    #pragma unroll
    for (int m = 0; m < 4; m++)
      #pragma unroll
      for (int ks = 0; ks < 2; ks++)
        a1[m][ks] = *(const s8v*)(aptr[m] + d0 * 2 + (ks * 4 + lhi) * 16);
  };
  auto LOAD_B = [&](int d0) {
    const float* bp = w2 + ((size_t)e * HID + d0 + kb * 4) * DIM + jg0 + jb * 4;
    br[0] = *(const fx4*)bp;
    br[1] = *(const fx4*)(bp + DIM);
    br[2] = *(const fx4*)(bp + 2 * DIM);
    br[3] = *(const fx4*)(bp + 3 * DIM);
  };
  auto WRITE_B = [&](int b) {
    #pragma unroll
    for (int jj = 0; jj < 4; jj++) {
      ux2 val;
      val[0] = cvt_pk(br[0][jj], br[1][jj]);
      val[1] = cvt_pk(br[2][jj], br[3][jj]);
      const int col = jb * 4 + jj;
      Bsh[b][(col * 8 + ((kb >> 1) ^ (col & 7))) * 2 + (kb & 1)] = val;
    }
  };
  auto COMPUTE0 = [&](int b) {
    #pragma unroll
    for (int ks = 0; ks < 2; ks++) {
      s8v bb[4];
      const int seg = ks * 4 + lhi;
      #pragma unroll
      for (int n = 0; n < 4; n++) {
        const int col = n * 16 + l16;
        V16 v; v.u = ((const ux4*)&Bsh[b][0])[col * 8 + (seg ^ (col & 7))]; bb[n] = v.s;
      }
      #pragma unroll
      for (int m = 0; m < 4; m++)
        #pragma unroll
        for (int n = 0; n < 4; n++)
          acc[m][n] = __builtin_amdgcn_mfma_f32_16x16x32_bf16(a0[m][ks], bb[n], acc[m][n], 0, 0, 0);
    }
  };
  auto COMPUTE1 = [&](int b) {
    #pragma unroll
    for (int ks = 0; ks < 2; ks++) {
      s8v bb[4];
      const int seg = ks * 4 + lhi;
      #pragma unroll
      for (int n = 0; n < 4; n++) {
        const int col = n * 16 + l16;
        V16 v; v.u = ((const ux4*)&Bsh[b][0])[col * 8 + (seg ^ (col & 7))]; bb[n] = v.s;
      }
      #pragma unroll
      for (int m = 0; m < 4; m++)
        #pragma unroll
        for (int n = 0; n < 4; n++)
          acc[m][n] = __builtin_amdgcn_mfma_f32_16x16x32_bf16(a1[m][ks], bb[n], acc[m][n], 0, 0, 0);
    }
  };

  if (bits) {
    int d0 = (__ffsll(bits) - 1) << 6; bits &= bits - 1;
    LOAD_A0(d0); LOAD_B(d0); WRITE_B(0);
    bar_lgkm();
    int cur = 0; bool useA0 = true;
    for (;;) {
      int nd0 = -1;
      if (bits) { nd0 = (__ffsll(bits) - 1) << 6; bits &= bits - 1; }
      if (useA0) {
        if (nd0 >= 0) { LOAD_A1(nd0); LOAD_B(nd0); }
        COMPUTE0(cur);
      } else {
        if (nd0 >= 0) { LOAD_A0(nd0); LOAD_B(nd0); }
        COMPUTE1(cur);
      }
      if (nd0 >= 0) WRITE_B(cur ^ 1);
      bar_lgkm();
      cur ^= 1; useA0 = !useA0;
      if (nd0 < 0) break;
    }
  }

  // epilogue: y = acc + b2
  #pragma unroll
  for (int m = 0; m < 4; m++)
    #pragma unroll
    for (int n = 0; n < 4; n++) {
      const int gcol = jg0 + n * 16 + l16;
      const float bbv = b2[e * DIM + gcol];
      #pragma unroll
      for (int i = 0; i < 4; i++) {
        const int lrow = wv * 64 + m * 16 + lhi * 4 + i;
        y[(size_t)(base + lrow) * DIM + gcol] = acc[m][n][i] + bbv;
      }
    }
}

// --------------------------- cross: out = x + eo @ cwm + cb -----------------
// eo rows formed on the fly: eo[tok] = w0*y[r0] + w1*y[r1]
__global__ __launch_bounds__(256, 2)
void k_cross(const float* __restrict__ y, const float* __restrict__ x,
             const float* __restrict__ cw, const float* __restrict__ cb,
             const unsigned int* __restrict__ bmc,
             const int* __restrict__ t2row, const float* __restrict__ t2w,
             float* __restrict__ out)
{
  __shared__ ux4 Ash[2048];
  __shared__ __align__(16) ux2 Bsh[1024];

  const int bid = xcd_swz();
  const int rt = bid >> 4, ct = bid & 15;
  const int base = rt * BM;
  const int tid = threadIdx.x;
  const int jg0 = ct * 64;

  const int tok = base + tid;
  const int r0 = t2row[2 * tok], r1 = t2row[2 * tok + 1];
  const float w0 = t2w[2 * tok], w1 = t2w[2 * tok + 1];

  fx4 acc[4][4] = {};
  const int wave = tid >> 6, l = tid & 63;
  const int l16 = l & 15, lhi = l >> 4;

  unsigned int bits = bmc[ct];
  while (bits) {
    const int kbx = __ffs(bits) - 1; bits &= bits - 1;
    const int d0 = kbx * 64;
    {   // stage A: combine two pair rows -> bf16 (swizzled ds_write)
      const fx4* s0 = (const fx4*)(y + (size_t)r0 * DIM + d0);
      const fx4* s1 = (const fx4*)(y + (size_t)r1 * DIM + d0);
      #pragma unroll
      for (int seg = 0; seg < 8; seg++) {
        fx4 p = w0 * s0[seg * 2]     + w1 * s1[seg * 2];
        fx4 q = w0 * s0[seg * 2 + 1] + w1 * s1[seg * 2 + 1];
        ux4 v;
        v[0] = cvt_pk(p[0], p[1]);
        v[1] = cvt_pk(p[2], p[3]);
        v[2] = cvt_pk(q[0], q[1]);
        v[3] = cvt_pk(q[2], q[3]);
        Ash[tid * 8 + (seg ^ (tid & 7))] = v;
      }
    }
    {   // stage B from cross_w (f32 reg-staged)
      const int kbt = tid >> 4, jb = tid & 15;
      const float* bp = cw + (size_t)(d0 + kbt * 4) * DIM + jg0 + jb * 4;
      fx4 r0v = *(const fx4*)bp;
      fx4 r1v = *(const fx4*)(bp + DIM);
      fx4 r2v = *(const fx4*)(bp + 2 * DIM);
      fx4 r3v = *(const fx4*)(bp + 3 * DIM);
      #pragma unroll
      for (int jj = 0; jj < 4; jj++) {
        ux2 val;
        val[0] = cvt_pk(r0v[jj], r1v[jj]);
        val[1] = cvt_pk(r2v[jj], r3v[jj]);
        const int col = jb * 4 + jj;
        Bsh[(col * 8 + ((kbt >> 1) ^ (col & 7))) * 2 + (kbt & 1)] = val;
      }
    }
    __syncthreads();
    #pragma unroll
    for (int ks = 0; ks < 2; ks++) {
      s8v a[4], b[4];
      const int seg = ks * 4 + lhi;
      #pragma unroll
      for (int m = 0; m < 4; m++) {
        const int row = wave * 64 + m * 16 + l16;
        V16 v; v.u = Ash[row * 8 + (seg ^ (row & 7))]; a[m] = v.s;
      }
      #pragma unroll
      for (int n = 0; n < 4; n++) {
        const int col = n * 16 + l16;
        V16 v; v.u = ((const ux4*)Bsh)[col * 8 + (seg ^ (col & 7))]; b[n] = v.s;
      }
      #pragma unroll
      for (int m = 0; m < 4; m++)
        #pragma unroll
        for (int n = 0; n < 4; n++)
          acc[m][n] = __builtin_amdgcn_mfma_f32_16x16x32_bf16(a[m], b[n], acc[m][n], 0, 0, 0);
    }
    __syncthreads();
  }

  #pragma unroll
  for (int m = 0; m < 4; m++)
    #pragma unroll
    for (int n = 0; n < 4; n++) {
      const int gcol = jg0 + n * 16 + l16;
      #pragma unroll
      for (int i = 0; i < 4; i++) {
        const int lrow = wave * 64 + m * 16 + lhi * 4 + i;
        const size_t idx = (size_t)(base + lrow) * DIM + gcol;
        out[idx] = acc[m][n][i] + x[idx] + cb[gcol];
      }
    }
}

// ---------------------------------------------------------------------------
extern "C" void kernel_launch(void* const* d_in, const int* in_sizes, int n_in,
                              void* d_out, int out_size, void* d_ws, size_t ws_size,
                              hipStream_t stream)
{
  (void)in_sizes; (void)n_in; (void)out_size; (void)ws_size;
  const float* x      = (const float*)d_in[0];
  const float* gate_w = (const float*)d_in[1];   // [2,16,1024]
  const float* temp   = (const float*)d_in[2];   // [2]
  const float* w1     = (const float*)d_in[3];   // [16,1024,4096]
  const float* b1     = (const float*)d_in[4];
  const float* w2     = (const float*)d_in[5];   // [16,4096,1024]
  const float* b2     = (const float*)d_in[6];
  const float* cw     = (const float*)d_in[7];   // [1024,1024]
  const float* cb     = (const float*)d_in[8];
  const void*  mask1  = d_in[9];
  const void*  mask2  = d_in[10];
  const void*  cmask  = d_in[11];
  float* out = (float*)d_out;
  char* ws = (char*)d_ws;

  size_t off = 0;
  auto walloc = [&](size_t b) { size_t r = off; off = (off + b + 255) & ~(size_t)255; return r; };
  size_t o_meta = walloc(4096);
  size_t o_bm1  = walloc(1024 * 4);
  size_t o_bm2  = walloc(256 * 8);
  size_t o_bmc  = walloc(64 * 4);
  size_t o_t2i  = walloc((size_t)NTOK * 2 * 4);
  size_t o_t2w  = walloc((size_t)NTOK * 2 * 4);
  size_t o_t2r  = walloc((size_t)NTOK * 2 * 4);
  size_t o_tok  = walloc((size_t)ROWS_CAP * 4);
  size_t o_xbf  = walloc((size_t)NTOK * DIM * 2);
  size_t o_y    = walloc((size_t)ROWS_CAP * DIM * 4);    // 80 MB
  size_t o_hc   = walloc((size_t)ROWS_CAP * HID * 2);    // 168 MB

  int*                meta = (int*)(ws + o_meta);
  unsigned int*       bm1  = (unsigned int*)(ws + o_bm1);
  unsigned long long* bm2  = (unsigned long long*)(ws + o_bm2);
  unsigned int*       bmc  = (unsigned int*)(ws + o_bmc);
  int*                t2i  = (int*)(ws + o_t2i);
  float*              t2w  = (float*)(ws + o_t2w);
  int*                t2r  = (int*)(ws + o_t2r);
  int*                tok  = (int*)(ws + o_tok);
  unsigned short*     xbf  = (unsigned short*)(ws + o_xbf);
  float*              y    = (float*)(ws + o_y);
  unsigned short*     hc   = (unsigned short*)(ws + o_hc);

  hipMemsetAsync(ws + o_meta, 0, 4096, stream);
  hipMemsetAsync(ws + o_tok, 0xFF, (size_t)ROWS_CAP * 4, stream);  // -1

  k_detect <<<64, 256, 0, stream>>>((const unsigned int*)mask1, meta);
  k_bmask  <<<4, 256, 0, stream>>>(mask1, mask2, cmask, meta, bm1, bm2, bmc);
  k_route  <<<NTOK / 16, 256, 0, stream>>>(x, gate_w + (size_t)1 * NEXP * DIM, temp + 1, t2i, t2w, meta);
  k_offsets<<<1, 64, 0, stream>>>(meta);
  k_assign <<<NTOK / 256, 256, 0, stream>>>(t2i, t2w, meta, tok, t2r);
  k_xcast  <<<(NTOK * DIM / 8) / 256, 256, 0, stream>>>(x, xbf);

  const int NRT = ROWS_CAP / BM;   // 80
  k_gemm1<<<NRT * 64, 256, 0, stream>>>(xbf, w1, b1, bm1, meta, tok, hc);
  k_gemm2<<<NRT * 16, 256, 0, stream>>>(hc, w2, b2, bm2, meta, y);
  k_cross<<<(NTOK / BM) * 16, 256, 0, stream>>>(y, x, cw, cb, bmc, t2r, t2w, out);
}

// Round 8
// 506.921 us; speedup vs baseline: 1.5303x; 1.5303x over previous
//
#include <hip/hip_runtime.h>

// ---------------------------------------------------------------------------
// HierarchicalSparseLayer: top-2 MoE with block-sparse (64x64) masked weights
// B=8192 tokens, D=1024, H=4096, E=16 experts, K=2, + block-sparse cross proj.
// R8: R6 core (best: BM=256/BN=64, A via global_load_lds dbuf contiguous
//     staging, B reg-staged f32 issue-early/write-late, XCD swizzle) +
//     gemm2 ct-loop (4 column tiles per block, temporal L2 reuse of h panel)
//     + y stored bf16 (LDS-restaged coalesced epilogue; cross reads bf16).
// ---------------------------------------------------------------------------

#define NTOK 8192
#define DIM  1024
#define HID  4096
#define NEXP 16
#define BM   256
#define ROWS_CAP (NTOK*2 + NEXP*256)   // 20480

typedef __attribute__((ext_vector_type(4))) float fx4;
typedef __attribute__((ext_vector_type(4))) unsigned int ux4;
typedef __attribute__((ext_vector_type(2))) unsigned int ux2;
typedef __attribute__((ext_vector_type(8))) short s8v;
union V16 { ux4 u; s8v s; };

__device__ __forceinline__ unsigned int f2bf(float f) {
  unsigned int u = __float_as_uint(f);
  return (u + 0x7fffu + ((u >> 16) & 1u)) >> 16;   // RNE, inputs finite
}

__device__ __forceinline__ unsigned int cvt_pk(float lo, float hi) {
  unsigned int r;
  asm("v_cvt_pk_bf16_f32 %0, %1, %2" : "=v"(r) : "v"(lo), "v"(hi));
  return r;
}

// Mask dtype detected at runtime: flag 0=u8, 1=i32, 2=f32
__device__ __forceinline__ bool mask_at(const void* m, int flag, size_t idx) {
  if (flag == 0) return ((const unsigned char*)m)[idx] != 0;
  if (flag == 1) return ((const int*)m)[idx] != 0;
  return ((const float*)m)[idx] != 0.0f;
}

__device__ __forceinline__ int flag_of(int ev) {
  return (ev & 2) ? 2 : ((ev & 1) ? 0 : 1);
}

// XCD-aware swizzle (grid % 8 == 0)
__device__ __forceinline__ int xcd_swz() {
  const int b = blockIdx.x, cpx = gridDim.x >> 3;
  return (b & 7) * cpx + (b >> 3);
}

// --------------------------- mask dtype detection ---------------------------
__global__ void k_detect(const unsigned int* __restrict__ m, int* __restrict__ meta) {
  int bits = 0;
  size_t base = (size_t)blockIdx.x * 4096 + threadIdx.x;
  for (int j = 0; j < 16; j++) {
    unsigned int v = m[base + 256 * j];
    if (v == 0x3f800000u) bits |= 2;
    else if (v > 1u)      bits |= 1;
  }
  if (bits) atomicOr(&meta[1], bits);
}

// --------------------------- routing ---------------------------------------
// meta: [1]=detect bits [8..23]=counts [32..47]=offsets [48]=total
//       [64..79]=slot counters [96..175]=expert_of_rt
__global__ void k_route(const float* __restrict__ x,
                        const float* __restrict__ gw,    // gate_w[-1] [16,1024]
                        const float* __restrict__ temp,
                        int* __restrict__ top2i, float* __restrict__ top2w,
                        int* __restrict__ meta)
{
  __shared__ float gwsh[NEXP * DIM];
  for (int i = threadIdx.x; i < NEXP * DIM; i += 256) gwsh[i] = gw[i];
  __syncthreads();

  const int wv = threadIdx.x >> 6;
  const int l = threadIdx.x & 63;
  #pragma unroll
  for (int tt = 0; tt < 4; tt++) {
    const int t = blockIdx.x * 16 + wv * 4 + tt;
    const float* xr = x + (size_t)t * DIM;
    float xv[16];
    #pragma unroll
    for (int j = 0; j < 16; j++) xv[j] = xr[l + 64 * j];
    float logit[16];
    #pragma unroll
    for (int e = 0; e < 16; e++) {
      const float* g = gwsh + e * DIM;
      float s = 0.f;
      #pragma unroll
      for (int j = 0; j < 16; j++) s += xv[j] * g[l + 64 * j];
      #pragma unroll
      for (int o = 32; o >= 1; o >>= 1) s += __shfl_xor(s, o);
      logit[e] = s;
    }
    if (l == 0) {
      const float tinv = 1.0f / temp[0];
      int i0 = 0; float v0 = logit[0] * tinv;
      #pragma unroll
      for (int e = 1; e < 16; e++) { float v = logit[e] * tinv; if (v > v0) { v0 = v; i0 = e; } }
      int i1 = -1; float v1 = 0.f; bool first = true;
      #pragma unroll
      for (int e = 0; e < 16; e++) {
        if (e == i0) continue;
        float v = logit[e] * tinv;
        if (first || v > v1) { v1 = v; i1 = e; first = false; }
      }
      float ex = expf(v1 - v0);
      float den = 1.0f + ex;
      top2i[2 * t] = i0; top2i[2 * t + 1] = i1;
      top2w[2 * t] = 1.0f / den; top2w[2 * t + 1] = ex / den;
      atomicAdd(&meta[8 + i0], 1);
      atomicAdd(&meta[8 + i1], 1);
    }
  }
}

__global__ void k_offsets(int* __restrict__ meta) {
  if (threadIdx.x == 0 && blockIdx.x == 0) {
    int o = 0;
    for (int e = 0; e < 16; e++) { meta[32 + e] = o; o += (meta[8 + e] + 255) & ~255; }
    meta[48] = o;
    for (int rt = 0; rt < ROWS_CAP / BM; rt++) {
      const int base = rt * BM;
      int e = 0;
      for (int i = 1; i < 16; i++) if (meta[32 + i] <= base) e = i;
      meta[96 + rt] = e;
    }
  }
}

__global__ void k_assign(const int* __restrict__ top2i,
                         const float* __restrict__ top2w,
                         int* __restrict__ meta, int* __restrict__ tok_of_row,
                         int* __restrict__ t2row)
{
  int t = blockIdx.x * 256 + threadIdx.x;
  if (t >= NTOK) return;
  #pragma unroll
  for (int k = 0; k < 2; k++) {
    int e = top2i[2 * t + k];
    int slot = atomicAdd(&meta[64 + e], 1);
    int row = meta[32 + e] + slot;
    tok_of_row[row] = t;
    t2row[2 * t + k] = row;
  }
}

// --------------------------- block-mask bitmaps ------------------------------
__global__ void k_bmask(const void* __restrict__ m1, const void* __restrict__ m2,
                        const void* __restrict__ mc, const int* __restrict__ meta,
                        unsigned int* __restrict__ bm1,
                        unsigned long long* __restrict__ bm2,
                        unsigned int* __restrict__ bmc)
{
  const int flag = flag_of(meta[1]);
  const int id = blockIdx.x * 256 + threadIdx.x;
  if (id < 1024) {
    int e = id >> 6, ct = id & 63;
    unsigned int bits = 0;
    size_t basei = (size_t)e * DIM * HID + (size_t)ct * 64;
    for (int db = 0; db < 16; db++)
      if (mask_at(m1, flag, basei + (size_t)db * 64 * HID)) bits |= 1u << db;
    bm1[id] = bits;
  }
  if (id < 256) {
    int e = id >> 4, ct = id & 15;
    unsigned long long bits = 0;
    size_t basei = (size_t)e * HID * DIM + (size_t)ct * 64;
    for (int db = 0; db < 64; db++)
      if (mask_at(m2, flag, basei + (size_t)db * 64 * DIM)) bits |= 1ull << db;
    bm2[id] = bits;
  }
  if (id < 16) {
    unsigned int bits = 0;
    for (int db = 0; db < 16; db++)
      if (mask_at(mc, flag, (size_t)db * 64 * DIM + (size_t)id * 64)) bits |= 1u << db;
    bmc[id] = bits;
  }
}

__global__ void k_xcast(const float* __restrict__ x, unsigned short* __restrict__ xb) {
  int i = blockIdx.x * 256 + threadIdx.x;
  const fx4* s = (const fx4*)x + (size_t)i * 2;
  fx4 a = s[0], b = s[1];
  ux4 o;
  o[0] = cvt_pk(a[0], a[1]);
  o[1] = cvt_pk(a[2], a[3]);
  o[2] = cvt_pk(b[0], b[1]);
  o[3] = cvt_pk(b[2], b[3]);
  ((ux4*)xb)[i] = o;
}

// --------------------------- GEMM 1: h = silu(x @ w1m + b1) -----------------
// BM=256 x BN=64, dbuf; A via global_load_lds (pre-swizzled source), B f32
// reg-staged: loads issued BEFORE compute, ds_write after (T14 overlap).
__global__ __launch_bounds__(256, 2)
void k_gemm1(const unsigned short* __restrict__ xb,
             const float* __restrict__ w1, const float* __restrict__ b1,
             const unsigned int* __restrict__ bm1,
             const int* __restrict__ meta, const int* __restrict__ tok_of_row,
             unsigned short* __restrict__ h_c)
{
  __shared__ ux4 Ash[2][2048];                  // 2 x 32 KB (256 rows x 64 k)
  __shared__ __align__(16) ux2 Bsh[2][1024];    // 2 x 8 KB

  const int bid = xcd_swz();
  const int rt = bid >> 6, ct = bid & 63;       // NCT = 64
  const int base = rt * BM;
  if (base >= meta[48]) return;
  const int e = meta[96 + rt];

  const int tid = threadIdx.x;
  const int wv = tid >> 6;
  const int jg0 = ct * 64;
  unsigned int bits = bm1[e * 64 + ct];

  const unsigned int sseg = (unsigned int)(((tid & 7) ^ ((tid >> 3) & 7)) * 16);
  unsigned int aoff[8];
  #pragma unroll
  for (int i = 0; i < 8; i++) {
    int tok = tok_of_row[base + i * 32 + (tid >> 3)];
    if (tok < 0) tok = 0;                       // pad rows: finite garbage, unused
    aoff[i] = (unsigned int)tok * (DIM * 2) + sseg;
  }

  const int l = tid & 63, l16 = l & 15, lhi = l >> 4;
  const int kb = tid >> 4, jb = tid & 15;

  fx4 acc[4][4] = {};

  auto STAGE_A = [&](int b, int d0) {
    const char* gp = (const char*)xb + (d0 << 1);
    #pragma unroll
    for (int i = 0; i < 8; i++)
      __builtin_amdgcn_global_load_lds(
        (const __attribute__((address_space(1))) unsigned int*)(gp + aoff[i]),
        (__attribute__((address_space(3))) unsigned int*)&Ash[b][i * 256 + wv * 64],
        16, 0, 0);
  };
  auto LOAD_B = [&](fx4* r, int d0) {
    const float* bp = w1 + ((size_t)e * DIM + d0 + kb * 4) * HID + jg0 + jb * 4;
    r[0] = *(const fx4*)bp;
    r[1] = *(const fx4*)(bp + HID);
    r[2] = *(const fx4*)(bp + 2 * HID);
    r[3] = *(const fx4*)(bp + 3 * HID);
  };
  auto WRITE_B = [&](int b, const fx4* r) {
    #pragma unroll
    for (int jj = 0; jj < 4; jj++) {
      ux2 val;
      val[0] = cvt_pk(r[0][jj], r[1][jj]);
      val[1] = cvt_pk(r[2][jj], r[3][jj]);
      const int col = jb * 4 + jj;
      Bsh[b][(col * 8 + ((kb >> 1) ^ (col & 7))) * 2 + (kb & 1)] = val;
    }
  };
  auto COMPUTE = [&](int b) {
    #pragma unroll
    for (int ks = 0; ks < 2; ks++) {
      s8v a[4], bb[4];
      const int seg = ks * 4 + lhi;
      #pragma unroll
      for (int m = 0; m < 4; m++) {
        const int row = wv * 64 + m * 16 + l16;
        V16 v; v.u = Ash[b][row * 8 + (seg ^ (row & 7))]; a[m] = v.s;
      }
      #pragma unroll
      for (int n = 0; n < 4; n++) {
        const int col = n * 16 + l16;
        V16 v; v.u = ((const ux4*)&Bsh[b][0])[col * 8 + (seg ^ (col & 7))]; bb[n] = v.s;
      }
      #pragma unroll
      for (int m = 0; m < 4; m++)
        #pragma unroll
        for (int n = 0; n < 4; n++)
          acc[m][n] = __builtin_amdgcn_mfma_f32_16x16x32_bf16(a[m], bb[n], acc[m][n], 0, 0, 0);
    }
  };

  if (bits) {
    int d0 = (__ffs(bits) - 1) << 6; bits &= bits - 1;
    {
      fx4 br[4];
      STAGE_A(0, d0);
      LOAD_B(br, d0);
      WRITE_B(0, br);
    }
    __syncthreads();
    int cur = 0;
    for (;;) {
      int nd0 = -1;
      fx4 br2[4];
      if (bits) { nd0 = (__ffs(bits) - 1) << 6; bits &= bits - 1; }
      if (nd0 >= 0) { STAGE_A(cur ^ 1, nd0); LOAD_B(br2, nd0); }
      COMPUTE(cur);
      if (nd0 >= 0) WRITE_B(cur ^ 1, br2);
      __syncthreads();
      cur ^= 1;
      if (nd0 < 0) break;
    }
  }

  // epilogue: silu(acc + b1) -> LDS bf16 tile -> coalesced 16B dump
  unsigned short* hs = (unsigned short*)&Ash[0][0];
  __syncthreads();
  #pragma unroll
  for (int m = 0; m < 4; m++)
    #pragma unroll
    for (int n = 0; n < 4; n++) {
      const int gcol = jg0 + n * 16 + l16;
      const float bbv = b1[e * HID + gcol];
      #pragma unroll
      for (int i = 0; i < 4; i++) {
        const int row = wv * 64 + m * 16 + lhi * 4 + i;
        float v = acc[m][n][i] + bbv;
        float hval = v / (1.0f + expf(-v));
        hs[row * 64 + n * 16 + l16] = (unsigned short)f2bf(hval);
      }
    }
  __syncthreads();
  {
    const ux4* s = (const ux4*)hs;
    #pragma unroll
    for (int j = 0; j < 8; j++) {
      const int c2 = j * 256 + tid;
      const int row = c2 >> 3;
      *(ux4*)(h_c + (size_t)(base + row) * HID + ct * 64 + (c2 & 7) * 8) = s[c2];
    }
  }
}

// --------------------------- GEMM 2: y = h @ w2m + b2 (pair rows, bf16 out) -
// Block = (rt, quarter): loops 4 column tiles; h panel re-reads are
// temporally local (L2-hot). Same DMA-staged dbuf pipeline per ct.
__global__ __launch_bounds__(256, 2)
void k_gemm2(const unsigned short* __restrict__ h_c,
             const float* __restrict__ w2, const float* __restrict__ b2,
             const unsigned long long* __restrict__ bm2,
             const int* __restrict__ meta, unsigned short* __restrict__ yb)
{
  __shared__ ux4 Ash[2][2048];
  __shared__ __align__(16) ux2 Bsh[2][1024];

  const int bid = xcd_swz();
  const int rt = bid >> 2, ctq = bid & 3;       // 4 quarters
  const int base = rt * BM;
  if (base >= meta[48]) return;
  const int e = meta[96 + rt];

  const int tid = threadIdx.x;
  const int wv = tid >> 6;

  const unsigned int sseg = (unsigned int)(((tid & 7) ^ ((tid >> 3) & 7)) * 16);
  unsigned int aoff[8];
  #pragma unroll
  for (int i = 0; i < 8; i++)
    aoff[i] = (unsigned int)(base + i * 32 + (tid >> 3)) * (unsigned int)(HID * 2) + sseg;

  const int l = tid & 63, l16 = l & 15, lhi = l >> 4;
  const int kb = tid >> 4, jb = tid & 15;

  auto STAGE_A = [&](int b, int d0) {
    const char* gp = (const char*)h_c + (d0 << 1);
    #pragma unroll
    for (int i = 0; i < 8; i++)
      __builtin_amdgcn_global_load_lds(
        (const __attribute__((address_space(1))) unsigned int*)(gp + aoff[i]),
        (__attribute__((address_space(3))) unsigned int*)&Ash[b][i * 256 + wv * 64],
        16, 0, 0);
  };

  for (int q = 0; q < 4; q++) {
    const int ct = ctq * 4 + q;
    const int jg0 = ct * 64;
    unsigned long long bits = bm2[e * 16 + ct];

    fx4 acc[4][4] = {};

    auto LOAD_B = [&](fx4* r, int d0) {
      const float* bp = w2 + ((size_t)e * HID + d0 + kb * 4) * DIM + jg0 + jb * 4;
      r[0] = *(const fx4*)bp;
      r[1] = *(const fx4*)(bp + DIM);
      r[2] = *(const fx4*)(bp + 2 * DIM);
      r[3] = *(const fx4*)(bp + 3 * DIM);
    };
    auto WRITE_B = [&](int b, const fx4* r) {
      #pragma unroll
      for (int jj = 0; jj < 4; jj++) {
        ux2 val;
        val[0] = cvt_pk(r[0][jj], r[1][jj]);
        val[1] = cvt_pk(r[2][jj], r[3][jj]);
        const int col = jb * 4 + jj;
        Bsh[b][(col * 8 + ((kb >> 1) ^ (col & 7))) * 2 + (kb & 1)] = val;
      }
    };
    auto COMPUTE = [&](int b) {
      #pragma unroll
      for (int ks = 0; ks < 2; ks++) {
        s8v a[4], bb[4];
        const int seg = ks * 4 + lhi;
        #pragma unroll
        for (int m = 0; m < 4; m++) {
          const int row = wv * 64 + m * 16 + l16;
          V16 v; v.u = Ash[b][row * 8 + (seg ^ (row & 7))]; a[m] = v.s;
        }
        #pragma unroll
        for (int n = 0; n < 4; n++) {
          const int col = n * 16 + l16;
          V16 v; v.u = ((const ux4*)&Bsh[b][0])[col * 8 + (seg ^ (col & 7))]; bb[n] = v.s;
        }
        #pragma unroll
        for (int m = 0; m < 4; m++)
          #pragma unroll
          for (int n = 0; n < 4; n++)
            acc[m][n] = __builtin_amdgcn_mfma_f32_16x16x32_bf16(a[m], bb[n], acc[m][n], 0, 0, 0);
      }
    };

    if (bits) {
      int d0 = (__ffsll(bits) - 1) << 6; bits &= bits - 1;
      {
        fx4 br[4];
        STAGE_A(0, d0);
        LOAD_B(br, d0);
        WRITE_B(0, br);
      }
      __syncthreads();
      int cur = 0;
      for (;;) {
        int nd0 = -1;
        fx4 br2[4];
        if (bits) { nd0 = (__ffsll(bits) - 1) << 6; bits &= bits - 1; }
        if (nd0 >= 0) { STAGE_A(cur ^ 1, nd0); LOAD_B(br2, nd0); }
        COMPUTE(cur);
        if (nd0 >= 0) WRITE_B(cur ^ 1, br2);
        __syncthreads();
        cur ^= 1;
        if (nd0 < 0) break;
      }
    }

    // epilogue: y = bf16(acc + b2), restaged via LDS for 16B coalesced dump
    __syncthreads();                       // protect Ash[0] (prior dump / DMA)
    unsigned short* hs = (unsigned short*)&Ash[0][0];
    #pragma unroll
    for (int m = 0; m < 4; m++)
      #pragma unroll
      for (int n = 0; n < 4; n++) {
        const int gcol = jg0 + n * 16 + l16;
        const float bbv = b2[e * DIM + gcol];
        #pragma unroll
        for (int i = 0; i < 4; i++) {
          const int row = wv * 64 + m * 16 + lhi * 4 + i;
          hs[row * 64 + n * 16 + l16] = (unsigned short)f2bf(acc[m][n][i] + bbv);
        }
      }
    __syncthreads();
    {
      const ux4* s = (const ux4*)hs;
      #pragma unroll
      for (int j = 0; j < 8; j++) {
        const int c2 = j * 256 + tid;
        const int row = c2 >> 3;
        *(ux4*)(yb + (size_t)(base + row) * DIM + ct * 64 + (c2 & 7) * 8) = s[c2];
      }
    }
    __syncthreads();                       // dump done before next ct's STAGE_A
  }
}

// --------------------------- cross: out = x + eo @ cwm + cb -----------------
// eo rows formed on the fly from bf16 y: eo[tok] = w0*y[r0] + w1*y[r1]
__global__ __launch_bounds__(256, 2)
void k_cross(const unsigned short* __restrict__ yb, const float* __restrict__ x,
             const float* __restrict__ cw, const float* __restrict__ cb,
             const unsigned int* __restrict__ bmc,
             const int* __restrict__ t2row, const float* __restrict__ t2w,
             float* __restrict__ out)
{
  __shared__ ux4 Ash[2048];
  __shared__ __align__(16) ux2 Bsh[1024];

  const int bid = xcd_swz();
  const int rt = bid >> 4, ct = bid & 15;
  const int base = rt * BM;
  const int tid = threadIdx.x;
  const int jg0 = ct * 64;

  const int tok = base + tid;
  const int r0 = t2row[2 * tok], r1 = t2row[2 * tok + 1];
  const float w0 = t2w[2 * tok], w1 = t2w[2 * tok + 1];

  fx4 acc[4][4] = {};
  const int wave = tid >> 6, l = tid & 63;
  const int l16 = l & 15, lhi = l >> 4;

  unsigned int bits = bmc[ct];
  while (bits) {
    const int kbx = __ffs(bits) - 1; bits &= bits - 1;
    const int d0 = kbx * 64;
    {   // stage A: combine two bf16 pair rows -> bf16 (swizzled ds_write)
      const ux4* s0 = (const ux4*)(yb + (size_t)r0 * DIM + d0);
      const ux4* s1 = (const ux4*)(yb + (size_t)r1 * DIM + d0);
      #pragma unroll
      for (int seg = 0; seg < 8; seg++) {
        ux4 v0 = s0[seg], v1 = s1[seg], o;
        #pragma unroll
        for (int j = 0; j < 4; j++) {
          float alo = __uint_as_float(v0[j] << 16);
          float ahi = __uint_as_float(v0[j] & 0xFFFF0000u);
          float blo = __uint_as_float(v1[j] << 16);
          float bhi = __uint_as_float(v1[j] & 0xFFFF0000u);
          o[j] = cvt_pk(w0 * alo + w1 * blo, w0 * ahi + w1 * bhi);
        }
        Ash[tid * 8 + (seg ^ (tid & 7))] = o;
      }
    }
    {   // stage B from cross_w (f32 reg-staged)
      const int kbt = tid >> 4, jb = tid & 15;
      const float* bp = cw + (size_t)(d0 + kbt * 4) * DIM + jg0 + jb * 4;
      fx4 r0v = *(const fx4*)bp;
      fx4 r1v = *(const fx4*)(bp + DIM);
      fx4 r2v = *(const fx4*)(bp + 2 * DIM);
      fx4 r3v = *(const fx4*)(bp + 3 * DIM);
      #pragma unroll
      for (int jj = 0; jj < 4; jj++) {
        ux2 val;
        val[0] = cvt_pk(r0v[jj], r1v[jj]);
        val[1] = cvt_pk(r2v[jj], r3v[jj]);
        const int col = jb * 4 + jj;
        Bsh[(col * 8 + ((kbt >> 1) ^ (col & 7))) * 2 + (kbt & 1)] = val;
      }
    }
    __syncthreads();
    #pragma unroll
    for (int ks = 0; ks < 2; ks++) {
      s8v a[4], b[4];
      const int seg = ks * 4 + lhi;
      #pragma unroll
      for (int m = 0; m < 4; m++) {
        const int row = wave * 64 + m * 16 + l16;
        V16 v; v.u = Ash[row * 8 + (seg ^ (row & 7))]; a[m] = v.s;
      }
      #pragma unroll
      for (int n = 0; n < 4; n++) {
        const int col = n * 16 + l16;
        V16 v; v.u = ((const ux4*)Bsh)[col * 8 + (seg ^ (col & 7))]; b[n] = v.s;
      }
      #pragma unroll
      for (int m = 0; m < 4; m++)
        #pragma unroll
        for (int n = 0; n < 4; n++)
          acc[m][n] = __builtin_amdgcn_mfma_f32_16x16x32_bf16(a[m], b[n], acc[m][n], 0, 0, 0);
    }
    __syncthreads();
  }

  #pragma unroll
  for (int m = 0; m < 4; m++)
    #pragma unroll
    for (int n = 0; n < 4; n++) {
      const int gcol = jg0 + n * 16 + l16;
      #pragma unroll
      for (int i = 0; i < 4; i++) {
        const int lrow = wave * 64 + m * 16 + lhi * 4 + i;
        const size_t idx = (size_t)(base + lrow) * DIM + gcol;
        out[idx] = acc[m][n][i] + x[idx] + cb[gcol];
      }
    }
}

// ---------------------------------------------------------------------------
extern "C" void kernel_launch(void* const* d_in, const int* in_sizes, int n_in,
                              void* d_out, int out_size, void* d_ws, size_t ws_size,
                              hipStream_t stream)
{
  (void)in_sizes; (void)n_in; (void)out_size; (void)ws_size;
  const float* x      = (const float*)d_in[0];
  const float* gate_w = (const float*)d_in[1];   // [2,16,1024]
  const float* temp   = (const float*)d_in[2];   // [2]
  const float* w1     = (const float*)d_in[3];   // [16,1024,4096]
  const float* b1     = (const float*)d_in[4];
  const float* w2     = (const float*)d_in[5];   // [16,4096,1024]
  const float* b2     = (const float*)d_in[6];
  const float* cw     = (const float*)d_in[7];   // [1024,1024]
  const float* cb     = (const float*)d_in[8];
  const void*  mask1  = d_in[9];
  const void*  mask2  = d_in[10];
  const void*  cmask  = d_in[11];
  float* out = (float*)d_out;
  char* ws = (char*)d_ws;

  size_t off = 0;
  auto walloc = [&](size_t b) { size_t r = off; off = (off + b + 255) & ~(size_t)255; return r; };
  size_t o_meta = walloc(4096);
  size_t o_bm1  = walloc(1024 * 4);
  size_t o_bm2  = walloc(256 * 8);
  size_t o_bmc  = walloc(64 * 4);
  size_t o_t2i  = walloc((size_t)NTOK * 2 * 4);
  size_t o_t2w  = walloc((size_t)NTOK * 2 * 4);
  size_t o_t2r  = walloc((size_t)NTOK * 2 * 4);
  size_t o_tok  = walloc((size_t)ROWS_CAP * 4);
  size_t o_xbf  = walloc((size_t)NTOK * DIM * 2);
  size_t o_y    = walloc((size_t)ROWS_CAP * DIM * 2);    // 40 MB (bf16)
  size_t o_hc   = walloc((size_t)ROWS_CAP * HID * 2);    // 168 MB

  int*                meta = (int*)(ws + o_meta);
  unsigned int*       bm1  = (unsigned int*)(ws + o_bm1);
  unsigned long long* bm2  = (unsigned long long*)(ws + o_bm2);
  unsigned int*       bmc  = (unsigned int*)(ws + o_bmc);
  int*                t2i  = (int*)(ws + o_t2i);
  float*              t2w  = (float*)(ws + o_t2w);
  int*                t2r  = (int*)(ws + o_t2r);
  int*                tok  = (int*)(ws + o_tok);
  unsigned short*     xbf  = (unsigned short*)(ws + o_xbf);
  unsigned short*     yb   = (unsigned short*)(ws + o_y);
  unsigned short*     hc   = (unsigned short*)(ws + o_hc);

  hipMemsetAsync(ws + o_meta, 0, 4096, stream);
  hipMemsetAsync(ws + o_tok, 0xFF, (size_t)ROWS_CAP * 4, stream);  // -1

  k_detect <<<64, 256, 0, stream>>>((const unsigned int*)mask1, meta);
  k_bmask  <<<4, 256, 0, stream>>>(mask1, mask2, cmask, meta, bm1, bm2, bmc);
  k_route  <<<NTOK / 16, 256, 0, stream>>>(x, gate_w + (size_t)1 * NEXP * DIM, temp + 1, t2i, t2w, meta);
  k_offsets<<<1, 64, 0, stream>>>(meta);
  k_assign <<<NTOK / 256, 256, 0, stream>>>(t2i, t2w, meta, tok, t2r);
  k_xcast  <<<(NTOK * DIM / 8) / 256, 256, 0, stream>>>(x, xbf);

  const int NRT = ROWS_CAP / BM;   // 80
  k_gemm1<<<NRT * 64, 256, 0, stream>>>(xbf, w1, b1, bm1, meta, tok, hc);
  k_gemm2<<<NRT * 4, 256, 0, stream>>>(hc, w2, b2, bm2, meta, yb);
  k_cross<<<(NTOK / BM) * 16, 256, 0, stream>>>(yb, x, cw, cb, bmc, t2r, t2w, out);
}

// Round 9
// 460.704 us; speedup vs baseline: 1.6838x; 1.1003x over previous
//
#include <hip/hip_runtime.h>

// ---------------------------------------------------------------------------
// HierarchicalSparseLayer: top-2 MoE with block-sparse (64x64) masked weights
// B=8192 tokens, D=1024, H=4096, E=16 experts, K=2, + block-sparse cross proj.
// R9: R6 core (BM=256/BN=64, A via global_load_lds dbuf, B reg-staged f32
//     issue-early/write-late, XCD swizzle) + bf16 y (R8) + gemm2 back to
//     per-ct blocks (1280, full machine) + __expf + detect folded into route.
// ---------------------------------------------------------------------------

#define NTOK 8192
#define DIM  1024
#define HID  4096
#define NEXP 16
#define BM   256
#define ROWS_CAP (NTOK*2 + NEXP*256)   // 20480

typedef __attribute__((ext_vector_type(4))) float fx4;
typedef __attribute__((ext_vector_type(4))) unsigned int ux4;
typedef __attribute__((ext_vector_type(2))) unsigned int ux2;
typedef __attribute__((ext_vector_type(8))) short s8v;
union V16 { ux4 u; s8v s; };

__device__ __forceinline__ unsigned int f2bf(float f) {
  unsigned int u = __float_as_uint(f);
  return (u + 0x7fffu + ((u >> 16) & 1u)) >> 16;   // RNE, inputs finite
}

__device__ __forceinline__ unsigned int cvt_pk(float lo, float hi) {
  unsigned int r;
  asm("v_cvt_pk_bf16_f32 %0, %1, %2" : "=v"(r) : "v"(lo), "v"(hi));
  return r;
}

// Mask dtype detected at runtime: flag 0=u8, 1=i32, 2=f32
__device__ __forceinline__ bool mask_at(const void* m, int flag, size_t idx) {
  if (flag == 0) return ((const unsigned char*)m)[idx] != 0;
  if (flag == 1) return ((const int*)m)[idx] != 0;
  return ((const float*)m)[idx] != 0.0f;
}

__device__ __forceinline__ int flag_of(int ev) {
  return (ev & 2) ? 2 : ((ev & 1) ? 0 : 1);
}

// XCD-aware swizzle (grid % 8 == 0)
__device__ __forceinline__ int xcd_swz() {
  const int b = blockIdx.x, cpx = gridDim.x >> 3;
  return (b & 7) * cpx + (b >> 3);
}

// --------------------------- routing (+ mask dtype detect) ------------------
// meta: [1]=detect bits [8..23]=counts [32..47]=offsets [48]=total
//       [64..79]=slot counters [96..175]=expert_of_rt
__global__ void k_route(const float* __restrict__ x,
                        const float* __restrict__ gw,    // gate_w[-1] [16,1024]
                        const float* __restrict__ temp,
                        const unsigned int* __restrict__ m1raw,
                        int* __restrict__ top2i, float* __restrict__ top2w,
                        int* __restrict__ meta)
{
  // fold k_detect into first 64 blocks (independent of routing work)
  if (blockIdx.x < 64) {
    int bits = 0;
    size_t base = (size_t)blockIdx.x * 4096 + threadIdx.x;
    for (int j = 0; j < 16; j++) {
      unsigned int v = m1raw[base + 256 * j];
      if (v == 0x3f800000u) bits |= 2;
      else if (v > 1u)      bits |= 1;
    }
    if (bits) atomicOr(&meta[1], bits);
  }

  __shared__ float gwsh[NEXP * DIM];
  for (int i = threadIdx.x; i < NEXP * DIM; i += 256) gwsh[i] = gw[i];
  __syncthreads();

  const int wv = threadIdx.x >> 6;
  const int l = threadIdx.x & 63;
  #pragma unroll
  for (int tt = 0; tt < 4; tt++) {
    const int t = blockIdx.x * 16 + wv * 4 + tt;
    const float* xr = x + (size_t)t * DIM;
    float xv[16];
    #pragma unroll
    for (int j = 0; j < 16; j++) xv[j] = xr[l + 64 * j];
    float logit[16];
    #pragma unroll
    for (int e = 0; e < 16; e++) {
      const float* g = gwsh + e * DIM;
      float s = 0.f;
      #pragma unroll
      for (int j = 0; j < 16; j++) s += xv[j] * g[l + 64 * j];
      #pragma unroll
      for (int o = 32; o >= 1; o >>= 1) s += __shfl_xor(s, o);
      logit[e] = s;
    }
    if (l == 0) {
      const float tinv = 1.0f / temp[0];
      int i0 = 0; float v0 = logit[0] * tinv;
      #pragma unroll
      for (int e = 1; e < 16; e++) { float v = logit[e] * tinv; if (v > v0) { v0 = v; i0 = e; } }
      int i1 = -1; float v1 = 0.f; bool first = true;
      #pragma unroll
      for (int e = 0; e < 16; e++) {
        if (e == i0) continue;
        float v = logit[e] * tinv;
        if (first || v > v1) { v1 = v; i1 = e; first = false; }
      }
      float ex = __expf(v1 - v0);
      float den = 1.0f + ex;
      top2i[2 * t] = i0; top2i[2 * t + 1] = i1;
      top2w[2 * t] = 1.0f / den; top2w[2 * t + 1] = ex / den;
      atomicAdd(&meta[8 + i0], 1);
      atomicAdd(&meta[8 + i1], 1);
    }
  }
}

__global__ void k_offsets(int* __restrict__ meta) {
  if (threadIdx.x == 0 && blockIdx.x == 0) {
    int o = 0;
    for (int e = 0; e < 16; e++) { meta[32 + e] = o; o += (meta[8 + e] + 255) & ~255; }
    meta[48] = o;
    for (int rt = 0; rt < ROWS_CAP / BM; rt++) {
      const int base = rt * BM;
      int e = 0;
      for (int i = 1; i < 16; i++) if (meta[32 + i] <= base) e = i;
      meta[96 + rt] = e;
    }
  }
}

__global__ void k_assign(const int* __restrict__ top2i,
                         const float* __restrict__ top2w,
                         int* __restrict__ meta, int* __restrict__ tok_of_row,
                         int* __restrict__ t2row)
{
  int t = blockIdx.x * 256 + threadIdx.x;
  if (t >= NTOK) return;
  #pragma unroll
  for (int k = 0; k < 2; k++) {
    int e = top2i[2 * t + k];
    int slot = atomicAdd(&meta[64 + e], 1);
    int row = meta[32 + e] + slot;
    tok_of_row[row] = t;
    t2row[2 * t + k] = row;
  }
}

// --------------------------- block-mask bitmaps ------------------------------
__global__ void k_bmask(const void* __restrict__ m1, const void* __restrict__ m2,
                        const void* __restrict__ mc, const int* __restrict__ meta,
                        unsigned int* __restrict__ bm1,
                        unsigned long long* __restrict__ bm2,
                        unsigned int* __restrict__ bmc)
{
  const int flag = flag_of(meta[1]);
  const int id = blockIdx.x * 256 + threadIdx.x;
  if (id < 1024) {
    int e = id >> 6, ct = id & 63;
    unsigned int bits = 0;
    size_t basei = (size_t)e * DIM * HID + (size_t)ct * 64;
    for (int db = 0; db < 16; db++)
      if (mask_at(m1, flag, basei + (size_t)db * 64 * HID)) bits |= 1u << db;
    bm1[id] = bits;
  }
  if (id < 256) {
    int e = id >> 4, ct = id & 15;
    unsigned long long bits = 0;
    size_t basei = (size_t)e * HID * DIM + (size_t)ct * 64;
    for (int db = 0; db < 64; db++)
      if (mask_at(m2, flag, basei + (size_t)db * 64 * DIM)) bits |= 1ull << db;
    bm2[id] = bits;
  }
  if (id < 16) {
    unsigned int bits = 0;
    for (int db = 0; db < 16; db++)
      if (mask_at(mc, flag, (size_t)db * 64 * DIM + (size_t)id * 64)) bits |= 1u << db;
    bmc[id] = bits;
  }
}

__global__ void k_xcast(const float* __restrict__ x, unsigned short* __restrict__ xb) {
  int i = blockIdx.x * 256 + threadIdx.x;
  const fx4* s = (const fx4*)x + (size_t)i * 2;
  fx4 a = s[0], b = s[1];
  ux4 o;
  o[0] = cvt_pk(a[0], a[1]);
  o[1] = cvt_pk(a[2], a[3]);
  o[2] = cvt_pk(b[0], b[1]);
  o[3] = cvt_pk(b[2], b[3]);
  ((ux4*)xb)[i] = o;
}

// --------------------------- GEMM 1: h = silu(x @ w1m + b1) -----------------
// BM=256 x BN=64, dbuf; A via global_load_lds (pre-swizzled source), B f32
// reg-staged: loads issued BEFORE compute, ds_write after (T14 overlap).
__global__ __launch_bounds__(256, 2)
void k_gemm1(const unsigned short* __restrict__ xb,
             const float* __restrict__ w1, const float* __restrict__ b1,
             const unsigned int* __restrict__ bm1,
             const int* __restrict__ meta, const int* __restrict__ tok_of_row,
             unsigned short* __restrict__ h_c)
{
  __shared__ ux4 Ash[2][2048];                  // 2 x 32 KB (256 rows x 64 k)
  __shared__ __align__(16) ux2 Bsh[2][1024];    // 2 x 8 KB

  const int bid = xcd_swz();
  const int rt = bid >> 6, ct = bid & 63;       // NCT = 64
  const int base = rt * BM;
  if (base >= meta[48]) return;
  const int e = meta[96 + rt];

  const int tid = threadIdx.x;
  const int wv = tid >> 6;
  const int jg0 = ct * 64;
  unsigned int bits = bm1[e * 64 + ct];

  const unsigned int sseg = (unsigned int)(((tid & 7) ^ ((tid >> 3) & 7)) * 16);
  unsigned int aoff[8];
  #pragma unroll
  for (int i = 0; i < 8; i++) {
    int tok = tok_of_row[base + i * 32 + (tid >> 3)];
    if (tok < 0) tok = 0;                       // pad rows: finite garbage, unused
    aoff[i] = (unsigned int)tok * (DIM * 2) + sseg;
  }

  const int l = tid & 63, l16 = l & 15, lhi = l >> 4;
  const int kb = tid >> 4, jb = tid & 15;

  fx4 acc[4][4] = {};

  auto STAGE_A = [&](int b, int d0) {
    const char* gp = (const char*)xb + (d0 << 1);
    #pragma unroll
    for (int i = 0; i < 8; i++)
      __builtin_amdgcn_global_load_lds(
        (const __attribute__((address_space(1))) unsigned int*)(gp + aoff[i]),
        (__attribute__((address_space(3))) unsigned int*)&Ash[b][i * 256 + wv * 64],
        16, 0, 0);
  };
  auto LOAD_B = [&](fx4* r, int d0) {
    const float* bp = w1 + ((size_t)e * DIM + d0 + kb * 4) * HID + jg0 + jb * 4;
    r[0] = *(const fx4*)bp;
    r[1] = *(const fx4*)(bp + HID);
    r[2] = *(const fx4*)(bp + 2 * HID);
    r[3] = *(const fx4*)(bp + 3 * HID);
  };
  auto WRITE_B = [&](int b, const fx4* r) {
    #pragma unroll
    for (int jj = 0; jj < 4; jj++) {
      ux2 val;
      val[0] = cvt_pk(r[0][jj], r[1][jj]);
      val[1] = cvt_pk(r[2][jj], r[3][jj]);
      const int col = jb * 4 + jj;
      Bsh[b][(col * 8 + ((kb >> 1) ^ (col & 7))) * 2 + (kb & 1)] = val;
    }
  };
  auto COMPUTE = [&](int b) {
    #pragma unroll
    for (int ks = 0; ks < 2; ks++) {
      s8v a[4], bb[4];
      const int seg = ks * 4 + lhi;
      #pragma unroll
      for (int m = 0; m < 4; m++) {
        const int row = wv * 64 + m * 16 + l16;
        V16 v; v.u = Ash[b][row * 8 + (seg ^ (row & 7))]; a[m] = v.s;
      }
      #pragma unroll
      for (int n = 0; n < 4; n++) {
        const int col = n * 16 + l16;
        V16 v; v.u = ((const ux4*)&Bsh[b][0])[col * 8 + (seg ^ (col & 7))]; bb[n] = v.s;
      }
      #pragma unroll
      for (int m = 0; m < 4; m++)
        #pragma unroll
        for (int n = 0; n < 4; n++)
          acc[m][n] = __builtin_amdgcn_mfma_f32_16x16x32_bf16(a[m], bb[n], acc[m][n], 0, 0, 0);
    }
  };

  if (bits) {
    int d0 = (__ffs(bits) - 1) << 6; bits &= bits - 1;
    {
      fx4 br[4];
      STAGE_A(0, d0);
      LOAD_B(br, d0);
      WRITE_B(0, br);
    }
    __syncthreads();
    int cur = 0;
    for (;;) {
      int nd0 = -1;
      fx4 br2[4];
      if (bits) { nd0 = (__ffs(bits) - 1) << 6; bits &= bits - 1; }
      if (nd0 >= 0) { STAGE_A(cur ^ 1, nd0); LOAD_B(br2, nd0); }
      COMPUTE(cur);
      if (nd0 >= 0) WRITE_B(cur ^ 1, br2);
      __syncthreads();
      cur ^= 1;
      if (nd0 < 0) break;
    }
  }

  // epilogue: silu(acc + b1) -> LDS bf16 tile -> coalesced 16B dump
  unsigned short* hs = (unsigned short*)&Ash[0][0];
  __syncthreads();
  #pragma unroll
  for (int m = 0; m < 4; m++)
    #pragma unroll
    for (int n = 0; n < 4; n++) {
      const int gcol = jg0 + n * 16 + l16;
      const float bbv = b1[e * HID + gcol];
      #pragma unroll
      for (int i = 0; i < 4; i++) {
        const int row = wv * 64 + m * 16 + lhi * 4 + i;
        float v = acc[m][n][i] + bbv;
        float hval = v / (1.0f + __expf(-v));
        hs[row * 64 + n * 16 + l16] = (unsigned short)f2bf(hval);
      }
    }
  __syncthreads();
  {
    const ux4* s = (const ux4*)hs;
    #pragma unroll
    for (int j = 0; j < 8; j++) {
      const int c2 = j * 256 + tid;
      const int row = c2 >> 3;
      *(ux4*)(h_c + (size_t)(base + row) * HID + ct * 64 + (c2 & 7) * 8) = s[c2];
    }
  }
}

// --------------------------- GEMM 2: y = bf16(h @ w2m + b2) (pair rows) -----
// Per-ct blocks (1280) for full machine utilization; XCD swizzle co-locates
// one rt's 16 cts on an XCD so the h panel is L2-shared concurrently.
__global__ __launch_bounds__(256, 2)
void k_gemm2(const unsigned short* __restrict__ h_c,
             const float* __restrict__ w2, const float* __restrict__ b2,
             const unsigned long long* __restrict__ bm2,
             const int* __restrict__ meta, unsigned short* __restrict__ yb)
{
  __shared__ ux4 Ash[2][2048];
  __shared__ __align__(16) ux2 Bsh[2][1024];

  const int bid = xcd_swz();
  const int rt = bid >> 4, ct = bid & 15;       // NCT = 16
  const int base = rt * BM;
  if (base >= meta[48]) return;
  const int e = meta[96 + rt];

  const int tid = threadIdx.x;
  const int wv = tid >> 6;
  const int jg0 = ct * 64;
  unsigned long long bits = bm2[e * 16 + ct];

  const unsigned int sseg = (unsigned int)(((tid & 7) ^ ((tid >> 3) & 7)) * 16);
  unsigned int aoff[8];
  #pragma unroll
  for (int i = 0; i < 8; i++)
    aoff[i] = (unsigned int)(base + i * 32 + (tid >> 3)) * (unsigned int)(HID * 2) + sseg;

  const int l = tid & 63, l16 = l & 15, lhi = l >> 4;
  const int kb = tid >> 4, jb = tid & 15;

  fx4 acc[4][4] = {};

  auto STAGE_A = [&](int b, int d0) {
    const char* gp = (const char*)h_c + (d0 << 1);
    #pragma unroll
    for (int i = 0; i < 8; i++)
      __builtin_amdgcn_global_load_lds(
        (const __attribute__((address_space(1))) unsigned int*)(gp + aoff[i]),
        (__attribute__((address_space(3))) unsigned int*)&Ash[b][i * 256 + wv * 64],
        16, 0, 0);
  };
  auto LOAD_B = [&](fx4* r, int d0) {
    const float* bp = w2 + ((size_t)e * HID + d0 + kb * 4) * DIM + jg0 + jb * 4;
    r[0] = *(const fx4*)bp;
    r[1] = *(const fx4*)(bp + DIM);
    r[2] = *(const fx4*)(bp + 2 * DIM);
    r[3] = *(const fx4*)(bp + 3 * DIM);
  };
  auto WRITE_B = [&](int b, const fx4* r) {
    #pragma unroll
    for (int jj = 0; jj < 4; jj++) {
      ux2 val;
      val[0] = cvt_pk(r[0][jj], r[1][jj]);
      val[1] = cvt_pk(r[2][jj], r[3][jj]);
      const int col = jb * 4 + jj;
      Bsh[b][(col * 8 + ((kb >> 1) ^ (col & 7))) * 2 + (kb & 1)] = val;
    }
  };
  auto COMPUTE = [&](int b) {
    #pragma unroll
    for (int ks = 0; ks < 2; ks++) {
      s8v a[4], bb[4];
      const int seg = ks * 4 + lhi;
      #pragma unroll
      for (int m = 0; m < 4; m++) {
        const int row = wv * 64 + m * 16 + l16;
        V16 v; v.u = Ash[b][row * 8 + (seg ^ (row & 7))]; a[m] = v.s;
      }
      #pragma unroll
      for (int n = 0; n < 4; n++) {
        const int col = n * 16 + l16;
        V16 v; v.u = ((const ux4*)&Bsh[b][0])[col * 8 + (seg ^ (col & 7))]; bb[n] = v.s;
      }
      #pragma unroll
      for (int m = 0; m < 4; m++)
        #pragma unroll
        for (int n = 0; n < 4; n++)
          acc[m][n] = __builtin_amdgcn_mfma_f32_16x16x32_bf16(a[m], bb[n], acc[m][n], 0, 0, 0);
    }
  };

  if (bits) {
    int d0 = (__ffsll(bits) - 1) << 6; bits &= bits - 1;
    {
      fx4 br[4];
      STAGE_A(0, d0);
      LOAD_B(br, d0);
      WRITE_B(0, br);
    }
    __syncthreads();
    int cur = 0;
    for (;;) {
      int nd0 = -1;
      fx4 br2[4];
      if (bits) { nd0 = (__ffsll(bits) - 1) << 6; bits &= bits - 1; }
      if (nd0 >= 0) { STAGE_A(cur ^ 1, nd0); LOAD_B(br2, nd0); }
      COMPUTE(cur);
      if (nd0 >= 0) WRITE_B(cur ^ 1, br2);
      __syncthreads();
      cur ^= 1;
      if (nd0 < 0) break;
    }
  }

  // epilogue: y = bf16(acc + b2), restaged via LDS for 16B coalesced dump
  unsigned short* hs = (unsigned short*)&Ash[0][0];
  __syncthreads();
  #pragma unroll
  for (int m = 0; m < 4; m++)
    #pragma unroll
    for (int n = 0; n < 4; n++) {
      const int gcol = jg0 + n * 16 + l16;
      const float bbv = b2[e * DIM + gcol];
      #pragma unroll
      for (int i = 0; i < 4; i++) {
        const int row = wv * 64 + m * 16 + lhi * 4 + i;
        hs[row * 64 + n * 16 + l16] = (unsigned short)f2bf(acc[m][n][i] + bbv);
      }
    }
  __syncthreads();
  {
    const ux4* s = (const ux4*)hs;
    #pragma unroll
    for (int j = 0; j < 8; j++) {
      const int c2 = j * 256 + tid;
      const int row = c2 >> 3;
      *(ux4*)(yb + (size_t)(base + row) * DIM + ct * 64 + (c2 & 7) * 8) = s[c2];
    }
  }
}

// --------------------------- cross: out = x + eo @ cwm + cb -----------------
// eo rows formed on the fly from bf16 y: eo[tok] = w0*y[r0] + w1*y[r1]
__global__ __launch_bounds__(256, 2)
void k_cross(const unsigned short* __restrict__ yb, const float* __restrict__ x,
             const float* __restrict__ cw, const float* __restrict__ cb,
             const unsigned int* __restrict__ bmc,
             const int* __restrict__ t2row, const float* __restrict__ t2w,
             float* __restrict__ out)
{
  __shared__ ux4 Ash[2048];
  __shared__ __align__(16) ux2 Bsh[1024];

  const int bid = xcd_swz();
  const int rt = bid >> 4, ct = bid & 15;
  const int base = rt * BM;
  const int tid = threadIdx.x;
  const int jg0 = ct * 64;

  const int tok = base + tid;
  const int r0 = t2row[2 * tok], r1 = t2row[2 * tok + 1];
  const float w0 = t2w[2 * tok], w1 = t2w[2 * tok + 1];

  fx4 acc[4][4] = {};
  const int wave = tid >> 6, l = tid & 63;
  const int l16 = l & 15, lhi = l >> 4;

  unsigned int bits = bmc[ct];
  while (bits) {
    const int kbx = __ffs(bits) - 1; bits &= bits - 1;
    const int d0 = kbx * 64;
    {   // stage A: combine two bf16 pair rows -> bf16 (swizzled ds_write)
      const ux4* s0 = (const ux4*)(yb + (size_t)r0 * DIM + d0);
      const ux4* s1 = (const ux4*)(yb + (size_t)r1 * DIM + d0);
      #pragma unroll
      for (int seg = 0; seg < 8; seg++) {
        ux4 v0 = s0[seg], v1 = s1[seg], o;
        #pragma unroll
        for (int j = 0; j < 4; j++) {
          float alo = __uint_as_float(v0[j] << 16);
          float ahi = __uint_as_float(v0[j] & 0xFFFF0000u);
          float blo = __uint_as_float(v1[j] << 16);
          float bhi = __uint_as_float(v1[j] & 0xFFFF0000u);
          o[j] = cvt_pk(w0 * alo + w1 * blo, w0 * ahi + w1 * bhi);
        }
        Ash[tid * 8 + (seg ^ (tid & 7))] = o;
      }
    }
    {   // stage B from cross_w (f32 reg-staged)
      const int kbt = tid >> 4, jb = tid & 15;
      const float* bp = cw + (size_t)(d0 + kbt * 4) * DIM + jg0 + jb * 4;
      fx4 r0v = *(const fx4*)bp;
      fx4 r1v = *(const fx4*)(bp + DIM);
      fx4 r2v = *(const fx4*)(bp + 2 * DIM);
      fx4 r3v = *(const fx4*)(bp + 3 * DIM);
      #pragma unroll
      for (int jj = 0; jj < 4; jj++) {
        ux2 val;
        val[0] = cvt_pk(r0v[jj], r1v[jj]);
        val[1] = cvt_pk(r2v[jj], r3v[jj]);
        const int col = jb * 4 + jj;
        Bsh[(col * 8 + ((kbt >> 1) ^ (col & 7))) * 2 + (kbt & 1)] = val;
      }
    }
    __syncthreads();
    #pragma unroll
    for (int ks = 0; ks < 2; ks++) {
      s8v a[4], b[4];
      const int seg = ks * 4 + lhi;
      #pragma unroll
      for (int m = 0; m < 4; m++) {
        const int row = wave * 64 + m * 16 + l16;
        V16 v; v.u = Ash[row * 8 + (seg ^ (row & 7))]; a[m] = v.s;
      }
      #pragma unroll
      for (int n = 0; n < 4; n++) {
        const int col = n * 16 + l16;
        V16 v; v.u = ((const ux4*)Bsh)[col * 8 + (seg ^ (col & 7))]; b[n] = v.s;
      }
      #pragma unroll
      for (int m = 0; m < 4; m++)
        #pragma unroll
        for (int n = 0; n < 4; n++)
          acc[m][n] = __builtin_amdgcn_mfma_f32_16x16x32_bf16(a[m], b[n], acc[m][n], 0, 0, 0);
    }
    __syncthreads();
  }

  #pragma unroll
  for (int m = 0; m < 4; m++)
    #pragma unroll
    for (int n = 0; n < 4; n++) {
      const int gcol = jg0 + n * 16 + l16;
      #pragma unroll
      for (int i = 0; i < 4; i++) {
        const int lrow = wave * 64 + m * 16 + lhi * 4 + i;
        const size_t idx = (size_t)(base + lrow) * DIM + gcol;
        out[idx] = acc[m][n][i] + x[idx] + cb[gcol];
      }
    }
}

// ---------------------------------------------------------------------------
extern "C" void kernel_launch(void* const* d_in, const int* in_sizes, int n_in,
                              void* d_out, int out_size, void* d_ws, size_t ws_size,
                              hipStream_t stream)
{
  (void)in_sizes; (void)n_in; (void)out_size; (void)ws_size;
  const float* x      = (const float*)d_in[0];
  const float* gate_w = (const float*)d_in[1];   // [2,16,1024]
  const float* temp   = (const float*)d_in[2];   // [2]
  const float* w1     = (const float*)d_in[3];   // [16,1024,4096]
  const float* b1     = (const float*)d_in[4];
  const float* w2     = (const float*)d_in[5];   // [16,4096,1024]
  const float* b2     = (const float*)d_in[6];
  const float* cw     = (const float*)d_in[7];   // [1024,1024]
  const float* cb     = (const float*)d_in[8];
  const void*  mask1  = d_in[9];
  const void*  mask2  = d_in[10];
  const void*  cmask  = d_in[11];
  float* out = (float*)d_out;
  char* ws = (char*)d_ws;

  size_t off = 0;
  auto walloc = [&](size_t b) { size_t r = off; off = (off + b + 255) & ~(size_t)255; return r; };
  size_t o_meta = walloc(4096);
  size_t o_bm1  = walloc(1024 * 4);
  size_t o_bm2  = walloc(256 * 8);
  size_t o_bmc  = walloc(64 * 4);
  size_t o_t2i  = walloc((size_t)NTOK * 2 * 4);
  size_t o_t2w  = walloc((size_t)NTOK * 2 * 4);
  size_t o_t2r  = walloc((size_t)NTOK * 2 * 4);
  size_t o_tok  = walloc((size_t)ROWS_CAP * 4);
  size_t o_xbf  = walloc((size_t)NTOK * DIM * 2);
  size_t o_y    = walloc((size_t)ROWS_CAP * DIM * 2);    // 40 MB (bf16)
  size_t o_hc   = walloc((size_t)ROWS_CAP * HID * 2);    // 168 MB

  int*                meta = (int*)(ws + o_meta);
  unsigned int*       bm1  = (unsigned int*)(ws + o_bm1);
  unsigned long long* bm2  = (unsigned long long*)(ws + o_bm2);
  unsigned int*       bmc  = (unsigned int*)(ws + o_bmc);
  int*                t2i  = (int*)(ws + o_t2i);
  float*              t2w  = (float*)(ws + o_t2w);
  int*                t2r  = (int*)(ws + o_t2r);
  int*                tok  = (int*)(ws + o_tok);
  unsigned short*     xbf  = (unsigned short*)(ws + o_xbf);
  unsigned short*     yb   = (unsigned short*)(ws + o_y);
  unsigned short*     hc   = (unsigned short*)(ws + o_hc);

  hipMemsetAsync(ws + o_meta, 0, 4096, stream);
  hipMemsetAsync(ws + o_tok, 0xFF, (size_t)ROWS_CAP * 4, stream);  // -1

  k_route  <<<NTOK / 16, 256, 0, stream>>>(x, gate_w + (size_t)1 * NEXP * DIM, temp + 1,
                                           (const unsigned int*)mask1, t2i, t2w, meta);
  k_xcast  <<<(NTOK * DIM / 8) / 256, 256, 0, stream>>>(x, xbf);
  k_bmask  <<<4, 256, 0, stream>>>(mask1, mask2, cmask, meta, bm1, bm2, bmc);
  k_offsets<<<1, 64, 0, stream>>>(meta);
  k_assign <<<NTOK / 256, 256, 0, stream>>>(t2i, t2w, meta, tok, t2r);

  const int NRT = ROWS_CAP / BM;   // 80
  k_gemm1<<<NRT * 64, 256, 0, stream>>>(xbf, w1, b1, bm1, meta, tok, hc);
  k_gemm2<<<NRT * 16, 256, 0, stream>>>(hc, w2, b2, bm2, meta, yb);
  k_cross<<<(NTOK / BM) * 16, 256, 0, stream>>>(yb, x, cw, cb, bmc, t2r, t2w, out);
}

// Round 10
// 434.486 us; speedup vs baseline: 1.7854x; 1.0603x over previous
//
#include <hip/hip_runtime.h>

// ---------------------------------------------------------------------------
// HierarchicalSparseLayer: top-2 MoE with block-sparse (64x64) masked weights
// B=8192 tokens, D=1024, H=4096, E=16 experts, K=2, + block-sparse cross proj.
// R10: R9 core + h stored FP8 e4m3 (x8 scale), gemm2 on fp8 MFMA (w2 -> fp8
//      x16 in B-staging, acc/128 in epilogue), xcast folded into k_route,
//      gemm2 at 40 KB LDS -> 3 blocks/CU.
// ---------------------------------------------------------------------------

#define NTOK 8192
#define DIM  1024
#define HID  4096
#define NEXP 16
#define BM   256
#define ROWS_CAP (NTOK*2 + NEXP*256)   // 20480

typedef __attribute__((ext_vector_type(4))) float fx4;
typedef __attribute__((ext_vector_type(4))) unsigned int ux4;
typedef __attribute__((ext_vector_type(2))) unsigned int ux2;
typedef __attribute__((ext_vector_type(8))) short s8v;
union V16 { ux4 u; s8v s; };

__device__ __forceinline__ unsigned int f2bf(float f) {
  unsigned int u = __float_as_uint(f);
  return (u + 0x7fffu + ((u >> 16) & 1u)) >> 16;   // RNE, inputs finite
}

__device__ __forceinline__ unsigned int cvt_pk(float lo, float hi) {
  unsigned int r;
  asm("v_cvt_pk_bf16_f32 %0, %1, %2" : "=v"(r) : "v"(lo), "v"(hi));
  return r;
}

__device__ __forceinline__ unsigned int f2fp8(float v) {
  return (unsigned int)__builtin_amdgcn_cvt_pk_fp8_f32(v, v, 0, false) & 0xFFu;
}

// Mask dtype detected at runtime: flag 0=u8, 1=i32, 2=f32
__device__ __forceinline__ bool mask_at(const void* m, int flag, size_t idx) {
  if (flag == 0) return ((const unsigned char*)m)[idx] != 0;
  if (flag == 1) return ((const int*)m)[idx] != 0;
  return ((const float*)m)[idx] != 0.0f;
}

__device__ __forceinline__ int flag_of(int ev) {
  return (ev & 2) ? 2 : ((ev & 1) ? 0 : 1);
}

// XCD-aware swizzle (grid % 8 == 0)
__device__ __forceinline__ int xcd_swz() {
  const int b = blockIdx.x, cpx = gridDim.x >> 3;
  return (b & 7) * cpx + (b >> 3);
}

// --------------------------- routing (+ detect + xcast) ---------------------
// meta: [1]=detect bits [8..23]=counts [32..47]=offsets [48]=total
//       [64..79]=slot counters [96..175]=expert_of_rt
__global__ void k_route(const float* __restrict__ x,
                        const float* __restrict__ gw,    // gate_w[-1] [16,1024]
                        const float* __restrict__ temp,
                        const unsigned int* __restrict__ m1raw,
                        int* __restrict__ top2i, float* __restrict__ top2w,
                        int* __restrict__ meta, unsigned short* __restrict__ xb)
{
  if (blockIdx.x < 64) {     // fold k_detect
    int bits = 0;
    size_t base = (size_t)blockIdx.x * 4096 + threadIdx.x;
    for (int j = 0; j < 16; j++) {
      unsigned int v = m1raw[base + 256 * j];
      if (v == 0x3f800000u) bits |= 2;
      else if (v > 1u)      bits |= 1;
    }
    if (bits) atomicOr(&meta[1], bits);
  }

  __shared__ float gwsh[NEXP * DIM];
  for (int i = threadIdx.x; i < NEXP * DIM; i += 256) gwsh[i] = gw[i];
  __syncthreads();

  const int wv = threadIdx.x >> 6;
  const int l = threadIdx.x & 63;
  #pragma unroll
  for (int tt = 0; tt < 4; tt++) {
    const int t = blockIdx.x * 16 + wv * 4 + tt;
    const float* xr = x + (size_t)t * DIM;
    float xv[16];
    #pragma unroll
    for (int j = 0; j < 16; j++) xv[j] = xr[l + 64 * j];
    float logit[16];
    #pragma unroll
    for (int e = 0; e < 16; e++) {
      const float* g = gwsh + e * DIM;
      float s = 0.f;
      #pragma unroll
      for (int j = 0; j < 16; j++) s += xv[j] * g[l + 64 * j];
      #pragma unroll
      for (int o = 32; o >= 1; o >>= 1) s += __shfl_xor(s, o);
      logit[e] = s;
    }
    if (l == 0) {
      const float tinv = 1.0f / temp[0];
      int i0 = 0; float v0 = logit[0] * tinv;
      #pragma unroll
      for (int e = 1; e < 16; e++) { float v = logit[e] * tinv; if (v > v0) { v0 = v; i0 = e; } }
      int i1 = -1; float v1 = 0.f; bool first = true;
      #pragma unroll
      for (int e = 0; e < 16; e++) {
        if (e == i0) continue;
        float v = logit[e] * tinv;
        if (first || v > v1) { v1 = v; i1 = e; first = false; }
      }
      float ex = __expf(v1 - v0);
      float den = 1.0f + ex;
      top2i[2 * t] = i0; top2i[2 * t + 1] = i1;
      top2w[2 * t] = 1.0f / den; top2w[2 * t + 1] = ex / den;
      atomicAdd(&meta[8 + i0], 1);
      atomicAdd(&meta[8 + i1], 1);
    }
  }

  // pack this block's 16 tokens to bf16 (slab is L1/L2-hot from routing reads)
  {
    const size_t be = (size_t)blockIdx.x * 16 * DIM;
    const fx4* src = (const fx4*)(x + be);
    ux4* dst = (ux4*)(xb + be);
    #pragma unroll
    for (int i = 0; i < 8; i++) {
      const int idx = i * 256 + threadIdx.x;
      fx4 a = src[2 * idx], b = src[2 * idx + 1];
      ux4 o;
      o[0] = cvt_pk(a[0], a[1]);
      o[1] = cvt_pk(a[2], a[3]);
      o[2] = cvt_pk(b[0], b[1]);
      o[3] = cvt_pk(b[2], b[3]);
      dst[idx] = o;
    }
  }
}

__global__ void k_offsets(int* __restrict__ meta) {
  if (threadIdx.x == 0 && blockIdx.x == 0) {
    int o = 0;
    for (int e = 0; e < 16; e++) { meta[32 + e] = o; o += (meta[8 + e] + 255) & ~255; }
    meta[48] = o;
    for (int rt = 0; rt < ROWS_CAP / BM; rt++) {
      const int base = rt * BM;
      int e = 0;
      for (int i = 1; i < 16; i++) if (meta[32 + i] <= base) e = i;
      meta[96 + rt] = e;
    }
  }
}

__global__ void k_assign(const int* __restrict__ top2i,
                         const float* __restrict__ top2w,
                         int* __restrict__ meta, int* __restrict__ tok_of_row,
                         int* __restrict__ t2row)
{
  int t = blockIdx.x * 256 + threadIdx.x;
  if (t >= NTOK) return;
  #pragma unroll
  for (int k = 0; k < 2; k++) {
    int e = top2i[2 * t + k];
    int slot = atomicAdd(&meta[64 + e], 1);
    int row = meta[32 + e] + slot;
    tok_of_row[row] = t;
    t2row[2 * t + k] = row;
  }
}

// --------------------------- block-mask bitmaps ------------------------------
__global__ void k_bmask(const void* __restrict__ m1, const void* __restrict__ m2,
                        const void* __restrict__ mc, const int* __restrict__ meta,
                        unsigned int* __restrict__ bm1,
                        unsigned long long* __restrict__ bm2,
                        unsigned int* __restrict__ bmc)
{
  const int flag = flag_of(meta[1]);
  const int id = blockIdx.x * 256 + threadIdx.x;
  if (id < 1024) {
    int e = id >> 6, ct = id & 63;
    unsigned int bits = 0;
    size_t basei = (size_t)e * DIM * HID + (size_t)ct * 64;
    for (int db = 0; db < 16; db++)
      if (mask_at(m1, flag, basei + (size_t)db * 64 * HID)) bits |= 1u << db;
    bm1[id] = bits;
  }
  if (id < 256) {
    int e = id >> 4, ct = id & 15;
    unsigned long long bits = 0;
    size_t basei = (size_t)e * HID * DIM + (size_t)ct * 64;
    for (int db = 0; db < 64; db++)
      if (mask_at(m2, flag, basei + (size_t)db * 64 * DIM)) bits |= 1ull << db;
    bm2[id] = bits;
  }
  if (id < 16) {
    unsigned int bits = 0;
    for (int db = 0; db < 16; db++)
      if (mask_at(mc, flag, (size_t)db * 64 * DIM + (size_t)id * 64)) bits |= 1u << db;
    bmc[id] = bits;
  }
}

// --------------------------- GEMM 1: h = fp8(8*silu(x @ w1m + b1)) ----------
__global__ __launch_bounds__(256, 2)
void k_gemm1(const unsigned short* __restrict__ xb,
             const float* __restrict__ w1, const float* __restrict__ b1,
             const unsigned int* __restrict__ bm1,
             const int* __restrict__ meta, const int* __restrict__ tok_of_row,
             unsigned char* __restrict__ h8)
{
  __shared__ ux4 Ash[2][2048];                  // 2 x 32 KB (256 rows x 64 k)
  __shared__ __align__(16) ux2 Bsh[2][1024];    // 2 x 8 KB

  const int bid = xcd_swz();
  const int rt = bid >> 6, ct = bid & 63;       // NCT = 64
  const int base = rt * BM;
  if (base >= meta[48]) return;
  const int e = meta[96 + rt];

  const int tid = threadIdx.x;
  const int wv = tid >> 6;
  const int jg0 = ct * 64;
  unsigned int bits = bm1[e * 64 + ct];

  const unsigned int sseg = (unsigned int)(((tid & 7) ^ ((tid >> 3) & 7)) * 16);
  unsigned int aoff[8];
  #pragma unroll
  for (int i = 0; i < 8; i++) {
    int tok = tok_of_row[base + i * 32 + (tid >> 3)];
    if (tok < 0) tok = 0;                       // pad rows: finite garbage, unused
    aoff[i] = (unsigned int)tok * (DIM * 2) + sseg;
  }

  const int l = tid & 63, l16 = l & 15, lhi = l >> 4;
  const int kb = tid >> 4, jb = tid & 15;

  fx4 acc[4][4] = {};

  auto STAGE_A = [&](int b, int d0) {
    const char* gp = (const char*)xb + (d0 << 1);
    #pragma unroll
    for (int i = 0; i < 8; i++)
      __builtin_amdgcn_global_load_lds(
        (const __attribute__((address_space(1))) unsigned int*)(gp + aoff[i]),
        (__attribute__((address_space(3))) unsigned int*)&Ash[b][i * 256 + wv * 64],
        16, 0, 0);
  };
  auto LOAD_B = [&](fx4* r, int d0) {
    const float* bp = w1 + ((size_t)e * DIM + d0 + kb * 4) * HID + jg0 + jb * 4;
    r[0] = *(const fx4*)bp;
    r[1] = *(const fx4*)(bp + HID);
    r[2] = *(const fx4*)(bp + 2 * HID);
    r[3] = *(const fx4*)(bp + 3 * HID);
  };
  auto WRITE_B = [&](int b, const fx4* r) {
    #pragma unroll
    for (int jj = 0; jj < 4; jj++) {
      ux2 val;
      val[0] = cvt_pk(r[0][jj], r[1][jj]);
      val[1] = cvt_pk(r[2][jj], r[3][jj]);
      const int col = jb * 4 + jj;
      Bsh[b][(col * 8 + ((kb >> 1) ^ (col & 7))) * 2 + (kb & 1)] = val;
    }
  };
  auto COMPUTE = [&](int b) {
    #pragma unroll
    for (int ks = 0; ks < 2; ks++) {
      s8v a[4], bb[4];
      const int seg = ks * 4 + lhi;
      #pragma unroll
      for (int m = 0; m < 4; m++) {
        const int row = wv * 64 + m * 16 + l16;
        V16 v; v.u = Ash[b][row * 8 + (seg ^ (row & 7))]; a[m] = v.s;
      }
      #pragma unroll
      for (int n = 0; n < 4; n++) {
        const int col = n * 16 + l16;
        V16 v; v.u = ((const ux4*)&Bsh[b][0])[col * 8 + (seg ^ (col & 7))]; bb[n] = v.s;
      }
      #pragma unroll
      for (int m = 0; m < 4; m++)
        #pragma unroll
        for (int n = 0; n < 4; n++)
          acc[m][n] = __builtin_amdgcn_mfma_f32_16x16x32_bf16(a[m], bb[n], acc[m][n], 0, 0, 0);
    }
  };

  if (bits) {
    int d0 = (__ffs(bits) - 1) << 6; bits &= bits - 1;
    {
      fx4 br[4];
      STAGE_A(0, d0);
      LOAD_B(br, d0);
      WRITE_B(0, br);
    }
    __syncthreads();
    int cur = 0;
    for (;;) {
      int nd0 = -1;
      fx4 br2[4];
      if (bits) { nd0 = (__ffs(bits) - 1) << 6; bits &= bits - 1; }
      if (nd0 >= 0) { STAGE_A(cur ^ 1, nd0); LOAD_B(br2, nd0); }
      COMPUTE(cur);
      if (nd0 >= 0) WRITE_B(cur ^ 1, br2);
      __syncthreads();
      cur ^= 1;
      if (nd0 < 0) break;
    }
  }

  // epilogue: h = fp8(8 * silu(acc + b1)) -> LDS byte tile -> 16B dump
  unsigned char* hs = (unsigned char*)&Ash[0][0];   // 256 x 64 B = 16 KB
  __syncthreads();
  #pragma unroll
  for (int m = 0; m < 4; m++)
    #pragma unroll
    for (int n = 0; n < 4; n++) {
      const int gcol = jg0 + n * 16 + l16;
      const float bbv = b1[e * HID + gcol];
      #pragma unroll
      for (int i = 0; i < 4; i++) {
        const int row = wv * 64 + m * 16 + lhi * 4 + i;
        float v = acc[m][n][i] + bbv;
        float hval = v / (1.0f + __expf(-v));
        hs[row * 64 + n * 16 + l16] = (unsigned char)f2fp8(hval * 8.0f);
      }
    }
  __syncthreads();
  {
    const ux4* s = (const ux4*)hs;
    #pragma unroll
    for (int j = 0; j < 4; j++) {
      const int c2 = j * 256 + tid;
      const int row = c2 >> 2;
      *(ux4*)(h8 + (size_t)(base + row) * HID + ct * 64 + (c2 & 3) * 16) = s[c2];
    }
  }
}

// --------------------------- GEMM 2: y = bf16(h8 @ w2fp8 / 128 + b2) --------
// fp8 MFMA. A: h8 via global_load_lds, 4 chunks/row, chunk swizzle
// c ^ ((row>>1)&3) pre-applied on source. B: w2 f32 -> fp8 x16 in LDS.
__global__ __launch_bounds__(256, 3)
void k_gemm2(const unsigned char* __restrict__ h8,
             const float* __restrict__ w2, const float* __restrict__ b2,
             const unsigned long long* __restrict__ bm2,
             const int* __restrict__ meta, unsigned short* __restrict__ yb)
{
  __shared__ ux4 Ash[2][1024];                       // 2 x 16 KB (256 rows x 64 B)
  __shared__ __align__(16) unsigned int Bsh[2][1024]; // 2 x 4 KB (64 cols x 64 B)

  const int bid = xcd_swz();
  const int rt = bid >> 4, ct = bid & 15;       // NCT = 16
  const int base = rt * BM;
  if (base >= meta[48]) return;
  const int e = meta[96 + rt];

  const int tid = threadIdx.x;
  const int wv = tid >> 6;
  const int jg0 = ct * 64;
  unsigned long long bits = bm2[e * 16 + ct];

  // A source offsets: LDS chunk ci = i*256+tid; row = i*64 + (tid>>2);
  // stored data chunk = (tid&3) ^ ((row>>1)&3) with (row>>1)&3 = (tid>>3)&3
  const unsigned int sw = (unsigned int)((tid & 3) ^ ((tid >> 3) & 3));
  unsigned int aoff[4];
  #pragma unroll
  for (int i = 0; i < 4; i++)
    aoff[i] = (unsigned int)(base + i * 64 + (tid >> 2)) * (unsigned int)HID + sw * 16;

  const int l = tid & 63, l16 = l & 15, lhi = l >> 4;
  const int kb = tid >> 4, jb = tid & 15;

  fx4 acc[4][4] = {};

  auto STAGE_A = [&](int b, int d0) {
    const char* gp = (const char*)h8 + d0;
    #pragma unroll
    for (int i = 0; i < 4; i++)
      __builtin_amdgcn_global_load_lds(
        (const __attribute__((address_space(1))) unsigned int*)(gp + aoff[i]),
        (__attribute__((address_space(3))) unsigned int*)&Ash[b][i * 256 + wv * 64],
        16, 0, 0);
  };
  auto LOAD_B = [&](fx4* r, int d0) {
    const float* bp = w2 + ((size_t)e * HID + d0 + kb * 4) * DIM + jg0 + jb * 4;
    r[0] = *(const fx4*)bp;
    r[1] = *(const fx4*)(bp + DIM);
    r[2] = *(const fx4*)(bp + 2 * DIM);
    r[3] = *(const fx4*)(bp + 3 * DIM);
  };
  auto WRITE_B = [&](int b, const fx4* r) {
    #pragma unroll
    for (int jj = 0; jj < 4; jj++) {
      const int col = jb * 4 + jj;
      unsigned int u = (unsigned int)__builtin_amdgcn_cvt_pk_fp8_f32(
                          r[0][jj] * 16.0f, r[1][jj] * 16.0f, 0, false);
      u = (unsigned int)__builtin_amdgcn_cvt_pk_fp8_f32(
                          r[2][jj] * 16.0f, r[3][jj] * 16.0f, (int)u, true);
      // k-bytes kb*4..+3 of col: chunk = kb>>2 (swizzled), internal (kb&3)*4
      Bsh[b][col * 16 + (((kb >> 2) ^ ((col >> 1) & 3)) << 2) + (kb & 3)] = u;
    }
  };
  auto COMPUTE = [&](int b) {
    const char* Ab = (const char*)&Ash[b][0];
    const char* Bb = (const char*)&Bsh[b][0];
    #pragma unroll
    for (int ks = 0; ks < 2; ks++) {
      const int c = ks * 2 + (lhi >> 1);
      const int sub = (lhi & 1) << 3;
      long long a[4], bb[4];
      #pragma unroll
      for (int m = 0; m < 4; m++) {
        const int row = wv * 64 + m * 16 + l16;
        a[m] = *(const long long*)(Ab + row * 64 + ((c ^ ((row >> 1) & 3)) << 4) + sub);
      }
      #pragma unroll
      for (int n = 0; n < 4; n++) {
        const int col = n * 16 + l16;
        bb[n] = *(const long long*)(Bb + col * 64 + ((c ^ ((col >> 1) & 3)) << 4) + sub);
      }
      #pragma unroll
      for (int m = 0; m < 4; m++)
        #pragma unroll
        for (int n = 0; n < 4; n++)
          acc[m][n] = __builtin_amdgcn_mfma_f32_16x16x32_fp8_fp8(a[m], bb[n], acc[m][n], 0, 0, 0);
    }
  };

  if (bits) {
    int d0 = (__ffsll(bits) - 1) << 6; bits &= bits - 1;
    {
      fx4 br[4];
      STAGE_A(0, d0);
      LOAD_B(br, d0);
      WRITE_B(0, br);
    }
    __syncthreads();
    int cur = 0;
    for (;;) {
      int nd0 = -1;
      fx4 br2[4];
      if (bits) { nd0 = (__ffsll(bits) - 1) << 6; bits &= bits - 1; }
      if (nd0 >= 0) { STAGE_A(cur ^ 1, nd0); LOAD_B(br2, nd0); }
      COMPUTE(cur);
      if (nd0 >= 0) WRITE_B(cur ^ 1, br2);
      __syncthreads();
      cur ^= 1;
      if (nd0 < 0) break;
    }
  }

  // epilogue: y = bf16(acc/128 + b2), restaged via LDS (Ash[0]+Ash[1] = 32 KB)
  unsigned short* hs = (unsigned short*)&Ash[0][0];
  __syncthreads();
  #pragma unroll
  for (int m = 0; m < 4; m++)
    #pragma unroll
    for (int n = 0; n < 4; n++) {
      const int gcol = jg0 + n * 16 + l16;
      const float bbv = b2[e * DIM + gcol];
      #pragma unroll
      for (int i = 0; i < 4; i++) {
        const int row = wv * 64 + m * 16 + lhi * 4 + i;
        hs[row * 64 + n * 16 + l16] =
            (unsigned short)f2bf(acc[m][n][i] * 0.0078125f + bbv);
      }
    }
  __syncthreads();
  {
    const ux4* s = (const ux4*)hs;
    #pragma unroll
    for (int j = 0; j < 8; j++) {
      const int c2 = j * 256 + tid;
      const int row = c2 >> 3;
      *(ux4*)(yb + (size_t)(base + row) * DIM + ct * 64 + (c2 & 7) * 8) = s[c2];
    }
  }
}

// --------------------------- cross: out = x + eo @ cwm + cb -----------------
// eo rows formed on the fly from bf16 y: eo[tok] = w0*y[r0] + w1*y[r1]
__global__ __launch_bounds__(256, 2)
void k_cross(const unsigned short* __restrict__ yb, const float* __restrict__ x,
             const float* __restrict__ cw, const float* __restrict__ cb,
             const unsigned int* __restrict__ bmc,
             const int* __restrict__ t2row, const float* __restrict__ t2w,
             float* __restrict__ out)
{
  __shared__ ux4 Ash[2048];
  __shared__ __align__(16) ux2 Bsh[1024];

  const int bid = xcd_swz();
  const int rt = bid >> 4, ct = bid & 15;
  const int base = rt * BM;
  const int tid = threadIdx.x;
  const int jg0 = ct * 64;

  const int tok = base + tid;
  const int r0 = t2row[2 * tok], r1 = t2row[2 * tok + 1];
  const float w0 = t2w[2 * tok], w1 = t2w[2 * tok + 1];

  fx4 acc[4][4] = {};
  const int wave = tid >> 6, l = tid & 63;
  const int l16 = l & 15, lhi = l >> 4;

  unsigned int bits = bmc[ct];
  while (bits) {
    const int kbx = __ffs(bits) - 1; bits &= bits - 1;
    const int d0 = kbx * 64;
    {   // stage A: combine two bf16 pair rows -> bf16 (swizzled ds_write)
      const ux4* s0 = (const ux4*)(yb + (size_t)r0 * DIM + d0);
      const ux4* s1 = (const ux4*)(yb + (size_t)r1 * DIM + d0);
      #pragma unroll
      for (int seg = 0; seg < 8; seg++) {
        ux4 v0 = s0[seg], v1 = s1[seg], o;
        #pragma unroll
        for (int j = 0; j < 4; j++) {
          float alo = __uint_as_float(v0[j] << 16);
          float ahi = __uint_as_float(v0[j] & 0xFFFF0000u);
          float blo = __uint_as_float(v1[j] << 16);
          float bhi = __uint_as_float(v1[j] & 0xFFFF0000u);
          o[j] = cvt_pk(w0 * alo + w1 * blo, w0 * ahi + w1 * bhi);
        }
        Ash[tid * 8 + (seg ^ (tid & 7))] = o;
      }
    }
    {   // stage B from cross_w (f32 reg-staged)
      const int kbt = tid >> 4, jb = tid & 15;
      const float* bp = cw + (size_t)(d0 + kbt * 4) * DIM + jg0 + jb * 4;
      fx4 r0v = *(const fx4*)bp;
      fx4 r1v = *(const fx4*)(bp + DIM);
      fx4 r2v = *(const fx4*)(bp + 2 * DIM);
      fx4 r3v = *(const fx4*)(bp + 3 * DIM);
      #pragma unroll
      for (int jj = 0; jj < 4; jj++) {
        ux2 val;
        val[0] = cvt_pk(r0v[jj], r1v[jj]);
        val[1] = cvt_pk(r2v[jj], r3v[jj]);
        const int col = jb * 4 + jj;
        Bsh[(col * 8 + ((kbt >> 1) ^ (col & 7))) * 2 + (kbt & 1)] = val;
      }
    }
    __syncthreads();
    #pragma unroll
    for (int ks = 0; ks < 2; ks++) {
      s8v a[4], b[4];
      const int seg = ks * 4 + lhi;
      #pragma unroll
      for (int m = 0; m < 4; m++) {
        const int row = wave * 64 + m * 16 + l16;
        V16 v; v.u = Ash[row * 8 + (seg ^ (row & 7))]; a[m] = v.s;
      }
      #pragma unroll
      for (int n = 0; n < 4; n++) {
        const int col = n * 16 + l16;
        V16 v; v.u = ((const ux4*)Bsh)[col * 8 + (seg ^ (col & 7))]; b[n] = v.s;
      }
      #pragma unroll
      for (int m = 0; m < 4; m++)
        #pragma unroll
        for (int n = 0; n < 4; n++)
          acc[m][n] = __builtin_amdgcn_mfma_f32_16x16x32_bf16(a[m], b[n], acc[m][n], 0, 0, 0);
    }
    __syncthreads();
  }

  #pragma unroll
  for (int m = 0; m < 4; m++)
    #pragma unroll
    for (int n = 0; n < 4; n++) {
      const int gcol = jg0 + n * 16 + l16;
      #pragma unroll
      for (int i = 0; i < 4; i++) {
        const int lrow = wave * 64 + m * 16 + lhi * 4 + i;
        const size_t idx = (size_t)(base + lrow) * DIM + gcol;
        out[idx] = acc[m][n][i] + x[idx] + cb[gcol];
      }
    }
}

// ---------------------------------------------------------------------------
extern "C" void kernel_launch(void* const* d_in, const int* in_sizes, int n_in,
                              void* d_out, int out_size, void* d_ws, size_t ws_size,
                              hipStream_t stream)
{
  (void)in_sizes; (void)n_in; (void)out_size; (void)ws_size;
  const float* x      = (const float*)d_in[0];
  const float* gate_w = (const float*)d_in[1];   // [2,16,1024]
  const float* temp   = (const float*)d_in[2];   // [2]
  const float* w1     = (const float*)d_in[3];   // [16,1024,4096]
  const float* b1     = (const float*)d_in[4];
  const float* w2     = (const float*)d_in[5];   // [16,4096,1024]
  const float* b2     = (const float*)d_in[6];
  const float* cw     = (const float*)d_in[7];   // [1024,1024]
  const float* cb     = (const float*)d_in[8];
  const void*  mask1  = d_in[9];
  const void*  mask2  = d_in[10];
  const void*  cmask  = d_in[11];
  float* out = (float*)d_out;
  char* ws = (char*)d_ws;

  size_t off = 0;
  auto walloc = [&](size_t b) { size_t r = off; off = (off + b + 255) & ~(size_t)255; return r; };
  size_t o_meta = walloc(4096);
  size_t o_bm1  = walloc(1024 * 4);
  size_t o_bm2  = walloc(256 * 8);
  size_t o_bmc  = walloc(64 * 4);
  size_t o_t2i  = walloc((size_t)NTOK * 2 * 4);
  size_t o_t2w  = walloc((size_t)NTOK * 2 * 4);
  size_t o_t2r  = walloc((size_t)NTOK * 2 * 4);
  size_t o_tok  = walloc((size_t)ROWS_CAP * 4);
  size_t o_xbf  = walloc((size_t)NTOK * DIM * 2);
  size_t o_y    = walloc((size_t)ROWS_CAP * DIM * 2);    // 40 MB (bf16)
  size_t o_hc   = walloc((size_t)ROWS_CAP * HID);        // 84 MB (fp8)

  int*                meta = (int*)(ws + o_meta);
  unsigned int*       bm1  = (unsigned int*)(ws + o_bm1);
  unsigned long long* bm2  = (unsigned long long*)(ws + o_bm2);
  unsigned int*       bmc  = (unsigned int*)(ws + o_bmc);
  int*                t2i  = (int*)(ws + o_t2i);
  float*              t2w  = (float*)(ws + o_t2w);
  int*                t2r  = (int*)(ws + o_t2r);
  int*                tok  = (int*)(ws + o_tok);
  unsigned short*     xbf  = (unsigned short*)(ws + o_xbf);
  unsigned short*     yb   = (unsigned short*)(ws + o_y);
  unsigned char*      h8   = (unsigned char*)(ws + o_hc);

  hipMemsetAsync(ws + o_meta, 0, 4096, stream);
  hipMemsetAsync(ws + o_tok, 0xFF, (size_t)ROWS_CAP * 4, stream);  // -1

  k_route  <<<NTOK / 16, 256, 0, stream>>>(x, gate_w + (size_t)1 * NEXP * DIM, temp + 1,
                                           (const unsigned int*)mask1, t2i, t2w, meta, xbf);
  k_bmask  <<<4, 256, 0, stream>>>(mask1, mask2, cmask, meta, bm1, bm2, bmc);
  k_offsets<<<1, 64, 0, stream>>>(meta);
  k_assign <<<NTOK / 256, 256, 0, stream>>>(t2i, t2w, meta, tok, t2r);

  const int NRT = ROWS_CAP / BM;   // 80
  k_gemm1<<<NRT * 64, 256, 0, stream>>>(xbf, w1, b1, bm1, meta, tok, h8);
  k_gemm2<<<NRT * 16, 256, 0, stream>>>(h8, w2, b2, bm2, meta, yb);
  k_cross<<<(NTOK / BM) * 16, 256, 0, stream>>>(yb, x, cw, cb, bmc, t2r, t2w, out);
}

// Round 11
// 374.743 us; speedup vs baseline: 2.0701x; 1.1594x over previous
//
#include <hip/hip_runtime.h>

// ---------------------------------------------------------------------------
// HierarchicalSparseLayer: top-2 MoE with block-sparse (64x64) masked weights
// B=8192 tokens, D=1024, H=4096, E=16 experts, K=2, + block-sparse cross proj.
// R11: R10 core (fp8 h, fp8-MFMA gemm2, bf16 y, XCD swizzle, DMA-A dbuf,
//      reg-staged B) + k_bmask eliminated (per-block ballot mask reads) +
//      route at 32 tokens/block (256 blocks).
// ---------------------------------------------------------------------------

#define NTOK 8192
#define DIM  1024
#define HID  4096
#define NEXP 16
#define BM   256
#define ROWS_CAP (NTOK*2 + NEXP*256)   // 20480

typedef __attribute__((ext_vector_type(4))) float fx4;
typedef __attribute__((ext_vector_type(4))) unsigned int ux4;
typedef __attribute__((ext_vector_type(2))) unsigned int ux2;
typedef __attribute__((ext_vector_type(8))) short s8v;
union V16 { ux4 u; s8v s; };

__device__ __forceinline__ unsigned int f2bf(float f) {
  unsigned int u = __float_as_uint(f);
  return (u + 0x7fffu + ((u >> 16) & 1u)) >> 16;   // RNE, inputs finite
}

__device__ __forceinline__ unsigned int cvt_pk(float lo, float hi) {
  unsigned int r;
  asm("v_cvt_pk_bf16_f32 %0, %1, %2" : "=v"(r) : "v"(lo), "v"(hi));
  return r;
}

__device__ __forceinline__ unsigned int f2fp8(float v) {
  return (unsigned int)__builtin_amdgcn_cvt_pk_fp8_f32(v, v, 0, false) & 0xFFu;
}

// Mask dtype detected at runtime: flag 0=u8, 1=i32, 2=f32
__device__ __forceinline__ bool mask_at(const void* m, int flag, size_t idx) {
  if (flag == 0) return ((const unsigned char*)m)[idx] != 0;
  if (flag == 1) return ((const int*)m)[idx] != 0;
  return ((const float*)m)[idx] != 0.0f;
}

__device__ __forceinline__ int flag_of(int ev) {
  return (ev & 2) ? 2 : ((ev & 1) ? 0 : 1);
}

// XCD-aware swizzle (grid % 8 == 0)
__device__ __forceinline__ int xcd_swz() {
  const int b = blockIdx.x, cpx = gridDim.x >> 3;
  return (b & 7) * cpx + (b >> 3);
}

// --------------------------- routing (+ detect + xcast) ---------------------
// meta: [1]=detect bits [8..23]=counts [32..47]=offsets [48]=total
//       [64..79]=slot counters [96..175]=expert_of_rt
__global__ void k_route(const float* __restrict__ x,
                        const float* __restrict__ gw,    // gate_w[-1] [16,1024]
                        const float* __restrict__ temp,
                        const unsigned int* __restrict__ m1raw,
                        int* __restrict__ top2i, float* __restrict__ top2w,
                        int* __restrict__ meta, unsigned short* __restrict__ xb)
{
  if (blockIdx.x < 64) {     // fold k_detect
    int bits = 0;
    size_t base = (size_t)blockIdx.x * 4096 + threadIdx.x;
    for (int j = 0; j < 16; j++) {
      unsigned int v = m1raw[base + 256 * j];
      if (v == 0x3f800000u) bits |= 2;
      else if (v > 1u)      bits |= 1;
    }
    if (bits) atomicOr(&meta[1], bits);
  }

  __shared__ float gwsh[NEXP * DIM];
  for (int i = threadIdx.x; i < NEXP * DIM; i += 256) gwsh[i] = gw[i];
  __syncthreads();

  const int wv = threadIdx.x >> 6;
  const int l = threadIdx.x & 63;
  #pragma unroll
  for (int tt = 0; tt < 8; tt++) {
    const int t = blockIdx.x * 32 + wv * 8 + tt;
    const float* xr = x + (size_t)t * DIM;
    float xv[16];
    #pragma unroll
    for (int j = 0; j < 16; j++) xv[j] = xr[l + 64 * j];
    float logit[16];
    #pragma unroll
    for (int e = 0; e < 16; e++) {
      const float* g = gwsh + e * DIM;
      float s = 0.f;
      #pragma unroll
      for (int j = 0; j < 16; j++) s += xv[j] * g[l + 64 * j];
      #pragma unroll
      for (int o = 32; o >= 1; o >>= 1) s += __shfl_xor(s, o);
      logit[e] = s;
    }
    if (l == 0) {
      const float tinv = 1.0f / temp[0];
      int i0 = 0; float v0 = logit[0] * tinv;
      #pragma unroll
      for (int e = 1; e < 16; e++) { float v = logit[e] * tinv; if (v > v0) { v0 = v; i0 = e; } }
      int i1 = -1; float v1 = 0.f; bool first = true;
      #pragma unroll
      for (int e = 0; e < 16; e++) {
        if (e == i0) continue;
        float v = logit[e] * tinv;
        if (first || v > v1) { v1 = v; i1 = e; first = false; }
      }
      float ex = __expf(v1 - v0);
      float den = 1.0f + ex;
      top2i[2 * t] = i0; top2i[2 * t + 1] = i1;
      top2w[2 * t] = 1.0f / den; top2w[2 * t + 1] = ex / den;
      atomicAdd(&meta[8 + i0], 1);
      atomicAdd(&meta[8 + i1], 1);
    }
  }

  // pack this block's 32 tokens to bf16 (slab is L1/L2-hot from routing reads)
  {
    const size_t be = (size_t)blockIdx.x * 32 * DIM;
    const fx4* src = (const fx4*)(x + be);
    ux4* dst = (ux4*)(xb + be);
    #pragma unroll
    for (int i = 0; i < 16; i++) {
      const int idx = i * 256 + threadIdx.x;
      fx4 a = src[2 * idx], b = src[2 * idx + 1];
      ux4 o;
      o[0] = cvt_pk(a[0], a[1]);
      o[1] = cvt_pk(a[2], a[3]);
      o[2] = cvt_pk(b[0], b[1]);
      o[3] = cvt_pk(b[2], b[3]);
      dst[idx] = o;
    }
  }
}

__global__ void k_offsets(int* __restrict__ meta) {
  if (threadIdx.x == 0 && blockIdx.x == 0) {
    int o = 0;
    for (int e = 0; e < 16; e++) { meta[32 + e] = o; o += (meta[8 + e] + 255) & ~255; }
    meta[48] = o;
    for (int rt = 0; rt < ROWS_CAP / BM; rt++) {
      const int base = rt * BM;
      int e = 0;
      for (int i = 1; i < 16; i++) if (meta[32 + i] <= base) e = i;
      meta[96 + rt] = e;
    }
  }
}

__global__ void k_assign(const int* __restrict__ top2i,
                         const float* __restrict__ top2w,
                         int* __restrict__ meta, int* __restrict__ tok_of_row,
                         int* __restrict__ t2row)
{
  int t = blockIdx.x * 256 + threadIdx.x;
  if (t >= NTOK) return;
  #pragma unroll
  for (int k = 0; k < 2; k++) {
    int e = top2i[2 * t + k];
    int slot = atomicAdd(&meta[64 + e], 1);
    int row = meta[32 + e] + slot;
    tok_of_row[row] = t;
    t2row[2 * t + k] = row;
  }
}

// --------------------------- GEMM 1: h = fp8(8*silu(x @ w1m + b1)) ----------
__global__ __launch_bounds__(256, 2)
void k_gemm1(const unsigned short* __restrict__ xb,
             const float* __restrict__ w1, const float* __restrict__ b1,
             const void* __restrict__ mask1,
             const int* __restrict__ meta, const int* __restrict__ tok_of_row,
             unsigned char* __restrict__ h8)
{
  __shared__ ux4 Ash[2][2048];                  // 2 x 32 KB (256 rows x 64 k)
  __shared__ __align__(16) ux2 Bsh[2][1024];    // 2 x 8 KB

  const int bid = xcd_swz();
  const int rt = bid >> 6, ct = bid & 63;       // NCT = 64
  const int base = rt * BM;
  if (base >= meta[48]) return;
  const int e = meta[96 + rt];

  const int tid = threadIdx.x;
  const int wv = tid >> 6;
  const int jg0 = ct * 64;

  // per-block mask bits via wave-parallel ballot (lane i -> k-block i)
  const int l = tid & 63, l16 = l & 15, lhi = l >> 4;
  unsigned int bits;
  {
    const int flag = flag_of(meta[1]);
    bool on = false;
    if (l < 16)
      on = mask_at(mask1, flag, (size_t)e * DIM * HID + (size_t)l * 64 * HID + jg0);
    bits = (unsigned int)(__ballot(on) & 0xFFFFull);
  }

  const unsigned int sseg = (unsigned int)(((tid & 7) ^ ((tid >> 3) & 7)) * 16);
  unsigned int aoff[8];
  #pragma unroll
  for (int i = 0; i < 8; i++) {
    int tok = tok_of_row[base + i * 32 + (tid >> 3)];
    if (tok < 0) tok = 0;                       // pad rows: finite garbage, unused
    aoff[i] = (unsigned int)tok * (DIM * 2) + sseg;
  }

  const int kb = tid >> 4, jb = tid & 15;

  fx4 acc[4][4] = {};

  auto STAGE_A = [&](int b, int d0) {
    const char* gp = (const char*)xb + (d0 << 1);
    #pragma unroll
    for (int i = 0; i < 8; i++)
      __builtin_amdgcn_global_load_lds(
        (const __attribute__((address_space(1))) unsigned int*)(gp + aoff[i]),
        (__attribute__((address_space(3))) unsigned int*)&Ash[b][i * 256 + wv * 64],
        16, 0, 0);
  };
  auto LOAD_B = [&](fx4* r, int d0) {
    const float* bp = w1 + ((size_t)e * DIM + d0 + kb * 4) * HID + jg0 + jb * 4;
    r[0] = *(const fx4*)bp;
    r[1] = *(const fx4*)(bp + HID);
    r[2] = *(const fx4*)(bp + 2 * HID);
    r[3] = *(const fx4*)(bp + 3 * HID);
  };
  auto WRITE_B = [&](int b, const fx4* r) {
    #pragma unroll
    for (int jj = 0; jj < 4; jj++) {
      ux2 val;
      val[0] = cvt_pk(r[0][jj], r[1][jj]);
      val[1] = cvt_pk(r[2][jj], r[3][jj]);
      const int col = jb * 4 + jj;
      Bsh[b][(col * 8 + ((kb >> 1) ^ (col & 7))) * 2 + (kb & 1)] = val;
    }
  };
  auto COMPUTE = [&](int b) {
    #pragma unroll
    for (int ks = 0; ks < 2; ks++) {
      s8v a[4], bb[4];
      const int seg = ks * 4 + lhi;
      #pragma unroll
      for (int m = 0; m < 4; m++) {
        const int row = wv * 64 + m * 16 + l16;
        V16 v; v.u = Ash[b][row * 8 + (seg ^ (row & 7))]; a[m] = v.s;
      }
      #pragma unroll
      for (int n = 0; n < 4; n++) {
        const int col = n * 16 + l16;
        V16 v; v.u = ((const ux4*)&Bsh[b][0])[col * 8 + (seg ^ (col & 7))]; bb[n] = v.s;
      }
      #pragma unroll
      for (int m = 0; m < 4; m++)
        #pragma unroll
        for (int n = 0; n < 4; n++)
          acc[m][n] = __builtin_amdgcn_mfma_f32_16x16x32_bf16(a[m], bb[n], acc[m][n], 0, 0, 0);
    }
  };

  if (bits) {
    int d0 = (__ffs(bits) - 1) << 6; bits &= bits - 1;
    {
      fx4 br[4];
      STAGE_A(0, d0);
      LOAD_B(br, d0);
      WRITE_B(0, br);
    }
    __syncthreads();
    int cur = 0;
    for (;;) {
      int nd0 = -1;
      fx4 br2[4];
      if (bits) { nd0 = (__ffs(bits) - 1) << 6; bits &= bits - 1; }
      if (nd0 >= 0) { STAGE_A(cur ^ 1, nd0); LOAD_B(br2, nd0); }
      COMPUTE(cur);
      if (nd0 >= 0) WRITE_B(cur ^ 1, br2);
      __syncthreads();
      cur ^= 1;
      if (nd0 < 0) break;
    }
  }

  // epilogue: h = fp8(8 * silu(acc + b1)) -> LDS byte tile -> 16B dump
  unsigned char* hs = (unsigned char*)&Ash[0][0];   // 256 x 64 B = 16 KB
  __syncthreads();
  #pragma unroll
  for (int m = 0; m < 4; m++)
    #pragma unroll
    for (int n = 0; n < 4; n++) {
      const int gcol = jg0 + n * 16 + l16;
      const float bbv = b1[e * HID + gcol];
      #pragma unroll
      for (int i = 0; i < 4; i++) {
        const int row = wv * 64 + m * 16 + lhi * 4 + i;
        float v = acc[m][n][i] + bbv;
        float hval = v / (1.0f + __expf(-v));
        hs[row * 64 + n * 16 + l16] = (unsigned char)f2fp8(hval * 8.0f);
      }
    }
  __syncthreads();
  {
    const ux4* s = (const ux4*)hs;
    #pragma unroll
    for (int j = 0; j < 4; j++) {
      const int c2 = j * 256 + tid;
      const int row = c2 >> 2;
      *(ux4*)(h8 + (size_t)(base + row) * HID + ct * 64 + (c2 & 3) * 16) = s[c2];
    }
  }
}

// --------------------------- GEMM 2: y = bf16(h8 @ w2fp8 / 128 + b2) --------
// fp8 MFMA. A: h8 via global_load_lds, 4 chunks/row, chunk swizzle
// c ^ ((row>>1)&3) pre-applied on source. B: w2 f32 -> fp8 x16 in LDS.
__global__ __launch_bounds__(256, 3)
void k_gemm2(const unsigned char* __restrict__ h8,
             const float* __restrict__ w2, const float* __restrict__ b2,
             const void* __restrict__ mask2,
             const int* __restrict__ meta, unsigned short* __restrict__ yb)
{
  __shared__ ux4 Ash[2][1024];                       // 2 x 16 KB (256 rows x 64 B)
  __shared__ __align__(16) unsigned int Bsh[2][1024]; // 2 x 4 KB (64 cols x 64 B)

  const int bid = xcd_swz();
  const int rt = bid >> 4, ct = bid & 15;       // NCT = 16
  const int base = rt * BM;
  if (base >= meta[48]) return;
  const int e = meta[96 + rt];

  const int tid = threadIdx.x;
  const int wv = tid >> 6;
  const int jg0 = ct * 64;

  const int l = tid & 63, l16 = l & 15, lhi = l >> 4;
  unsigned long long bits;
  {
    const int flag = flag_of(meta[1]);
    bits = __ballot(mask_at(mask2, flag,
             (size_t)e * HID * DIM + (size_t)l * 64 * DIM + jg0));
  }

  // A source offsets: LDS chunk ci = i*256+tid; row = i*64 + (tid>>2);
  // stored data chunk = (tid&3) ^ ((row>>1)&3) with (row>>1)&3 = (tid>>3)&3
  const unsigned int sw = (unsigned int)((tid & 3) ^ ((tid >> 3) & 3));
  unsigned int aoff[4];
  #pragma unroll
  for (int i = 0; i < 4; i++)
    aoff[i] = (unsigned int)(base + i * 64 + (tid >> 2)) * (unsigned int)HID + sw * 16;

  const int kb = tid >> 4, jb = tid & 15;

  fx4 acc[4][4] = {};

  auto STAGE_A = [&](int b, int d0) {
    const char* gp = (const char*)h8 + d0;
    #pragma unroll
    for (int i = 0; i < 4; i++)
      __builtin_amdgcn_global_load_lds(
        (const __attribute__((address_space(1))) unsigned int*)(gp + aoff[i]),
        (__attribute__((address_space(3))) unsigned int*)&Ash[b][i * 256 + wv * 64],
        16, 0, 0);
  };
  auto LOAD_B = [&](fx4* r, int d0) {
    const float* bp = w2 + ((size_t)e * HID + d0 + kb * 4) * DIM + jg0 + jb * 4;
    r[0] = *(const fx4*)bp;
    r[1] = *(const fx4*)(bp + DIM);
    r[2] = *(const fx4*)(bp + 2 * DIM);
    r[3] = *(const fx4*)(bp + 3 * DIM);
  };
  auto WRITE_B = [&](int b, const fx4* r) {
    #pragma unroll
    for (int jj = 0; jj < 4; jj++) {
      const int col = jb * 4 + jj;
      unsigned int u = (unsigned int)__builtin_amdgcn_cvt_pk_fp8_f32(
                          r[0][jj] * 16.0f, r[1][jj] * 16.0f, 0, false);
      u = (unsigned int)__builtin_amdgcn_cvt_pk_fp8_f32(
                          r[2][jj] * 16.0f, r[3][jj] * 16.0f, (int)u, true);
      // k-bytes kb*4..+3 of col: chunk = kb>>2 (swizzled), internal (kb&3)*4
      Bsh[b][col * 16 + (((kb >> 2) ^ ((col >> 1) & 3)) << 2) + (kb & 3)] = u;
    }
  };
  auto COMPUTE = [&](int b) {
    const char* Ab = (const char*)&Ash[b][0];
    const char* Bb = (const char*)&Bsh[b][0];
    #pragma unroll
    for (int ks = 0; ks < 2; ks++) {
      const int c = ks * 2 + (lhi >> 1);
      const int sub = (lhi & 1) << 3;
      long long a[4], bb[4];
      #pragma unroll
      for (int m = 0; m < 4; m++) {
        const int row = wv * 64 + m * 16 + l16;
        a[m] = *(const long long*)(Ab + row * 64 + ((c ^ ((row >> 1) & 3)) << 4) + sub);
      }
      #pragma unroll
      for (int n = 0; n < 4; n++) {
        const int col = n * 16 + l16;
        bb[n] = *(const long long*)(Bb + col * 64 + ((c ^ ((col >> 1) & 3)) << 4) + sub);
      }
      #pragma unroll
      for (int m = 0; m < 4; m++)
        #pragma unroll
        for (int n = 0; n < 4; n++)
          acc[m][n] = __builtin_amdgcn_mfma_f32_16x16x32_fp8_fp8(a[m], bb[n], acc[m][n], 0, 0, 0);
    }
  };

  if (bits) {
    int d0 = (__ffsll(bits) - 1) << 6; bits &= bits - 1;
    {
      fx4 br[4];
      STAGE_A(0, d0);
      LOAD_B(br, d0);
      WRITE_B(0, br);
    }
    __syncthreads();
    int cur = 0;
    for (;;) {
      int nd0 = -1;
      fx4 br2[4];
      if (bits) { nd0 = (__ffsll(bits) - 1) << 6; bits &= bits - 1; }
      if (nd0 >= 0) { STAGE_A(cur ^ 1, nd0); LOAD_B(br2, nd0); }
      COMPUTE(cur);
      if (nd0 >= 0) WRITE_B(cur ^ 1, br2);
      __syncthreads();
      cur ^= 1;
      if (nd0 < 0) break;
    }
  }

  // epilogue: y = bf16(acc/128 + b2), restaged via LDS (Ash[0]+Ash[1] = 32 KB)
  unsigned short* hs = (unsigned short*)&Ash[0][0];
  __syncthreads();
  #pragma unroll
  for (int m = 0; m < 4; m++)
    #pragma unroll
    for (int n = 0; n < 4; n++) {
      const int gcol = jg0 + n * 16 + l16;
      const float bbv = b2[e * DIM + gcol];
      #pragma unroll
      for (int i = 0; i < 4; i++) {
        const int row = wv * 64 + m * 16 + lhi * 4 + i;
        hs[row * 64 + n * 16 + l16] =
            (unsigned short)f2bf(acc[m][n][i] * 0.0078125f + bbv);
      }
    }
  __syncthreads();
  {
    const ux4* s = (const ux4*)hs;
    #pragma unroll
    for (int j = 0; j < 8; j++) {
      const int c2 = j * 256 + tid;
      const int row = c2 >> 3;
      *(ux4*)(yb + (size_t)(base + row) * DIM + ct * 64 + (c2 & 7) * 8) = s[c2];
    }
  }
}

// --------------------------- cross: out = x + eo @ cwm + cb -----------------
// eo rows formed on the fly from bf16 y: eo[tok] = w0*y[r0] + w1*y[r1]
__global__ __launch_bounds__(256, 2)
void k_cross(const unsigned short* __restrict__ yb, const float* __restrict__ x,
             const float* __restrict__ cw, const float* __restrict__ cb,
             const void* __restrict__ cmask, const int* __restrict__ meta,
             const int* __restrict__ t2row, const float* __restrict__ t2w,
             float* __restrict__ out)
{
  __shared__ ux4 Ash[2048];
  __shared__ __align__(16) ux2 Bsh[1024];

  const int bid = xcd_swz();
  const int rt = bid >> 4, ct = bid & 15;
  const int base = rt * BM;
  const int tid = threadIdx.x;
  const int jg0 = ct * 64;

  const int wave = tid >> 6, l = tid & 63;
  const int l16 = l & 15, lhi = l >> 4;

  unsigned int bits;
  {
    const int flag = flag_of(meta[1]);
    bool on = false;
    if (l < 16)
      on = mask_at(cmask, flag, (size_t)l * 64 * DIM + jg0);
    bits = (unsigned int)(__ballot(on) & 0xFFFFull);
  }

  const int tok = base + tid;
  const int r0 = t2row[2 * tok], r1 = t2row[2 * tok + 1];
  const float w0 = t2w[2 * tok], w1 = t2w[2 * tok + 1];

  fx4 acc[4][4] = {};

  while (bits) {
    const int kbx = __ffs(bits) - 1; bits &= bits - 1;
    const int d0 = kbx * 64;
    {   // stage A: combine two bf16 pair rows -> bf16 (swizzled ds_write)
      const ux4* s0 = (const ux4*)(yb + (size_t)r0 * DIM + d0);
      const ux4* s1 = (const ux4*)(yb + (size_t)r1 * DIM + d0);
      #pragma unroll
      for (int seg = 0; seg < 8; seg++) {
        ux4 v0 = s0[seg], v1 = s1[seg], o;
        #pragma unroll
        for (int j = 0; j < 4; j++) {
          float alo = __uint_as_float(v0[j] << 16);
          float ahi = __uint_as_float(v0[j] & 0xFFFF0000u);
          float blo = __uint_as_float(v1[j] << 16);
          float bhi = __uint_as_float(v1[j] & 0xFFFF0000u);
          o[j] = cvt_pk(w0 * alo + w1 * blo, w0 * ahi + w1 * bhi);
        }
        Ash[tid * 8 + (seg ^ (tid & 7))] = o;
      }
    }
    {   // stage B from cross_w (f32 reg-staged)
      const int kbt = tid >> 4, jb = tid & 15;
      const float* bp = cw + (size_t)(d0 + kbt * 4) * DIM + jg0 + jb * 4;
      fx4 r0v = *(const fx4*)bp;
      fx4 r1v = *(const fx4*)(bp + DIM);
      fx4 r2v = *(const fx4*)(bp + 2 * DIM);
      fx4 r3v = *(const fx4*)(bp + 3 * DIM);
      #pragma unroll
      for (int jj = 0; jj < 4; jj++) {
        ux2 val;
        val[0] = cvt_pk(r0v[jj], r1v[jj]);
        val[1] = cvt_pk(r2v[jj], r3v[jj]);
        const int col = jb * 4 + jj;
        Bsh[(col * 8 + ((kbt >> 1) ^ (col & 7))) * 2 + (kbt & 1)] = val;
      }
    }
    __syncthreads();
    #pragma unroll
    for (int ks = 0; ks < 2; ks++) {
      s8v a[4], b[4];
      const int seg = ks * 4 + lhi;
      #pragma unroll
      for (int m = 0; m < 4; m++) {
        const int row = wave * 64 + m * 16 + l16;
        V16 v; v.u = Ash[row * 8 + (seg ^ (row & 7))]; a[m] = v.s;
      }
      #pragma unroll
      for (int n = 0; n < 4; n++) {
        const int col = n * 16 + l16;
        V16 v; v.u = ((const ux4*)Bsh)[col * 8 + (seg ^ (col & 7))]; b[n] = v.s;
      }
      #pragma unroll
      for (int m = 0; m < 4; m++)
        #pragma unroll
        for (int n = 0; n < 4; n++)
          acc[m][n] = __builtin_amdgcn_mfma_f32_16x16x32_bf16(a[m], b[n], acc[m][n], 0, 0, 0);
    }
    __syncthreads();
  }

  #pragma unroll
  for (int m = 0; m < 4; m++)
    #pragma unroll
    for (int n = 0; n < 4; n++) {
      const int gcol = jg0 + n * 16 + l16;
      #pragma unroll
      for (int i = 0; i < 4; i++) {
        const int lrow = wave * 64 + m * 16 + lhi * 4 + i;
        const size_t idx = (size_t)(base + lrow) * DIM + gcol;
        out[idx] = acc[m][n][i] + x[idx] + cb[gcol];
      }
    }
}

// ---------------------------------------------------------------------------
extern "C" void kernel_launch(void* const* d_in, const int* in_sizes, int n_in,
                              void* d_out, int out_size, void* d_ws, size_t ws_size,
                              hipStream_t stream)
{
  (void)in_sizes; (void)n_in; (void)out_size; (void)ws_size;
  const float* x      = (const float*)d_in[0];
  const float* gate_w = (const float*)d_in[1];   // [2,16,1024]
  const float* temp   = (const float*)d_in[2];   // [2]
  const float* w1     = (const float*)d_in[3];   // [16,1024,4096]
  const float* b1     = (const float*)d_in[4];
  const float* w2     = (const float*)d_in[5];   // [16,4096,1024]
  const float* b2     = (const float*)d_in[6];
  const float* cw     = (const float*)d_in[7];   // [1024,1024]
  const float* cb     = (const float*)d_in[8];
  const void*  mask1  = d_in[9];
  const void*  mask2  = d_in[10];
  const void*  cmask  = d_in[11];
  float* out = (float*)d_out;
  char* ws = (char*)d_ws;

  size_t off = 0;
  auto walloc = [&](size_t b) { size_t r = off; off = (off + b + 255) & ~(size_t)255; return r; };
  size_t o_meta = walloc(4096);
  size_t o_t2i  = walloc((size_t)NTOK * 2 * 4);
  size_t o_t2w  = walloc((size_t)NTOK * 2 * 4);
  size_t o_t2r  = walloc((size_t)NTOK * 2 * 4);
  size_t o_tok  = walloc((size_t)ROWS_CAP * 4);
  size_t o_xbf  = walloc((size_t)NTOK * DIM * 2);
  size_t o_y    = walloc((size_t)ROWS_CAP * DIM * 2);    // 40 MB (bf16)
  size_t o_hc   = walloc((size_t)ROWS_CAP * HID);        // 84 MB (fp8)

  int*                meta = (int*)(ws + o_meta);
  int*                t2i  = (int*)(ws + o_t2i);
  float*              t2w  = (float*)(ws + o_t2w);
  int*                t2r  = (int*)(ws + o_t2r);
  int*                tok  = (int*)(ws + o_tok);
  unsigned short*     xbf  = (unsigned short*)(ws + o_xbf);
  unsigned short*     yb   = (unsigned short*)(ws + o_y);
  unsigned char*      h8   = (unsigned char*)(ws + o_hc);

  hipMemsetAsync(ws + o_meta, 0, 4096, stream);
  hipMemsetAsync(ws + o_tok, 0xFF, (size_t)ROWS_CAP * 4, stream);  // -1

  k_route  <<<NTOK / 32, 256, 0, stream>>>(x, gate_w + (size_t)1 * NEXP * DIM, temp + 1,
                                           (const unsigned int*)mask1, t2i, t2w, meta, xbf);
  k_offsets<<<1, 64, 0, stream>>>(meta);
  k_assign <<<NTOK / 256, 256, 0, stream>>>(t2i, t2w, meta, tok, t2r);

  const int NRT = ROWS_CAP / BM;   // 80
  k_gemm1<<<NRT * 64, 256, 0, stream>>>(xbf, w1, b1, mask1, meta, tok, h8);
  k_gemm2<<<NRT * 16, 256, 0, stream>>>(h8, w2, b2, mask2, meta, yb);
  k_cross<<<(NTOK / BM) * 16, 256, 0, stream>>>(yb, x, cw, cb, cmask, meta, t2r, t2w, out);
}

// Round 12
// 351.835 us; speedup vs baseline: 2.2049x; 1.0651x over previous
//
#include <hip/hip_runtime.h>

// ---------------------------------------------------------------------------
// HierarchicalSparseLayer: top-2 MoE with block-sparse (64x64) masked weights
// B=8192 tokens, D=1024, H=4096, E=16 experts, K=2, + block-sparse cross proj.
// R12: R11 + gemm1 end-to-end fp8 (x stored fp8 x16, w1 -> fp8 x16 in B-stage,
//      fp8 MFMA, 40 KB LDS -> 3 blocks/CU), cross at 3 blocks/CU, tok memset
//      folded into k_offsets (pad-row writes).
// ---------------------------------------------------------------------------

#define NTOK 8192
#define DIM  1024
#define HID  4096
#define NEXP 16
#define BM   256
#define ROWS_CAP (NTOK*2 + NEXP*256)   // 20480

typedef __attribute__((ext_vector_type(4))) float fx4;
typedef __attribute__((ext_vector_type(4))) unsigned int ux4;
typedef __attribute__((ext_vector_type(2))) unsigned int ux2;
typedef __attribute__((ext_vector_type(8))) short s8v;
union V16 { ux4 u; s8v s; };

__device__ __forceinline__ unsigned int f2bf(float f) {
  unsigned int u = __float_as_uint(f);
  return (u + 0x7fffu + ((u >> 16) & 1u)) >> 16;   // RNE, inputs finite
}

__device__ __forceinline__ unsigned int cvt_pk(float lo, float hi) {
  unsigned int r;
  asm("v_cvt_pk_bf16_f32 %0, %1, %2" : "=v"(r) : "v"(lo), "v"(hi));
  return r;
}

__device__ __forceinline__ unsigned int f2fp8(float v) {
  return (unsigned int)__builtin_amdgcn_cvt_pk_fp8_f32(v, v, 0, false) & 0xFFu;
}

// pack 4 f32 (scaled) into one u32 of 4 fp8 e4m3
__device__ __forceinline__ unsigned int pk4fp8(float a, float b, float c, float d) {
  unsigned int u = (unsigned int)__builtin_amdgcn_cvt_pk_fp8_f32(a, b, 0, false);
  u = (unsigned int)__builtin_amdgcn_cvt_pk_fp8_f32(c, d, (int)u, true);
  return u;
}

// Mask dtype detected at runtime: flag 0=u8, 1=i32, 2=f32
__device__ __forceinline__ bool mask_at(const void* m, int flag, size_t idx) {
  if (flag == 0) return ((const unsigned char*)m)[idx] != 0;
  if (flag == 1) return ((const int*)m)[idx] != 0;
  return ((const float*)m)[idx] != 0.0f;
}

__device__ __forceinline__ int flag_of(int ev) {
  return (ev & 2) ? 2 : ((ev & 1) ? 0 : 1);
}

// XCD-aware swizzle (grid % 8 == 0)
__device__ __forceinline__ int xcd_swz() {
  const int b = blockIdx.x, cpx = gridDim.x >> 3;
  return (b & 7) * cpx + (b >> 3);
}

// --------------------------- routing (+ detect + x->fp8 pack) ---------------
// meta: [1]=detect bits [8..23]=counts [32..47]=offsets [48]=total
//       [64..79]=slot counters [96..175]=expert_of_rt
__global__ void k_route(const float* __restrict__ x,
                        const float* __restrict__ gw,    // gate_w[-1] [16,1024]
                        const float* __restrict__ temp,
                        const unsigned int* __restrict__ m1raw,
                        int* __restrict__ top2i, float* __restrict__ top2w,
                        int* __restrict__ meta, unsigned char* __restrict__ x8)
{
  if (blockIdx.x < 64) {     // fold k_detect
    int bits = 0;
    size_t base = (size_t)blockIdx.x * 4096 + threadIdx.x;
    for (int j = 0; j < 16; j++) {
      unsigned int v = m1raw[base + 256 * j];
      if (v == 0x3f800000u) bits |= 2;
      else if (v > 1u)      bits |= 1;
    }
    if (bits) atomicOr(&meta[1], bits);
  }

  __shared__ float gwsh[NEXP * DIM];
  for (int i = threadIdx.x; i < NEXP * DIM; i += 256) gwsh[i] = gw[i];
  __syncthreads();

  const int wv = threadIdx.x >> 6;
  const int l = threadIdx.x & 63;
  #pragma unroll
  for (int tt = 0; tt < 8; tt++) {
    const int t = blockIdx.x * 32 + wv * 8 + tt;
    const float* xr = x + (size_t)t * DIM;
    float xv[16];
    #pragma unroll
    for (int j = 0; j < 16; j++) xv[j] = xr[l + 64 * j];
    float logit[16];
    #pragma unroll
    for (int e = 0; e < 16; e++) {
      const float* g = gwsh + e * DIM;
      float s = 0.f;
      #pragma unroll
      for (int j = 0; j < 16; j++) s += xv[j] * g[l + 64 * j];
      #pragma unroll
      for (int o = 32; o >= 1; o >>= 1) s += __shfl_xor(s, o);
      logit[e] = s;
    }
    if (l == 0) {
      const float tinv = 1.0f / temp[0];
      int i0 = 0; float v0 = logit[0] * tinv;
      #pragma unroll
      for (int e = 1; e < 16; e++) { float v = logit[e] * tinv; if (v > v0) { v0 = v; i0 = e; } }
      int i1 = -1; float v1 = 0.f; bool first = true;
      #pragma unroll
      for (int e = 0; e < 16; e++) {
        if (e == i0) continue;
        float v = logit[e] * tinv;
        if (first || v > v1) { v1 = v; i1 = e; first = false; }
      }
      float ex = __expf(v1 - v0);
      float den = 1.0f + ex;
      top2i[2 * t] = i0; top2i[2 * t + 1] = i1;
      top2w[2 * t] = 1.0f / den; top2w[2 * t + 1] = ex / den;
      atomicAdd(&meta[8 + i0], 1);
      atomicAdd(&meta[8 + i1], 1);
    }
  }

  // pack this block's 32 tokens to fp8 (x16 scale); slab is L1/L2-hot
  {
    const size_t be = (size_t)blockIdx.x * 32 * DIM;
    const fx4* src = (const fx4*)(x + be);
    ux4* dst = (ux4*)(x8 + be);          // 2048 ux4 per block
    #pragma unroll
    for (int i = 0; i < 8; i++) {
      const int idx = i * 256 + threadIdx.x;
      fx4 a = src[4 * idx], b = src[4 * idx + 1];
      fx4 c = src[4 * idx + 2], d = src[4 * idx + 3];
      ux4 o;
      o[0] = pk4fp8(a[0] * 16.f, a[1] * 16.f, a[2] * 16.f, a[3] * 16.f);
      o[1] = pk4fp8(b[0] * 16.f, b[1] * 16.f, b[2] * 16.f, b[3] * 16.f);
      o[2] = pk4fp8(c[0] * 16.f, c[1] * 16.f, c[2] * 16.f, c[3] * 16.f);
      o[3] = pk4fp8(d[0] * 16.f, d[1] * 16.f, d[2] * 16.f, d[3] * 16.f);
      dst[idx] = o;
    }
  }
}

// offsets + expert_of_rt + pad-row init (replaces tok memset)
__global__ void k_offsets(int* __restrict__ meta, int* __restrict__ tok_of_row) {
  if (threadIdx.x == 0) {
    int o = 0;
    for (int e = 0; e < 16; e++) { meta[32 + e] = o; o += (meta[8 + e] + 255) & ~255; }
    meta[48] = o;
    for (int rt = 0; rt < ROWS_CAP / BM; rt++) {
      const int base = rt * BM;
      int e = 0;
      for (int i = 1; i < 16; i++) if (meta[32 + i] <= base) e = i;
      meta[96 + rt] = e;
    }
  }
  __syncthreads();
  const int total = meta[48];
  for (int r = threadIdx.x; r < total; r += 256) {
    const int e = meta[96 + r / BM];
    if (r >= meta[32 + e] + meta[8 + e]) tok_of_row[r] = -1;
  }
}

__global__ void k_assign(const int* __restrict__ top2i,
                         const float* __restrict__ top2w,
                         int* __restrict__ meta, int* __restrict__ tok_of_row,
                         int* __restrict__ t2row)
{
  int t = blockIdx.x * 256 + threadIdx.x;
  if (t >= NTOK) return;
  #pragma unroll
  for (int k = 0; k < 2; k++) {
    int e = top2i[2 * t + k];
    int slot = atomicAdd(&meta[64 + e], 1);
    int row = meta[32 + e] + slot;
    tok_of_row[row] = t;
    t2row[2 * t + k] = row;
  }
}

// --------------------------- GEMM 1: h8 = fp8(8*silu(x8 @ w1fp8/256 + b1)) --
// Full fp8: A via global_load_lds (chunk swizzle on source), B w1 f32->fp8 x16
// reg-staged, fp8 MFMA, 40 KB LDS -> 3 blocks/CU.
__global__ __launch_bounds__(256, 3)
void k_gemm1(const unsigned char* __restrict__ x8,
             const float* __restrict__ w1, const float* __restrict__ b1,
             const void* __restrict__ mask1,
             const int* __restrict__ meta, const int* __restrict__ tok_of_row,
             unsigned char* __restrict__ h8)
{
  __shared__ ux4 Ash[2][1024];                        // 2 x 16 KB (256 rows x 64 B)
  __shared__ __align__(16) unsigned int Bsh[2][1024]; // 2 x 4 KB

  const int bid = xcd_swz();
  const int rt = bid >> 6, ct = bid & 63;       // NCT = 64
  const int base = rt * BM;
  if (base >= meta[48]) return;
  const int e = meta[96 + rt];

  const int tid = threadIdx.x;
  const int wv = tid >> 6;
  const int jg0 = ct * 64;
  const int l = tid & 63, l16 = l & 15, lhi = l >> 4;

  unsigned int bits;
  {
    const int flag = flag_of(meta[1]);
    bool on = false;
    if (l < 16)
      on = mask_at(mask1, flag, (size_t)e * DIM * HID + (size_t)l * 64 * HID + jg0);
    bits = (unsigned int)(__ballot(on) & 0xFFFFull);
  }

  // A source offsets: row = i*64 + (tid>>2), gathered; stored chunk
  // (tid&3) ^ ((row>>1)&3) pre-applied on source
  const unsigned int sw = (unsigned int)((tid & 3) ^ ((tid >> 3) & 3));
  unsigned int aoff[4];
  #pragma unroll
  for (int i = 0; i < 4; i++) {
    int tok = tok_of_row[base + i * 64 + (tid >> 2)];
    if (tok < 0) tok = 0;                       // pad rows: finite garbage, unused
    aoff[i] = (unsigned int)tok * (unsigned int)DIM + sw * 16;
  }

  const int kb = tid >> 4, jb = tid & 15;

  fx4 acc[4][4] = {};

  auto STAGE_A = [&](int b, int d0) {
    const char* gp = (const char*)x8 + d0;
    #pragma unroll
    for (int i = 0; i < 4; i++)
      __builtin_amdgcn_global_load_lds(
        (const __attribute__((address_space(1))) unsigned int*)(gp + aoff[i]),
        (__attribute__((address_space(3))) unsigned int*)&Ash[b][i * 256 + wv * 64],
        16, 0, 0);
  };
  auto LOAD_B = [&](fx4* r, int d0) {
    const float* bp = w1 + ((size_t)e * DIM + d0 + kb * 4) * HID + jg0 + jb * 4;
    r[0] = *(const fx4*)bp;
    r[1] = *(const fx4*)(bp + HID);
    r[2] = *(const fx4*)(bp + 2 * HID);
    r[3] = *(const fx4*)(bp + 3 * HID);
  };
  auto WRITE_B = [&](int b, const fx4* r) {
    #pragma unroll
    for (int jj = 0; jj < 4; jj++) {
      const int col = jb * 4 + jj;
      unsigned int u = pk4fp8(r[0][jj] * 16.0f, r[1][jj] * 16.0f,
                              r[2][jj] * 16.0f, r[3][jj] * 16.0f);
      Bsh[b][col * 16 + (((kb >> 2) ^ ((col >> 1) & 3)) << 2) + (kb & 3)] = u;
    }
  };
  auto COMPUTE = [&](int b) {
    const char* Ab = (const char*)&Ash[b][0];
    const char* Bb = (const char*)&Bsh[b][0];
    #pragma unroll
    for (int ks = 0; ks < 2; ks++) {
      const int c = ks * 2 + (lhi >> 1);
      const int sub = (lhi & 1) << 3;
      long long a[4], bb[4];
      #pragma unroll
      for (int m = 0; m < 4; m++) {
        const int row = wv * 64 + m * 16 + l16;
        a[m] = *(const long long*)(Ab + row * 64 + ((c ^ ((row >> 1) & 3)) << 4) + sub);
      }
      #pragma unroll
      for (int n = 0; n < 4; n++) {
        const int col = n * 16 + l16;
        bb[n] = *(const long long*)(Bb + col * 64 + ((c ^ ((col >> 1) & 3)) << 4) + sub);
      }
      #pragma unroll
      for (int m = 0; m < 4; m++)
        #pragma unroll
        for (int n = 0; n < 4; n++)
          acc[m][n] = __builtin_amdgcn_mfma_f32_16x16x32_fp8_fp8(a[m], bb[n], acc[m][n], 0, 0, 0);
    }
  };

  if (bits) {
    int d0 = (__ffs(bits) - 1) << 6; bits &= bits - 1;
    {
      fx4 br[4];
      STAGE_A(0, d0);
      LOAD_B(br, d0);
      WRITE_B(0, br);
    }
    __syncthreads();
    int cur = 0;
    for (;;) {
      int nd0 = -1;
      fx4 br2[4];
      if (bits) { nd0 = (__ffs(bits) - 1) << 6; bits &= bits - 1; }
      if (nd0 >= 0) { STAGE_A(cur ^ 1, nd0); LOAD_B(br2, nd0); }
      COMPUTE(cur);
      if (nd0 >= 0) WRITE_B(cur ^ 1, br2);
      __syncthreads();
      cur ^= 1;
      if (nd0 < 0) break;
    }
  }

  // epilogue: h = fp8(8 * silu(acc/256 + b1)) -> LDS byte tile -> 16B dump
  unsigned char* hs = (unsigned char*)&Ash[0][0];   // 16 KB tile
  __syncthreads();
  #pragma unroll
  for (int m = 0; m < 4; m++)
    #pragma unroll
    for (int n = 0; n < 4; n++) {
      const int gcol = jg0 + n * 16 + l16;
      const float bbv = b1[e * HID + gcol];
      #pragma unroll
      for (int i = 0; i < 4; i++) {
        const int row = wv * 64 + m * 16 + lhi * 4 + i;
        float v = acc[m][n][i] * 0.00390625f + bbv;
        float hval = v / (1.0f + __expf(-v));
        hs[row * 64 + n * 16 + l16] = (unsigned char)f2fp8(hval * 8.0f);
      }
    }
  __syncthreads();
  {
    const ux4* s = (const ux4*)hs;
    #pragma unroll
    for (int j = 0; j < 4; j++) {
      const int c2 = j * 256 + tid;
      const int row = c2 >> 2;
      *(ux4*)(h8 + (size_t)(base + row) * HID + ct * 64 + (c2 & 3) * 16) = s[c2];
    }
  }
}

// --------------------------- GEMM 2: y = bf16(h8 @ w2fp8 / 128 + b2) --------
__global__ __launch_bounds__(256, 3)
void k_gemm2(const unsigned char* __restrict__ h8,
             const float* __restrict__ w2, const float* __restrict__ b2,
             const void* __restrict__ mask2,
             const int* __restrict__ meta, unsigned short* __restrict__ yb)
{
  __shared__ ux4 Ash[2][1024];                       // 2 x 16 KB (256 rows x 64 B)
  __shared__ __align__(16) unsigned int Bsh[2][1024]; // 2 x 4 KB (64 cols x 64 B)

  const int bid = xcd_swz();
  const int rt = bid >> 4, ct = bid & 15;       // NCT = 16
  const int base = rt * BM;
  if (base >= meta[48]) return;
  const int e = meta[96 + rt];

  const int tid = threadIdx.x;
  const int wv = tid >> 6;
  const int jg0 = ct * 64;

  const int l = tid & 63, l16 = l & 15, lhi = l >> 4;
  unsigned long long bits;
  {
    const int flag = flag_of(meta[1]);
    bits = __ballot(mask_at(mask2, flag,
             (size_t)e * HID * DIM + (size_t)l * 64 * DIM + jg0));
  }

  const unsigned int sw = (unsigned int)((tid & 3) ^ ((tid >> 3) & 3));
  unsigned int aoff[4];
  #pragma unroll
  for (int i = 0; i < 4; i++)
    aoff[i] = (unsigned int)(base + i * 64 + (tid >> 2)) * (unsigned int)HID + sw * 16;

  const int kb = tid >> 4, jb = tid & 15;

  fx4 acc[4][4] = {};

  auto STAGE_A = [&](int b, int d0) {
    const char* gp = (const char*)h8 + d0;
    #pragma unroll
    for (int i = 0; i < 4; i++)
      __builtin_amdgcn_global_load_lds(
        (const __attribute__((address_space(1))) unsigned int*)(gp + aoff[i]),
        (__attribute__((address_space(3))) unsigned int*)&Ash[b][i * 256 + wv * 64],
        16, 0, 0);
  };
  auto LOAD_B = [&](fx4* r, int d0) {
    const float* bp = w2 + ((size_t)e * HID + d0 + kb * 4) * DIM + jg0 + jb * 4;
    r[0] = *(const fx4*)bp;
    r[1] = *(const fx4*)(bp + DIM);
    r[2] = *(const fx4*)(bp + 2 * DIM);
    r[3] = *(const fx4*)(bp + 3 * DIM);
  };
  auto WRITE_B = [&](int b, const fx4* r) {
    #pragma unroll
    for (int jj = 0; jj < 4; jj++) {
      const int col = jb * 4 + jj;
      unsigned int u = pk4fp8(r[0][jj] * 16.0f, r[1][jj] * 16.0f,
                              r[2][jj] * 16.0f, r[3][jj] * 16.0f);
      Bsh[b][col * 16 + (((kb >> 2) ^ ((col >> 1) & 3)) << 2) + (kb & 3)] = u;
    }
  };
  auto COMPUTE = [&](int b) {
    const char* Ab = (const char*)&Ash[b][0];
    const char* Bb = (const char*)&Bsh[b][0];
    #pragma unroll
    for (int ks = 0; ks < 2; ks++) {
      const int c = ks * 2 + (lhi >> 1);
      const int sub = (lhi & 1) << 3;
      long long a[4], bb[4];
      #pragma unroll
      for (int m = 0; m < 4; m++) {
        const int row = wv * 64 + m * 16 + l16;
        a[m] = *(const long long*)(Ab + row * 64 + ((c ^ ((row >> 1) & 3)) << 4) + sub);
      }
      #pragma unroll
      for (int n = 0; n < 4; n++) {
        const int col = n * 16 + l16;
        bb[n] = *(const long long*)(Bb + col * 64 + ((c ^ ((col >> 1) & 3)) << 4) + sub);
      }
      #pragma unroll
      for (int m = 0; m < 4; m++)
        #pragma unroll
        for (int n = 0; n < 4; n++)
          acc[m][n] = __builtin_amdgcn_mfma_f32_16x16x32_fp8_fp8(a[m], bb[n], acc[m][n], 0, 0, 0);
    }
  };

  if (bits) {
    int d0 = (__ffsll(bits) - 1) << 6; bits &= bits - 1;
    {
      fx4 br[4];
      STAGE_A(0, d0);
      LOAD_B(br, d0);
      WRITE_B(0, br);
    }
    __syncthreads();
    int cur = 0;
    for (;;) {
      int nd0 = -1;
      fx4 br2[4];
      if (bits) { nd0 = (__ffsll(bits) - 1) << 6; bits &= bits - 1; }
      if (nd0 >= 0) { STAGE_A(cur ^ 1, nd0); LOAD_B(br2, nd0); }
      COMPUTE(cur);
      if (nd0 >= 0) WRITE_B(cur ^ 1, br2);
      __syncthreads();
      cur ^= 1;
      if (nd0 < 0) break;
    }
  }

  // epilogue: y = bf16(acc/128 + b2), restaged via LDS (Ash = 32 KB)
  unsigned short* hs = (unsigned short*)&Ash[0][0];
  __syncthreads();
  #pragma unroll
  for (int m = 0; m < 4; m++)
    #pragma unroll
    for (int n = 0; n < 4; n++) {
      const int gcol = jg0 + n * 16 + l16;
      const float bbv = b2[e * DIM + gcol];
      #pragma unroll
      for (int i = 0; i < 4; i++) {
        const int row = wv * 64 + m * 16 + lhi * 4 + i;
        hs[row * 64 + n * 16 + l16] =
            (unsigned short)f2bf(acc[m][n][i] * 0.0078125f + bbv);
      }
    }
  __syncthreads();
  {
    const ux4* s = (const ux4*)hs;
    #pragma unroll
    for (int j = 0; j < 8; j++) {
      const int c2 = j * 256 + tid;
      const int row = c2 >> 3;
      *(ux4*)(yb + (size_t)(base + row) * DIM + ct * 64 + (c2 & 7) * 8) = s[c2];
    }
  }
}

// --------------------------- cross: out = x + eo @ cwm + cb -----------------
// eo rows formed on the fly from bf16 y: eo[tok] = w0*y[r0] + w1*y[r1]
__global__ __launch_bounds__(256, 3)
void k_cross(const unsigned short* __restrict__ yb, const float* __restrict__ x,
             const float* __restrict__ cw, const float* __restrict__ cb,
             const void* __restrict__ cmask, const int* __restrict__ meta,
             const int* __restrict__ t2row, const float* __restrict__ t2w,
             float* __restrict__ out)
{
  __shared__ ux4 Ash[2048];
  __shared__ __align__(16) ux2 Bsh[1024];

  const int bid = xcd_swz();
  const int rt = bid >> 4, ct = bid & 15;
  const int base = rt * BM;
  const int tid = threadIdx.x;
  const int jg0 = ct * 64;

  const int wave = tid >> 6, l = tid & 63;
  const int l16 = l & 15, lhi = l >> 4;

  unsigned int bits;
  {
    const int flag = flag_of(meta[1]);
    bool on = false;
    if (l < 16)
      on = mask_at(cmask, flag, (size_t)l * 64 * DIM + jg0);
    bits = (unsigned int)(__ballot(on) & 0xFFFFull);
  }

  const int tok = base + tid;
  const int r0 = t2row[2 * tok], r1 = t2row[2 * tok + 1];
  const float w0 = t2w[2 * tok], w1 = t2w[2 * tok + 1];

  fx4 acc[4][4] = {};

  while (bits) {
    const int kbx = __ffs(bits) - 1; bits &= bits - 1;
    const int d0 = kbx * 64;
    {   // stage A: combine two bf16 pair rows -> bf16 (swizzled ds_write)
      const ux4* s0 = (const ux4*)(yb + (size_t)r0 * DIM + d0);
      const ux4* s1 = (const ux4*)(yb + (size_t)r1 * DIM + d0);
      #pragma unroll
      for (int seg = 0; seg < 8; seg++) {
        ux4 v0 = s0[seg], v1 = s1[seg], o;
        #pragma unroll
        for (int j = 0; j < 4; j++) {
          float alo = __uint_as_float(v0[j] << 16);
          float ahi = __uint_as_float(v0[j] & 0xFFFF0000u);
          float blo = __uint_as_float(v1[j] << 16);
          float bhi = __uint_as_float(v1[j] & 0xFFFF0000u);
          o[j] = cvt_pk(w0 * alo + w1 * blo, w0 * ahi + w1 * bhi);
        }
        Ash[tid * 8 + (seg ^ (tid & 7))] = o;
      }
    }
    {   // stage B from cross_w (f32 reg-staged)
      const int kbt = tid >> 4, jb = tid & 15;
      const float* bp = cw + (size_t)(d0 + kbt * 4) * DIM + jg0 + jb * 4;
      fx4 r0v = *(const fx4*)bp;
      fx4 r1v = *(const fx4*)(bp + DIM);
      fx4 r2v = *(const fx4*)(bp + 2 * DIM);
      fx4 r3v = *(const fx4*)(bp + 3 * DIM);
      #pragma unroll
      for (int jj = 0; jj < 4; jj++) {
        ux2 val;
        val[0] = cvt_pk(r0v[jj], r1v[jj]);
        val[1] = cvt_pk(r2v[jj], r3v[jj]);
        const int col = jb * 4 + jj;
        Bsh[(col * 8 + ((kbt >> 1) ^ (col & 7))) * 2 + (kbt & 1)] = val;
      }
    }
    __syncthreads();
    #pragma unroll
    for (int ks = 0; ks < 2; ks++) {
      s8v a[4], b[4];
      const int seg = ks * 4 + lhi;
      #pragma unroll
      for (int m = 0; m < 4; m++) {
        const int row = wave * 64 + m * 16 + l16;
        V16 v; v.u = Ash[row * 8 + (seg ^ (row & 7))]; a[m] = v.s;
      }
      #pragma unroll
      for (int n = 0; n < 4; n++) {
        const int col = n * 16 + l16;
        V16 v; v.u = ((const ux4*)Bsh)[col * 8 + (seg ^ (col & 7))]; b[n] = v.s;
      }
      #pragma unroll
      for (int m = 0; m < 4; m++)
        #pragma unroll
        for (int n = 0; n < 4; n++)
          acc[m][n] = __builtin_amdgcn_mfma_f32_16x16x32_bf16(a[m], b[n], acc[m][n], 0, 0, 0);
    }
    __syncthreads();
  }

  #pragma unroll
  for (int m = 0; m < 4; m++)
    #pragma unroll
    for (int n = 0; n < 4; n++) {
      const int gcol = jg0 + n * 16 + l16;
      #pragma unroll
      for (int i = 0; i < 4; i++) {
        const int lrow = wave * 64 + m * 16 + lhi * 4 + i;
        const size_t idx = (size_t)(base + lrow) * DIM + gcol;
        out[idx] = acc[m][n][i] + x[idx] + cb[gcol];
      }
    }
}

// ---------------------------------------------------------------------------
extern "C" void kernel_launch(void* const* d_in, const int* in_sizes, int n_in,
                              void* d_out, int out_size, void* d_ws, size_t ws_size,
                              hipStream_t stream)
{
  (void)in_sizes; (void)n_in; (void)out_size; (void)ws_size;
  const float* x      = (const float*)d_in[0];
  const float* gate_w = (const float*)d_in[1];   // [2,16,1024]
  const float* temp   = (const float*)d_in[2];   // [2]
  const float* w1     = (const float*)d_in[3];   // [16,1024,4096]
  const float* b1     = (const float*)d_in[4];
  const float* w2     = (const float*)d_in[5];   // [16,4096,1024]
  const float* b2     = (const float*)d_in[6];
  const float* cw     = (const float*)d_in[7];   // [1024,1024]
  const float* cb     = (const float*)d_in[8];
  const void*  mask1  = d_in[9];
  const void*  mask2  = d_in[10];
  const void*  cmask  = d_in[11];
  float* out = (float*)d_out;
  char* ws = (char*)d_ws;

  size_t off = 0;
  auto walloc = [&](size_t b) { size_t r = off; off = (off + b + 255) & ~(size_t)255; return r; };
  size_t o_meta = walloc(4096);
  size_t o_t2i  = walloc((size_t)NTOK * 2 * 4);
  size_t o_t2w  = walloc((size_t)NTOK * 2 * 4);
  size_t o_t2r  = walloc((size_t)NTOK * 2 * 4);
  size_t o_tok  = walloc((size_t)ROWS_CAP * 4);
  size_t o_x8   = walloc((size_t)NTOK * DIM);            // 8 MB (fp8)
  size_t o_y    = walloc((size_t)ROWS_CAP * DIM * 2);    // 40 MB (bf16)
  size_t o_hc   = walloc((size_t)ROWS_CAP * HID);        // 84 MB (fp8)

  int*                meta = (int*)(ws + o_meta);
  int*                t2i  = (int*)(ws + o_t2i);
  float*              t2w  = (float*)(ws + o_t2w);
  int*                t2r  = (int*)(ws + o_t2r);
  int*                tok  = (int*)(ws + o_tok);
  unsigned char*      x8   = (unsigned char*)(ws + o_x8);
  unsigned short*     yb   = (unsigned short*)(ws + o_y);
  unsigned char*      h8   = (unsigned char*)(ws + o_hc);

  hipMemsetAsync(ws + o_meta, 0, 4096, stream);

  k_route  <<<NTOK / 32, 256, 0, stream>>>(x, gate_w + (size_t)1 * NEXP * DIM, temp + 1,
                                           (const unsigned int*)mask1, t2i, t2w, meta, x8);
  k_offsets<<<1, 256, 0, stream>>>(meta, tok);
  k_assign <<<NTOK / 256, 256, 0, stream>>>(t2i, t2w, meta, tok, t2r);

  const int NRT = ROWS_CAP / BM;   // 80
  k_gemm1<<<NRT * 64, 256, 0, stream>>>(x8, w1, b1, mask1, meta, tok, h8);
  k_gemm2<<<NRT * 16, 256, 0, stream>>>(h8, w2, b2, mask2, meta, yb);
  k_cross<<<(NTOK / BM) * 16, 256, 0, stream>>>(yb, x, cw, cb, cmask, meta, t2r, t2w, out);
}

// Round 13
// 345.788 us; speedup vs baseline: 2.2434x; 1.0175x over previous
//
#include <hip/hip_runtime.h>

// ---------------------------------------------------------------------------
// HierarchicalSparseLayer: top-2 MoE with block-sparse (64x64) masked weights
// B=8192 tokens, D=1024, H=4096, E=16 experts, K=2, + block-sparse cross proj.
// R13: R12 + occupancy round: gemm1/gemm2 at (256,4) (40 KB LDS x4 = 160 KB),
//      cross rebuilt at BM=128 (R5 structure, 24 KB LDS, grid 1024, (256,4)).
// ---------------------------------------------------------------------------

#define NTOK 8192
#define DIM  1024
#define HID  4096
#define NEXP 16
#define BM   256
#define ROWS_CAP (NTOK*2 + NEXP*256)   // 20480

typedef __attribute__((ext_vector_type(4))) float fx4;
typedef __attribute__((ext_vector_type(4))) unsigned int ux4;
typedef __attribute__((ext_vector_type(2))) unsigned int ux2;
typedef __attribute__((ext_vector_type(8))) short s8v;
union V16 { ux4 u; s8v s; };

__device__ __forceinline__ unsigned int f2bf(float f) {
  unsigned int u = __float_as_uint(f);
  return (u + 0x7fffu + ((u >> 16) & 1u)) >> 16;   // RNE, inputs finite
}

__device__ __forceinline__ unsigned int cvt_pk(float lo, float hi) {
  unsigned int r;
  asm("v_cvt_pk_bf16_f32 %0, %1, %2" : "=v"(r) : "v"(lo), "v"(hi));
  return r;
}

__device__ __forceinline__ unsigned int f2fp8(float v) {
  return (unsigned int)__builtin_amdgcn_cvt_pk_fp8_f32(v, v, 0, false) & 0xFFu;
}

// pack 4 f32 (scaled) into one u32 of 4 fp8 e4m3
__device__ __forceinline__ unsigned int pk4fp8(float a, float b, float c, float d) {
  unsigned int u = (unsigned int)__builtin_amdgcn_cvt_pk_fp8_f32(a, b, 0, false);
  u = (unsigned int)__builtin_amdgcn_cvt_pk_fp8_f32(c, d, (int)u, true);
  return u;
}

// Mask dtype detected at runtime: flag 0=u8, 1=i32, 2=f32
__device__ __forceinline__ bool mask_at(const void* m, int flag, size_t idx) {
  if (flag == 0) return ((const unsigned char*)m)[idx] != 0;
  if (flag == 1) return ((const int*)m)[idx] != 0;
  return ((const float*)m)[idx] != 0.0f;
}

__device__ __forceinline__ int flag_of(int ev) {
  return (ev & 2) ? 2 : ((ev & 1) ? 0 : 1);
}

// XCD-aware swizzle (grid % 8 == 0)
__device__ __forceinline__ int xcd_swz() {
  const int b = blockIdx.x, cpx = gridDim.x >> 3;
  return (b & 7) * cpx + (b >> 3);
}

// --------------------------- routing (+ detect + x->fp8 pack) ---------------
// meta: [1]=detect bits [8..23]=counts [32..47]=offsets [48]=total
//       [64..79]=slot counters [96..175]=expert_of_rt
__global__ void k_route(const float* __restrict__ x,
                        const float* __restrict__ gw,    // gate_w[-1] [16,1024]
                        const float* __restrict__ temp,
                        const unsigned int* __restrict__ m1raw,
                        int* __restrict__ top2i, float* __restrict__ top2w,
                        int* __restrict__ meta, unsigned char* __restrict__ x8)
{
  if (blockIdx.x < 64) {     // fold k_detect
    int bits = 0;
    size_t base = (size_t)blockIdx.x * 4096 + threadIdx.x;
    for (int j = 0; j < 16; j++) {
      unsigned int v = m1raw[base + 256 * j];
      if (v == 0x3f800000u) bits |= 2;
      else if (v > 1u)      bits |= 1;
    }
    if (bits) atomicOr(&meta[1], bits);
  }

  __shared__ float gwsh[NEXP * DIM];
  for (int i = threadIdx.x; i < NEXP * DIM; i += 256) gwsh[i] = gw[i];
  __syncthreads();

  const int wv = threadIdx.x >> 6;
  const int l = threadIdx.x & 63;
  #pragma unroll
  for (int tt = 0; tt < 8; tt++) {
    const int t = blockIdx.x * 32 + wv * 8 + tt;
    const float* xr = x + (size_t)t * DIM;
    float xv[16];
    #pragma unroll
    for (int j = 0; j < 16; j++) xv[j] = xr[l + 64 * j];
    float logit[16];
    #pragma unroll
    for (int e = 0; e < 16; e++) {
      const float* g = gwsh + e * DIM;
      float s = 0.f;
      #pragma unroll
      for (int j = 0; j < 16; j++) s += xv[j] * g[l + 64 * j];
      #pragma unroll
      for (int o = 32; o >= 1; o >>= 1) s += __shfl_xor(s, o);
      logit[e] = s;
    }
    if (l == 0) {
      const float tinv = 1.0f / temp[0];
      int i0 = 0; float v0 = logit[0] * tinv;
      #pragma unroll
      for (int e = 1; e < 16; e++) { float v = logit[e] * tinv; if (v > v0) { v0 = v; i0 = e; } }
      int i1 = -1; float v1 = 0.f; bool first = true;
      #pragma unroll
      for (int e = 0; e < 16; e++) {
        if (e == i0) continue;
        float v = logit[e] * tinv;
        if (first || v > v1) { v1 = v; i1 = e; first = false; }
      }
      float ex = __expf(v1 - v0);
      float den = 1.0f + ex;
      top2i[2 * t] = i0; top2i[2 * t + 1] = i1;
      top2w[2 * t] = 1.0f / den; top2w[2 * t + 1] = ex / den;
      atomicAdd(&meta[8 + i0], 1);
      atomicAdd(&meta[8 + i1], 1);
    }
  }

  // pack this block's 32 tokens to fp8 (x16 scale); slab is L1/L2-hot
  {
    const size_t be = (size_t)blockIdx.x * 32 * DIM;
    const fx4* src = (const fx4*)(x + be);
    ux4* dst = (ux4*)(x8 + be);          // 2048 ux4 per block
    #pragma unroll
    for (int i = 0; i < 8; i++) {
      const int idx = i * 256 + threadIdx.x;
      fx4 a = src[4 * idx], b = src[4 * idx + 1];
      fx4 c = src[4 * idx + 2], d = src[4 * idx + 3];
      ux4 o;
      o[0] = pk4fp8(a[0] * 16.f, a[1] * 16.f, a[2] * 16.f, a[3] * 16.f);
      o[1] = pk4fp8(b[0] * 16.f, b[1] * 16.f, b[2] * 16.f, b[3] * 16.f);
      o[2] = pk4fp8(c[0] * 16.f, c[1] * 16.f, c[2] * 16.f, c[3] * 16.f);
      o[3] = pk4fp8(d[0] * 16.f, d[1] * 16.f, d[2] * 16.f, d[3] * 16.f);
      dst[idx] = o;
    }
  }
}

// offsets + expert_of_rt + pad-row init (replaces tok memset)
__global__ void k_offsets(int* __restrict__ meta, int* __restrict__ tok_of_row) {
  if (threadIdx.x == 0) {
    int o = 0;
    for (int e = 0; e < 16; e++) { meta[32 + e] = o; o += (meta[8 + e] + 255) & ~255; }
    meta[48] = o;
    for (int rt = 0; rt < ROWS_CAP / BM; rt++) {
      const int base = rt * BM;
      int e = 0;
      for (int i = 1; i < 16; i++) if (meta[32 + i] <= base) e = i;
      meta[96 + rt] = e;
    }
  }
  __syncthreads();
  const int total = meta[48];
  for (int r = threadIdx.x; r < total; r += 256) {
    const int e = meta[96 + r / BM];
    if (r >= meta[32 + e] + meta[8 + e]) tok_of_row[r] = -1;
  }
}

__global__ void k_assign(const int* __restrict__ top2i,
                         const float* __restrict__ top2w,
                         int* __restrict__ meta, int* __restrict__ tok_of_row,
                         int* __restrict__ t2row)
{
  int t = blockIdx.x * 256 + threadIdx.x;
  if (t >= NTOK) return;
  #pragma unroll
  for (int k = 0; k < 2; k++) {
    int e = top2i[2 * t + k];
    int slot = atomicAdd(&meta[64 + e], 1);
    int row = meta[32 + e] + slot;
    tok_of_row[row] = t;
    t2row[2 * t + k] = row;
  }
}

// --------------------------- GEMM 1: h8 = fp8(8*silu(x8 @ w1fp8/256 + b1)) --
// Full fp8: A via global_load_lds (chunk swizzle on source), B w1 f32->fp8 x16
// reg-staged, fp8 MFMA, 40 KB LDS -> 4 blocks/CU.
__global__ __launch_bounds__(256, 4)
void k_gemm1(const unsigned char* __restrict__ x8,
             const float* __restrict__ w1, const float* __restrict__ b1,
             const void* __restrict__ mask1,
             const int* __restrict__ meta, const int* __restrict__ tok_of_row,
             unsigned char* __restrict__ h8)
{
  __shared__ ux4 Ash[2][1024];                        // 2 x 16 KB (256 rows x 64 B)
  __shared__ __align__(16) unsigned int Bsh[2][1024]; // 2 x 4 KB

  const int bid = xcd_swz();
  const int rt = bid >> 6, ct = bid & 63;       // NCT = 64
  const int base = rt * BM;
  if (base >= meta[48]) return;
  const int e = meta[96 + rt];

  const int tid = threadIdx.x;
  const int wv = tid >> 6;
  const int jg0 = ct * 64;
  const int l = tid & 63, l16 = l & 15, lhi = l >> 4;

  unsigned int bits;
  {
    const int flag = flag_of(meta[1]);
    bool on = false;
    if (l < 16)
      on = mask_at(mask1, flag, (size_t)e * DIM * HID + (size_t)l * 64 * HID + jg0);
    bits = (unsigned int)(__ballot(on) & 0xFFFFull);
  }

  // A source offsets: row = i*64 + (tid>>2), gathered; stored chunk
  // (tid&3) ^ ((row>>1)&3) pre-applied on source
  const unsigned int sw = (unsigned int)((tid & 3) ^ ((tid >> 3) & 3));
  unsigned int aoff[4];
  #pragma unroll
  for (int i = 0; i < 4; i++) {
    int tok = tok_of_row[base + i * 64 + (tid >> 2)];
    if (tok < 0) tok = 0;                       // pad rows: finite garbage, unused
    aoff[i] = (unsigned int)tok * (unsigned int)DIM + sw * 16;
  }

  const int kb = tid >> 4, jb = tid & 15;

  fx4 acc[4][4] = {};

  auto STAGE_A = [&](int b, int d0) {
    const char* gp = (const char*)x8 + d0;
    #pragma unroll
    for (int i = 0; i < 4; i++)
      __builtin_amdgcn_global_load_lds(
        (const __attribute__((address_space(1))) unsigned int*)(gp + aoff[i]),
        (__attribute__((address_space(3))) unsigned int*)&Ash[b][i * 256 + wv * 64],
        16, 0, 0);
  };
  auto LOAD_B = [&](fx4* r, int d0) {
    const float* bp = w1 + ((size_t)e * DIM + d0 + kb * 4) * HID + jg0 + jb * 4;
    r[0] = *(const fx4*)bp;
    r[1] = *(const fx4*)(bp + HID);
    r[2] = *(const fx4*)(bp + 2 * HID);
    r[3] = *(const fx4*)(bp + 3 * HID);
  };
  auto WRITE_B = [&](int b, const fx4* r) {
    #pragma unroll
    for (int jj = 0; jj < 4; jj++) {
      const int col = jb * 4 + jj;
      unsigned int u = pk4fp8(r[0][jj] * 16.0f, r[1][jj] * 16.0f,
                              r[2][jj] * 16.0f, r[3][jj] * 16.0f);
      Bsh[b][col * 16 + (((kb >> 2) ^ ((col >> 1) & 3)) << 2) + (kb & 3)] = u;
    }
  };
  auto COMPUTE = [&](int b) {
    const char* Ab = (const char*)&Ash[b][0];
    const char* Bb = (const char*)&Bsh[b][0];
    #pragma unroll
    for (int ks = 0; ks < 2; ks++) {
      const int c = ks * 2 + (lhi >> 1);
      const int sub = (lhi & 1) << 3;
      long long a[4], bb[4];
      #pragma unroll
      for (int m = 0; m < 4; m++) {
        const int row = wv * 64 + m * 16 + l16;
        a[m] = *(const long long*)(Ab + row * 64 + ((c ^ ((row >> 1) & 3)) << 4) + sub);
      }
      #pragma unroll
      for (int n = 0; n < 4; n++) {
        const int col = n * 16 + l16;
        bb[n] = *(const long long*)(Bb + col * 64 + ((c ^ ((col >> 1) & 3)) << 4) + sub);
      }
      #pragma unroll
      for (int m = 0; m < 4; m++)
        #pragma unroll
        for (int n = 0; n < 4; n++)
          acc[m][n] = __builtin_amdgcn_mfma_f32_16x16x32_fp8_fp8(a[m], bb[n], acc[m][n], 0, 0, 0);
    }
  };

  if (bits) {
    int d0 = (__ffs(bits) - 1) << 6; bits &= bits - 1;
    {
      fx4 br[4];
      STAGE_A(0, d0);
      LOAD_B(br, d0);
      WRITE_B(0, br);
    }
    __syncthreads();
    int cur = 0;
    for (;;) {
      int nd0 = -1;
      fx4 br2[4];
      if (bits) { nd0 = (__ffs(bits) - 1) << 6; bits &= bits - 1; }
      if (nd0 >= 0) { STAGE_A(cur ^ 1, nd0); LOAD_B(br2, nd0); }
      COMPUTE(cur);
      if (nd0 >= 0) WRITE_B(cur ^ 1, br2);
      __syncthreads();
      cur ^= 1;
      if (nd0 < 0) break;
    }
  }

  // epilogue: h = fp8(8 * silu(acc/256 + b1)) -> LDS byte tile -> 16B dump
  unsigned char* hs = (unsigned char*)&Ash[0][0];   // 16 KB tile
  __syncthreads();
  #pragma unroll
  for (int m = 0; m < 4; m++)
    #pragma unroll
    for (int n = 0; n < 4; n++) {
      const int gcol = jg0 + n * 16 + l16;
      const float bbv = b1[e * HID + gcol];
      #pragma unroll
      for (int i = 0; i < 4; i++) {
        const int row = wv * 64 + m * 16 + lhi * 4 + i;
        float v = acc[m][n][i] * 0.00390625f + bbv;
        float hval = v / (1.0f + __expf(-v));
        hs[row * 64 + n * 16 + l16] = (unsigned char)f2fp8(hval * 8.0f);
      }
    }
  __syncthreads();
  {
    const ux4* s = (const ux4*)hs;
    #pragma unroll
    for (int j = 0; j < 4; j++) {
      const int c2 = j * 256 + tid;
      const int row = c2 >> 2;
      *(ux4*)(h8 + (size_t)(base + row) * HID + ct * 64 + (c2 & 3) * 16) = s[c2];
    }
  }
}

// --------------------------- GEMM 2: y = bf16(h8 @ w2fp8 / 128 + b2) --------
__global__ __launch_bounds__(256, 4)
void k_gemm2(const unsigned char* __restrict__ h8,
             const float* __restrict__ w2, const float* __restrict__ b2,
             const void* __restrict__ mask2,
             const int* __restrict__ meta, unsigned short* __restrict__ yb)
{
  __shared__ ux4 Ash[2][1024];                       // 2 x 16 KB (256 rows x 64 B)
  __shared__ __align__(16) unsigned int Bsh[2][1024]; // 2 x 4 KB (64 cols x 64 B)

  const int bid = xcd_swz();
  const int rt = bid >> 4, ct = bid & 15;       // NCT = 16
  const int base = rt * BM;
  if (base >= meta[48]) return;
  const int e = meta[96 + rt];

  const int tid = threadIdx.x;
  const int wv = tid >> 6;
  const int jg0 = ct * 64;

  const int l = tid & 63, l16 = l & 15, lhi = l >> 4;
  unsigned long long bits;
  {
    const int flag = flag_of(meta[1]);
    bits = __ballot(mask_at(mask2, flag,
             (size_t)e * HID * DIM + (size_t)l * 64 * DIM + jg0));
  }

  const unsigned int sw = (unsigned int)((tid & 3) ^ ((tid >> 3) & 3));
  unsigned int aoff[4];
  #pragma unroll
  for (int i = 0; i < 4; i++)
    aoff[i] = (unsigned int)(base + i * 64 + (tid >> 2)) * (unsigned int)HID + sw * 16;

  const int kb = tid >> 4, jb = tid & 15;

  fx4 acc[4][4] = {};

  auto STAGE_A = [&](int b, int d0) {
    const char* gp = (const char*)h8 + d0;
    #pragma unroll
    for (int i = 0; i < 4; i++)
      __builtin_amdgcn_global_load_lds(
        (const __attribute__((address_space(1))) unsigned int*)(gp + aoff[i]),
        (__attribute__((address_space(3))) unsigned int*)&Ash[b][i * 256 + wv * 64],
        16, 0, 0);
  };
  auto LOAD_B = [&](fx4* r, int d0) {
    const float* bp = w2 + ((size_t)e * HID + d0 + kb * 4) * DIM + jg0 + jb * 4;
    r[0] = *(const fx4*)bp;
    r[1] = *(const fx4*)(bp + DIM);
    r[2] = *(const fx4*)(bp + 2 * DIM);
    r[3] = *(const fx4*)(bp + 3 * DIM);
  };
  auto WRITE_B = [&](int b, const fx4* r) {
    #pragma unroll
    for (int jj = 0; jj < 4; jj++) {
      const int col = jb * 4 + jj;
      unsigned int u = pk4fp8(r[0][jj] * 16.0f, r[1][jj] * 16.0f,
                              r[2][jj] * 16.0f, r[3][jj] * 16.0f);
      Bsh[b][col * 16 + (((kb >> 2) ^ ((col >> 1) & 3)) << 2) + (kb & 3)] = u;
    }
  };
  auto COMPUTE = [&](int b) {
    const char* Ab = (const char*)&Ash[b][0];
    const char* Bb = (const char*)&Bsh[b][0];
    #pragma unroll
    for (int ks = 0; ks < 2; ks++) {
      const int c = ks * 2 + (lhi >> 1);
      const int sub = (lhi & 1) << 3;
      long long a[4], bb[4];
      #pragma unroll
      for (int m = 0; m < 4; m++) {
        const int row = wv * 64 + m * 16 + l16;
        a[m] = *(const long long*)(Ab + row * 64 + ((c ^ ((row >> 1) & 3)) << 4) + sub);
      }
      #pragma unroll
      for (int n = 0; n < 4; n++) {
        const int col = n * 16 + l16;
        bb[n] = *(const long long*)(Bb + col * 64 + ((c ^ ((col >> 1) & 3)) << 4) + sub);
      }
      #pragma unroll
      for (int m = 0; m < 4; m++)
        #pragma unroll
        for (int n = 0; n < 4; n++)
          acc[m][n] = __builtin_amdgcn_mfma_f32_16x16x32_fp8_fp8(a[m], bb[n], acc[m][n], 0, 0, 0);
    }
  };

  if (bits) {
    int d0 = (__ffsll(bits) - 1) << 6; bits &= bits - 1;
    {
      fx4 br[4];
      STAGE_A(0, d0);
      LOAD_B(br, d0);
      WRITE_B(0, br);
    }
    __syncthreads();
    int cur = 0;
    for (;;) {
      int nd0 = -1;
      fx4 br2[4];
      if (bits) { nd0 = (__ffsll(bits) - 1) << 6; bits &= bits - 1; }
      if (nd0 >= 0) { STAGE_A(cur ^ 1, nd0); LOAD_B(br2, nd0); }
      COMPUTE(cur);
      if (nd0 >= 0) WRITE_B(cur ^ 1, br2);
      __syncthreads();
      cur ^= 1;
      if (nd0 < 0) break;
    }
  }

  // epilogue: y = bf16(acc/128 + b2), restaged via LDS (Ash = 32 KB)
  unsigned short* hs = (unsigned short*)&Ash[0][0];
  __syncthreads();
  #pragma unroll
  for (int m = 0; m < 4; m++)
    #pragma unroll
    for (int n = 0; n < 4; n++) {
      const int gcol = jg0 + n * 16 + l16;
      const float bbv = b2[e * DIM + gcol];
      #pragma unroll
      for (int i = 0; i < 4; i++) {
        const int row = wv * 64 + m * 16 + lhi * 4 + i;
        hs[row * 64 + n * 16 + l16] =
            (unsigned short)f2bf(acc[m][n][i] * 0.0078125f + bbv);
      }
    }
  __syncthreads();
  {
    const ux4* s = (const ux4*)hs;
    #pragma unroll
    for (int j = 0; j < 8; j++) {
      const int c2 = j * 256 + tid;
      const int row = c2 >> 3;
      *(ux4*)(yb + (size_t)(base + row) * DIM + ct * 64 + (c2 & 7) * 8) = s[c2];
    }
  }
}

// --------------------------- cross: out = x + eo @ cwm + cb -----------------
// BM=128 (R5 structure): 4 waves in 2x2 grid, acc[4][2], 24 KB LDS, grid 1024.
// eo rows formed on the fly from bf16 y: eo[tok] = w0*y[r0] + w1*y[r1]
__global__ __launch_bounds__(256, 4)
void k_cross(const unsigned short* __restrict__ yb, const float* __restrict__ x,
             const float* __restrict__ cw, const float* __restrict__ cb,
             const void* __restrict__ cmask, const int* __restrict__ meta,
             const int* __restrict__ t2row, const float* __restrict__ t2w,
             float* __restrict__ out)
{
  __shared__ ux4 Ash[1024];                  // 128 rows x 64 k bf16 = 16 KB
  __shared__ __align__(16) ux2 Bsh[1024];    // 8 KB

  const int bid = xcd_swz();
  const int rt = bid >> 4, ct = bid & 15;    // 64 row tiles x 16 col tiles
  const int base = rt * 128;
  const int tid = threadIdx.x;
  const int wv = tid >> 6;
  const int wr = wv >> 1, wc = wv & 1;
  const int jg0 = ct * 64;

  const int l = tid & 63, l16 = l & 15, lhi = l >> 4;

  unsigned int bits;
  {
    const int flag = flag_of(meta[1]);
    bool on = false;
    if (l < 16)
      on = mask_at(cmask, flag, (size_t)l * 64 * DIM + jg0);
    bits = (unsigned int)(__ballot(on) & 0xFFFFull);
  }

  const int arow = tid >> 1, sub = tid & 1;
  const int r0 = t2row[2 * (base + arow)], r1 = t2row[2 * (base + arow) + 1];
  const float w0 = t2w[2 * (base + arow)], w1 = t2w[2 * (base + arow) + 1];

  fx4 acc[4][2] = {};

  while (bits) {
    const int kbx = __ffs(bits) - 1; bits &= bits - 1;
    const int d0 = kbx * 64;
    {   // stage A: combine two bf16 pair rows -> bf16 (swizzled ds_write)
      const ux4* s0 = (const ux4*)(yb + (size_t)r0 * DIM + d0);
      const ux4* s1 = (const ux4*)(yb + (size_t)r1 * DIM + d0);
      #pragma unroll
      for (int s = 0; s < 4; s++) {
        const int seg = sub * 4 + s;
        ux4 v0 = s0[seg], v1 = s1[seg], o;
        #pragma unroll
        for (int j = 0; j < 4; j++) {
          float alo = __uint_as_float(v0[j] << 16);
          float ahi = __uint_as_float(v0[j] & 0xFFFF0000u);
          float blo = __uint_as_float(v1[j] << 16);
          float bhi = __uint_as_float(v1[j] & 0xFFFF0000u);
          o[j] = cvt_pk(w0 * alo + w1 * blo, w0 * ahi + w1 * bhi);
        }
        Ash[arow * 8 + (seg ^ (arow & 7))] = o;
      }
    }
    {   // stage B from cross_w (f32 reg-staged)
      const int kbt = tid >> 4, jb = tid & 15;
      const float* bp = cw + (size_t)(d0 + kbt * 4) * DIM + jg0 + jb * 4;
      fx4 r0v = *(const fx4*)bp;
      fx4 r1v = *(const fx4*)(bp + DIM);
      fx4 r2v = *(const fx4*)(bp + 2 * DIM);
      fx4 r3v = *(const fx4*)(bp + 3 * DIM);
      #pragma unroll
      for (int jj = 0; jj < 4; jj++) {
        ux2 val;
        val[0] = cvt_pk(r0v[jj], r1v[jj]);
        val[1] = cvt_pk(r2v[jj], r3v[jj]);
        const int col = jb * 4 + jj;
        Bsh[(col * 8 + ((kbt >> 1) ^ (col & 7))) * 2 + (kbt & 1)] = val;
      }
    }
    __syncthreads();
    #pragma unroll
    for (int ks = 0; ks < 2; ks++) {
      s8v a[4], b[2];
      const int seg = ks * 4 + lhi;
      #pragma unroll
      for (int m = 0; m < 4; m++) {
        const int row = wr * 64 + m * 16 + l16;
        V16 v; v.u = Ash[row * 8 + (seg ^ (row & 7))]; a[m] = v.s;
      }
      #pragma unroll
      for (int n = 0; n < 2; n++) {
        const int col = wc * 32 + n * 16 + l16;
        V16 v; v.u = ((const ux4*)Bsh)[col * 8 + (seg ^ (col & 7))]; b[n] = v.s;
      }
      #pragma unroll
      for (int m = 0; m < 4; m++)
        #pragma unroll
        for (int n = 0; n < 2; n++)
          acc[m][n] = __builtin_amdgcn_mfma_f32_16x16x32_bf16(a[m], b[n], acc[m][n], 0, 0, 0);
    }
    __syncthreads();
  }

  #pragma unroll
  for (int m = 0; m < 4; m++)
    #pragma unroll
    for (int n = 0; n < 2; n++) {
      const int gcol = jg0 + wc * 32 + n * 16 + l16;
      #pragma unroll
      for (int i = 0; i < 4; i++) {
        const int row = wr * 64 + m * 16 + lhi * 4 + i;
        const size_t idx = (size_t)(base + row) * DIM + gcol;
        out[idx] = acc[m][n][i] + x[idx] + cb[gcol];
      }
    }
}

// ---------------------------------------------------------------------------
extern "C" void kernel_launch(void* const* d_in, const int* in_sizes, int n_in,
                              void* d_out, int out_size, void* d_ws, size_t ws_size,
                              hipStream_t stream)
{
  (void)in_sizes; (void)n_in; (void)out_size; (void)ws_size;
  const float* x      = (const float*)d_in[0];
  const float* gate_w = (const float*)d_in[1];   // [2,16,1024]
  const float* temp   = (const float*)d_in[2];   // [2]
  const float* w1     = (const float*)d_in[3];   // [16,1024,4096]
  const float* b1     = (const float*)d_in[4];
  const float* w2     = (const float*)d_in[5];   // [16,4096,1024]
  const float* b2     = (const float*)d_in[6];
  const float* cw     = (const float*)d_in[7];   // [1024,1024]
  const float* cb     = (const float*)d_in[8];
  const void*  mask1  = d_in[9];
  const void*  mask2  = d_in[10];
  const void*  cmask  = d_in[11];
  float* out = (float*)d_out;
  char* ws = (char*)d_ws;

  size_t off = 0;
  auto walloc = [&](size_t b) { size_t r = off; off = (off + b + 255) & ~(size_t)255; return r; };
  size_t o_meta = walloc(4096);
  size_t o_t2i  = walloc((size_t)NTOK * 2 * 4);
  size_t o_t2w  = walloc((size_t)NTOK * 2 * 4);
  size_t o_t2r  = walloc((size_t)NTOK * 2 * 4);
  size_t o_tok  = walloc((size_t)ROWS_CAP * 4);
  size_t o_x8   = walloc((size_t)NTOK * DIM);            // 8 MB (fp8)
  size_t o_y    = walloc((size_t)ROWS_CAP * DIM * 2);    // 40 MB (bf16)
  size_t o_hc   = walloc((size_t)ROWS_CAP * HID);        // 84 MB (fp8)

  int*                meta = (int*)(ws + o_meta);
  int*                t2i  = (int*)(ws + o_t2i);
  float*              t2w  = (float*)(ws + o_t2w);
  int*                t2r  = (int*)(ws + o_t2r);
  int*                tok  = (int*)(ws + o_tok);
  unsigned char*      x8   = (unsigned char*)(ws + o_x8);
  unsigned short*     yb   = (unsigned short*)(ws + o_y);
  unsigned char*      h8   = (unsigned char*)(ws + o_hc);

  hipMemsetAsync(ws + o_meta, 0, 4096, stream);

  k_route  <<<NTOK / 32, 256, 0, stream>>>(x, gate_w + (size_t)1 * NEXP * DIM, temp + 1,
                                           (const unsigned int*)mask1, t2i, t2w, meta, x8);
  k_offsets<<<1, 256, 0, stream>>>(meta, tok);
  k_assign <<<NTOK / 256, 256, 0, stream>>>(t2i, t2w, meta, tok, t2r);

  const int NRT = ROWS_CAP / BM;   // 80
  k_gemm1<<<NRT * 64, 256, 0, stream>>>(x8, w1, b1, mask1, meta, tok, h8);
  k_gemm2<<<NRT * 16, 256, 0, stream>>>(h8, w2, b2, mask2, meta, yb);
  k_cross<<<(NTOK / 128) * 16, 256, 0, stream>>>(yb, x, cw, cb, cmask, meta, t2r, t2w, out);
}

// Round 14
// 336.423 us; speedup vs baseline: 2.3059x; 1.0278x over previous
//
#include <hip/hip_runtime.h>

// ---------------------------------------------------------------------------
// HierarchicalSparseLayer: top-2 MoE with block-sparse (64x64) masked weights
// B=8192 tokens, D=1024, H=4096, E=16 experts, K=2, + block-sparse cross proj.
// R14: R13 + active w1/w2 blocks pre-cast once to fp8 (x16) in the EXACT
//      swizzled LDS B-image layout; B staging = one global_load_lds issue
//      (no f32 loads / cvt / ds_write in the hot loop).
// ---------------------------------------------------------------------------

#define NTOK 8192
#define DIM  1024
#define HID  4096
#define NEXP 16
#define BM   256
#define ROWS_CAP (NTOK*2 + NEXP*256)   // 20480

typedef __attribute__((ext_vector_type(4))) float fx4;
typedef __attribute__((ext_vector_type(4))) unsigned int ux4;
typedef __attribute__((ext_vector_type(2))) unsigned int ux2;
typedef __attribute__((ext_vector_type(8))) short s8v;
union V16 { ux4 u; s8v s; };

__device__ __forceinline__ unsigned int f2bf(float f) {
  unsigned int u = __float_as_uint(f);
  return (u + 0x7fffu + ((u >> 16) & 1u)) >> 16;   // RNE, inputs finite
}

__device__ __forceinline__ unsigned int cvt_pk(float lo, float hi) {
  unsigned int r;
  asm("v_cvt_pk_bf16_f32 %0, %1, %2" : "=v"(r) : "v"(lo), "v"(hi));
  return r;
}

__device__ __forceinline__ unsigned int f2fp8(float v) {
  return (unsigned int)__builtin_amdgcn_cvt_pk_fp8_f32(v, v, 0, false) & 0xFFu;
}

// pack 4 f32 (scaled) into one u32 of 4 fp8 e4m3
__device__ __forceinline__ unsigned int pk4fp8(float a, float b, float c, float d) {
  unsigned int u = (unsigned int)__builtin_amdgcn_cvt_pk_fp8_f32(a, b, 0, false);
  u = (unsigned int)__builtin_amdgcn_cvt_pk_fp8_f32(c, d, (int)u, true);
  return u;
}

// Mask dtype detected at runtime: flag 0=u8, 1=i32, 2=f32
__device__ __forceinline__ bool mask_at(const void* m, int flag, size_t idx) {
  if (flag == 0) return ((const unsigned char*)m)[idx] != 0;
  if (flag == 1) return ((const int*)m)[idx] != 0;
  return ((const float*)m)[idx] != 0.0f;
}

__device__ __forceinline__ int flag_of(int ev) {
  return (ev & 2) ? 2 : ((ev & 1) ? 0 : 1);
}

// XCD-aware swizzle (grid % 8 == 0)
__device__ __forceinline__ int xcd_swz() {
  const int b = blockIdx.x, cpx = gridDim.x >> 3;
  return (b & 7) * cpx + (b >> 3);
}

// --------------------------- routing (+ detect + x->fp8 pack) ---------------
// meta: [1]=detect bits [8..23]=counts [32..47]=offsets [48]=total
//       [64..79]=slot counters [96..175]=expert_of_rt
__global__ void k_route(const float* __restrict__ x,
                        const float* __restrict__ gw,    // gate_w[-1] [16,1024]
                        const float* __restrict__ temp,
                        const unsigned int* __restrict__ m1raw,
                        int* __restrict__ top2i, float* __restrict__ top2w,
                        int* __restrict__ meta, unsigned char* __restrict__ x8)
{
  if (blockIdx.x < 64) {     // fold k_detect
    int bits = 0;
    size_t base = (size_t)blockIdx.x * 4096 + threadIdx.x;
    for (int j = 0; j < 16; j++) {
      unsigned int v = m1raw[base + 256 * j];
      if (v == 0x3f800000u) bits |= 2;
      else if (v > 1u)      bits |= 1;
    }
    if (bits) atomicOr(&meta[1], bits);
  }

  __shared__ float gwsh[NEXP * DIM];
  for (int i = threadIdx.x; i < NEXP * DIM; i += 256) gwsh[i] = gw[i];
  __syncthreads();

  const int wv = threadIdx.x >> 6;
  const int l = threadIdx.x & 63;
  #pragma unroll
  for (int tt = 0; tt < 8; tt++) {
    const int t = blockIdx.x * 32 + wv * 8 + tt;
    const float* xr = x + (size_t)t * DIM;
    float xv[16];
    #pragma unroll
    for (int j = 0; j < 16; j++) xv[j] = xr[l + 64 * j];
    float logit[16];
    #pragma unroll
    for (int e = 0; e < 16; e++) {
      const float* g = gwsh + e * DIM;
      float s = 0.f;
      #pragma unroll
      for (int j = 0; j < 16; j++) s += xv[j] * g[l + 64 * j];
      #pragma unroll
      for (int o = 32; o >= 1; o >>= 1) s += __shfl_xor(s, o);
      logit[e] = s;
    }
    if (l == 0) {
      const float tinv = 1.0f / temp[0];
      int i0 = 0; float v0 = logit[0] * tinv;
      #pragma unroll
      for (int e = 1; e < 16; e++) { float v = logit[e] * tinv; if (v > v0) { v0 = v; i0 = e; } }
      int i1 = -1; float v1 = 0.f; bool first = true;
      #pragma unroll
      for (int e = 0; e < 16; e++) {
        if (e == i0) continue;
        float v = logit[e] * tinv;
        if (first || v > v1) { v1 = v; i1 = e; first = false; }
      }
      float ex = __expf(v1 - v0);
      float den = 1.0f + ex;
      top2i[2 * t] = i0; top2i[2 * t + 1] = i1;
      top2w[2 * t] = 1.0f / den; top2w[2 * t + 1] = ex / den;
      atomicAdd(&meta[8 + i0], 1);
      atomicAdd(&meta[8 + i1], 1);
    }
  }

  // pack this block's 32 tokens to fp8 (x16 scale); slab is L1/L2-hot
  {
    const size_t be = (size_t)blockIdx.x * 32 * DIM;
    const fx4* src = (const fx4*)(x + be);
    ux4* dst = (ux4*)(x8 + be);          // 2048 ux4 per block
    #pragma unroll
    for (int i = 0; i < 8; i++) {
      const int idx = i * 256 + threadIdx.x;
      fx4 a = src[4 * idx], b = src[4 * idx + 1];
      fx4 c = src[4 * idx + 2], d = src[4 * idx + 3];
      ux4 o;
      o[0] = pk4fp8(a[0] * 16.f, a[1] * 16.f, a[2] * 16.f, a[3] * 16.f);
      o[1] = pk4fp8(b[0] * 16.f, b[1] * 16.f, b[2] * 16.f, b[3] * 16.f);
      o[2] = pk4fp8(c[0] * 16.f, c[1] * 16.f, c[2] * 16.f, c[3] * 16.f);
      o[3] = pk4fp8(d[0] * 16.f, d[1] * 16.f, d[2] * 16.f, d[3] * 16.f);
      dst[idx] = o;
    }
  }
}

// --------------------------- weight pre-cast to fp8 B-images ----------------
// Active 64x64 block -> 4 KB image == the compute loop's swizzled LDS B
// layout: chunk c (k bytes c*16..c*16+15) of col at col*64+((c^((col>>1)&3))<<4).
__global__ void k_wcast(const float* __restrict__ w1, const float* __restrict__ w2,
                        const void* __restrict__ mask1, const void* __restrict__ mask2,
                        const int* __restrict__ meta,
                        unsigned char* __restrict__ w1p, unsigned char* __restrict__ w2p)
{
  const int flag = flag_of(meta[1]);
  const int gid = blockIdx.x;
  const int tid = threadIdx.x;
  const int c = tid >> 6, col = tid & 63;

  if (gid < 16384) {                 // w1: panel p = gid>>4 (= e*64+ct), kb = gid&15
    const int p = gid >> 4, kb = gid & 15;
    const int e = p >> 6, ct = p & 63;
    if (!mask_at(mask1, flag, (size_t)e * DIM * HID + (size_t)kb * 64 * HID + ct * 64)) return;
    const float* src = w1 + ((size_t)e * DIM + kb * 64 + c * 16) * HID + ct * 64 + col;
    ux4 v;
    #pragma unroll
    for (int q = 0; q < 4; q++) {
      float f0 = src[(size_t)(q * 4 + 0) * HID], f1 = src[(size_t)(q * 4 + 1) * HID];
      float f2 = src[(size_t)(q * 4 + 2) * HID], f3 = src[(size_t)(q * 4 + 3) * HID];
      v[q] = pk4fp8(f0 * 16.f, f1 * 16.f, f2 * 16.f, f3 * 16.f);
    }
    *(ux4*)(w1p + ((size_t)gid << 12) + col * 64 + ((c ^ ((col >> 1) & 3)) << 4)) = v;
  } else {                           // w2: g2 = gid-16384; p = g2>>6 (= e*16+ct), kb = g2&63
    const int g2 = gid - 16384;
    const int p = g2 >> 6, kb = g2 & 63;
    const int e = p >> 4, ct = p & 15;
    if (!mask_at(mask2, flag, (size_t)e * HID * DIM + (size_t)kb * 64 * DIM + ct * 64)) return;
    const float* src = w2 + ((size_t)e * HID + kb * 64 + c * 16) * DIM + ct * 64 + col;
    ux4 v;
    #pragma unroll
    for (int q = 0; q < 4; q++) {
      float f0 = src[(size_t)(q * 4 + 0) * DIM], f1 = src[(size_t)(q * 4 + 1) * DIM];
      float f2 = src[(size_t)(q * 4 + 2) * DIM], f3 = src[(size_t)(q * 4 + 3) * DIM];
      v[q] = pk4fp8(f0 * 16.f, f1 * 16.f, f2 * 16.f, f3 * 16.f);
    }
    *(ux4*)(w2p + ((size_t)g2 << 12) + col * 64 + ((c ^ ((col >> 1) & 3)) << 4)) = v;
  }
}

// offsets + expert_of_rt + pad-row init (replaces tok memset)
__global__ void k_offsets(int* __restrict__ meta, int* __restrict__ tok_of_row) {
  if (threadIdx.x == 0) {
    int o = 0;
    for (int e = 0; e < 16; e++) { meta[32 + e] = o; o += (meta[8 + e] + 255) & ~255; }
    meta[48] = o;
    for (int rt = 0; rt < ROWS_CAP / BM; rt++) {
      const int base = rt * BM;
      int e = 0;
      for (int i = 1; i < 16; i++) if (meta[32 + i] <= base) e = i;
      meta[96 + rt] = e;
    }
  }
  __syncthreads();
  const int total = meta[48];
  for (int r = threadIdx.x; r < total; r += 256) {
    const int e = meta[96 + r / BM];
    if (r >= meta[32 + e] + meta[8 + e]) tok_of_row[r] = -1;
  }
}

__global__ void k_assign(const int* __restrict__ top2i,
                         const float* __restrict__ top2w,
                         int* __restrict__ meta, int* __restrict__ tok_of_row,
                         int* __restrict__ t2row)
{
  int t = blockIdx.x * 256 + threadIdx.x;
  if (t >= NTOK) return;
  #pragma unroll
  for (int k = 0; k < 2; k++) {
    int e = top2i[2 * t + k];
    int slot = atomicAdd(&meta[64 + e], 1);
    int row = meta[32 + e] + slot;
    tok_of_row[row] = t;
    t2row[2 * t + k] = row;
  }
}

// --------------------------- GEMM 1: h8 = fp8(8*silu(x8 @ w1p/256 + b1)) ----
// Full fp8, both operands DMA'd: A gathered x8 rows, B packed w1p images.
__global__ __launch_bounds__(256, 4)
void k_gemm1(const unsigned char* __restrict__ x8,
             const unsigned char* __restrict__ w1p, const float* __restrict__ b1,
             const void* __restrict__ mask1,
             const int* __restrict__ meta, const int* __restrict__ tok_of_row,
             unsigned char* __restrict__ h8)
{
  __shared__ ux4 Ash[2][1024];                        // 2 x 16 KB (256 rows x 64 B)
  __shared__ __align__(16) unsigned int Bsh[2][1024]; // 2 x 4 KB

  const int bid = xcd_swz();
  const int rt = bid >> 6, ct = bid & 63;       // NCT = 64
  const int base = rt * BM;
  if (base >= meta[48]) return;
  const int e = meta[96 + rt];

  const int tid = threadIdx.x;
  const int wv = tid >> 6;
  const int jg0 = ct * 64;
  const int l = tid & 63, l16 = l & 15, lhi = l >> 4;

  unsigned int bits;
  {
    const int flag = flag_of(meta[1]);
    bool on = false;
    if (l < 16)
      on = mask_at(mask1, flag, (size_t)e * DIM * HID + (size_t)l * 64 * HID + jg0);
    bits = (unsigned int)(__ballot(on) & 0xFFFFull);
  }

  // A source offsets: row = i*64 + (tid>>2), gathered; stored chunk
  // (tid&3) ^ ((row>>1)&3) pre-applied on source
  const unsigned int sw = (unsigned int)((tid & 3) ^ ((tid >> 3) & 3));
  unsigned int aoff[4];
  #pragma unroll
  for (int i = 0; i < 4; i++) {
    int tok = tok_of_row[base + i * 64 + (tid >> 2)];
    if (tok < 0) tok = 0;                       // pad rows: finite garbage, unused
    aoff[i] = (unsigned int)tok * (unsigned int)DIM + sw * 16;
  }

  fx4 acc[4][4] = {};

  auto STAGE_A = [&](int b, int d0) {
    const char* gp = (const char*)x8 + d0;
    #pragma unroll
    for (int i = 0; i < 4; i++)
      __builtin_amdgcn_global_load_lds(
        (const __attribute__((address_space(1))) unsigned int*)(gp + aoff[i]),
        (__attribute__((address_space(3))) unsigned int*)&Ash[b][i * 256 + wv * 64],
        16, 0, 0);
  };
  auto STAGE_B = [&](int b, int kb) {
    const char* src = (const char*)w1p + (((size_t)(e * 64 + ct) * 16 + kb) << 12) + tid * 16;
    __builtin_amdgcn_global_load_lds(
      (const __attribute__((address_space(1))) unsigned int*)src,
      (__attribute__((address_space(3))) unsigned int*)&Bsh[b][wv * 256],
      16, 0, 0);
  };
  auto COMPUTE = [&](int b) {
    const char* Ab = (const char*)&Ash[b][0];
    const char* Bb = (const char*)&Bsh[b][0];
    #pragma unroll
    for (int ks = 0; ks < 2; ks++) {
      const int c = ks * 2 + (lhi >> 1);
      const int sub = (lhi & 1) << 3;
      long long a[4], bb[4];
      #pragma unroll
      for (int m = 0; m < 4; m++) {
        const int row = wv * 64 + m * 16 + l16;
        a[m] = *(const long long*)(Ab + row * 64 + ((c ^ ((row >> 1) & 3)) << 4) + sub);
      }
      #pragma unroll
      for (int n = 0; n < 4; n++) {
        const int col = n * 16 + l16;
        bb[n] = *(const long long*)(Bb + col * 64 + ((c ^ ((col >> 1) & 3)) << 4) + sub);
      }
      #pragma unroll
      for (int m = 0; m < 4; m++)
        #pragma unroll
        for (int n = 0; n < 4; n++)
          acc[m][n] = __builtin_amdgcn_mfma_f32_16x16x32_fp8_fp8(a[m], bb[n], acc[m][n], 0, 0, 0);
    }
  };

  if (bits) {
    int kb0 = __ffs(bits) - 1; bits &= bits - 1;
    STAGE_A(0, kb0 << 6); STAGE_B(0, kb0);
    __syncthreads();
    int cur = 0;
    for (;;) {
      int nkb = -1;
      if (bits) { nkb = __ffs(bits) - 1; bits &= bits - 1; }
      if (nkb >= 0) { STAGE_A(cur ^ 1, nkb << 6); STAGE_B(cur ^ 1, nkb); }
      COMPUTE(cur);
      __syncthreads();
      cur ^= 1;
      if (nkb < 0) break;
    }
  }

  // epilogue: h = fp8(8 * silu(acc/256 + b1)) -> LDS byte tile -> 16B dump
  unsigned char* hs = (unsigned char*)&Ash[0][0];   // 16 KB tile
  __syncthreads();
  #pragma unroll
  for (int m = 0; m < 4; m++)
    #pragma unroll
    for (int n = 0; n < 4; n++) {
      const int gcol = jg0 + n * 16 + l16;
      const float bbv = b1[e * HID + gcol];
      #pragma unroll
      for (int i = 0; i < 4; i++) {
        const int row = wv * 64 + m * 16 + lhi * 4 + i;
        float v = acc[m][n][i] * 0.00390625f + bbv;
        float hval = v / (1.0f + __expf(-v));
        hs[row * 64 + n * 16 + l16] = (unsigned char)f2fp8(hval * 8.0f);
      }
    }
  __syncthreads();
  {
    const ux4* s = (const ux4*)hs;
    #pragma unroll
    for (int j = 0; j < 4; j++) {
      const int c2 = j * 256 + tid;
      const int row = c2 >> 2;
      *(ux4*)(h8 + (size_t)(base + row) * HID + ct * 64 + (c2 & 3) * 16) = s[c2];
    }
  }
}

// --------------------------- GEMM 2: y = bf16(h8 @ w2p / 128 + b2) ----------
__global__ __launch_bounds__(256, 4)
void k_gemm2(const unsigned char* __restrict__ h8,
             const unsigned char* __restrict__ w2p, const float* __restrict__ b2,
             const void* __restrict__ mask2,
             const int* __restrict__ meta, unsigned short* __restrict__ yb)
{
  __shared__ ux4 Ash[2][1024];                       // 2 x 16 KB (256 rows x 64 B)
  __shared__ __align__(16) unsigned int Bsh[2][1024]; // 2 x 4 KB (64 cols x 64 B)

  const int bid = xcd_swz();
  const int rt = bid >> 4, ct = bid & 15;       // NCT = 16
  const int base = rt * BM;
  if (base >= meta[48]) return;
  const int e = meta[96 + rt];

  const int tid = threadIdx.x;
  const int wv = tid >> 6;
  const int jg0 = ct * 64;

  const int l = tid & 63, l16 = l & 15, lhi = l >> 4;
  unsigned long long bits;
  {
    const int flag = flag_of(meta[1]);
    bits = __ballot(mask_at(mask2, flag,
             (size_t)e * HID * DIM + (size_t)l * 64 * DIM + jg0));
  }

  const unsigned int sw = (unsigned int)((tid & 3) ^ ((tid >> 3) & 3));
  unsigned int aoff[4];
  #pragma unroll
  for (int i = 0; i < 4; i++)
    aoff[i] = (unsigned int)(base + i * 64 + (tid >> 2)) * (unsigned int)HID + sw * 16;

  fx4 acc[4][4] = {};

  auto STAGE_A = [&](int b, int d0) {
    const char* gp = (const char*)h8 + d0;
    #pragma unroll
    for (int i = 0; i < 4; i++)
      __builtin_amdgcn_global_load_lds(
        (const __attribute__((address_space(1))) unsigned int*)(gp + aoff[i]),
        (__attribute__((address_space(3))) unsigned int*)&Ash[b][i * 256 + wv * 64],
        16, 0, 0);
  };
  auto STAGE_B = [&](int b, int kb) {
    const char* src = (const char*)w2p + (((size_t)(e * 16 + ct) * 64 + kb) << 12) + tid * 16;
    __builtin_amdgcn_global_load_lds(
      (const __attribute__((address_space(1))) unsigned int*)src,
      (__attribute__((address_space(3))) unsigned int*)&Bsh[b][wv * 256],
      16, 0, 0);
  };
  auto COMPUTE = [&](int b) {
    const char* Ab = (const char*)&Ash[b][0];
    const char* Bb = (const char*)&Bsh[b][0];
    #pragma unroll
    for (int ks = 0; ks < 2; ks++) {
      const int c = ks * 2 + (lhi >> 1);
      const int sub = (lhi & 1) << 3;
      long long a[4], bb[4];
      #pragma unroll
      for (int m = 0; m < 4; m++) {
        const int row = wv * 64 + m * 16 + l16;
        a[m] = *(const long long*)(Ab + row * 64 + ((c ^ ((row >> 1) & 3)) << 4) + sub);
      }
      #pragma unroll
      for (int n = 0; n < 4; n++) {
        const int col = n * 16 + l16;
        bb[n] = *(const long long*)(Bb + col * 64 + ((c ^ ((col >> 1) & 3)) << 4) + sub);
      }
      #pragma unroll
      for (int m = 0; m < 4; m++)
        #pragma unroll
        for (int n = 0; n < 4; n++)
          acc[m][n] = __builtin_amdgcn_mfma_f32_16x16x32_fp8_fp8(a[m], bb[n], acc[m][n], 0, 0, 0);
    }
  };

  if (bits) {
    int kb0 = __ffsll(bits) - 1; bits &= bits - 1;
    STAGE_A(0, kb0 << 6); STAGE_B(0, kb0);
    __syncthreads();
    int cur = 0;
    for (;;) {
      int nkb = -1;
      if (bits) { nkb = __ffsll(bits) - 1; bits &= bits - 1; }
      if (nkb >= 0) { STAGE_A(cur ^ 1, nkb << 6); STAGE_B(cur ^ 1, nkb); }
      COMPUTE(cur);
      __syncthreads();
      cur ^= 1;
      if (nkb < 0) break;
    }
  }

  // epilogue: y = bf16(acc/128 + b2), restaged via LDS (Ash = 32 KB)
  unsigned short* hs = (unsigned short*)&Ash[0][0];
  __syncthreads();
  #pragma unroll
  for (int m = 0; m < 4; m++)
    #pragma unroll
    for (int n = 0; n < 4; n++) {
      const int gcol = jg0 + n * 16 + l16;
      const float bbv = b2[e * DIM + gcol];
      #pragma unroll
      for (int i = 0; i < 4; i++) {
        const int row = wv * 64 + m * 16 + lhi * 4 + i;
        hs[row * 64 + n * 16 + l16] =
            (unsigned short)f2bf(acc[m][n][i] * 0.0078125f + bbv);
      }
    }
  __syncthreads();
  {
    const ux4* s = (const ux4*)hs;
    #pragma unroll
    for (int j = 0; j < 8; j++) {
      const int c2 = j * 256 + tid;
      const int row = c2 >> 3;
      *(ux4*)(yb + (size_t)(base + row) * DIM + ct * 64 + (c2 & 7) * 8) = s[c2];
    }
  }
}

// --------------------------- cross: out = x + eo @ cwm + cb -----------------
// BM=128 (R5 structure): 4 waves in 2x2 grid, acc[4][2], 24 KB LDS, grid 1024.
// eo rows formed on the fly from bf16 y: eo[tok] = w0*y[r0] + w1*y[r1]
__global__ __launch_bounds__(256, 4)
void k_cross(const unsigned short* __restrict__ yb, const float* __restrict__ x,
             const float* __restrict__ cw, const float* __restrict__ cb,
             const void* __restrict__ cmask, const int* __restrict__ meta,
             const int* __restrict__ t2row, const float* __restrict__ t2w,
             float* __restrict__ out)
{
  __shared__ ux4 Ash[1024];                  // 128 rows x 64 k bf16 = 16 KB
  __shared__ __align__(16) ux2 Bsh[1024];    // 8 KB

  const int bid = xcd_swz();
  const int rt = bid >> 4, ct = bid & 15;    // 64 row tiles x 16 col tiles
  const int base = rt * 128;
  const int tid = threadIdx.x;
  const int wv = tid >> 6;
  const int wr = wv >> 1, wc = wv & 1;
  const int jg0 = ct * 64;

  const int l = tid & 63, l16 = l & 15, lhi = l >> 4;

  unsigned int bits;
  {
    const int flag = flag_of(meta[1]);
    bool on = false;
    if (l < 16)
      on = mask_at(cmask, flag, (size_t)l * 64 * DIM + jg0);
    bits = (unsigned int)(__ballot(on) & 0xFFFFull);
  }

  const int arow = tid >> 1, sub = tid & 1;
  const int r0 = t2row[2 * (base + arow)], r1 = t2row[2 * (base + arow) + 1];
  const float w0 = t2w[2 * (base + arow)], w1 = t2w[2 * (base + arow) + 1];

  fx4 acc[4][2] = {};

  while (bits) {
    const int kbx = __ffs(bits) - 1; bits &= bits - 1;
    const int d0 = kbx * 64;
    {   // stage A: combine two bf16 pair rows -> bf16 (swizzled ds_write)
      const ux4* s0 = (const ux4*)(yb + (size_t)r0 * DIM + d0);
      const ux4* s1 = (const ux4*)(yb + (size_t)r1 * DIM + d0);
      #pragma unroll
      for (int s = 0; s < 4; s++) {
        const int seg = sub * 4 + s;
        ux4 v0 = s0[seg], v1 = s1[seg], o;
        #pragma unroll
        for (int j = 0; j < 4; j++) {
          float alo = __uint_as_float(v0[j] << 16);
          float ahi = __uint_as_float(v0[j] & 0xFFFF0000u);
          float blo = __uint_as_float(v1[j] << 16);
          float bhi = __uint_as_float(v1[j] & 0xFFFF0000u);
          o[j] = cvt_pk(w0 * alo + w1 * blo, w0 * ahi + w1 * bhi);
        }
        Ash[arow * 8 + (seg ^ (arow & 7))] = o;
      }
    }
    {   // stage B from cross_w (f32 reg-staged)
      const int kbt = tid >> 4, jb = tid & 15;
      const float* bp = cw + (size_t)(d0 + kbt * 4) * DIM + jg0 + jb * 4;
      fx4 r0v = *(const fx4*)bp;
      fx4 r1v = *(const fx4*)(bp + DIM);
      fx4 r2v = *(const fx4*)(bp + 2 * DIM);
      fx4 r3v = *(const fx4*)(bp + 3 * DIM);
      #pragma unroll
      for (int jj = 0; jj < 4; jj++) {
        ux2 val;
        val[0] = cvt_pk(r0v[jj], r1v[jj]);
        val[1] = cvt_pk(r2v[jj], r3v[jj]);
        const int col = jb * 4 + jj;
        Bsh[(col * 8 + ((kbt >> 1) ^ (col & 7))) * 2 + (kbt & 1)] = val;
      }
    }
    __syncthreads();
    #pragma unroll
    for (int ks = 0; ks < 2; ks++) {
      s8v a[4], b[2];
      const int seg = ks * 4 + lhi;
      #pragma unroll
      for (int m = 0; m < 4; m++) {
        const int row = wr * 64 + m * 16 + l16;
        V16 v; v.u = Ash[row * 8 + (seg ^ (row & 7))]; a[m] = v.s;
      }
      #pragma unroll
      for (int n = 0; n < 2; n++) {
        const int col = wc * 32 + n * 16 + l16;
        V16 v; v.u = ((const ux4*)Bsh)[col * 8 + (seg ^ (col & 7))]; b[n] = v.s;
      }
      #pragma unroll
      for (int m = 0; m < 4; m++)
        #pragma unroll
        for (int n = 0; n < 2; n++)
          acc[m][n] = __builtin_amdgcn_mfma_f32_16x16x32_bf16(a[m], b[n], acc[m][n], 0, 0, 0);
    }
    __syncthreads();
  }

  #pragma unroll
  for (int m = 0; m < 4; m++)
    #pragma unroll
    for (int n = 0; n < 2; n++) {
      const int gcol = jg0 + wc * 32 + n * 16 + l16;
      #pragma unroll
      for (int i = 0; i < 4; i++) {
        const int row = wr * 64 + m * 16 + lhi * 4 + i;
        const size_t idx = (size_t)(base + row) * DIM + gcol;
        out[idx] = acc[m][n][i] + x[idx] + cb[gcol];
      }
    }
}

// ---------------------------------------------------------------------------
extern "C" void kernel_launch(void* const* d_in, const int* in_sizes, int n_in,
                              void* d_out, int out_size, void* d_ws, size_t ws_size,
                              hipStream_t stream)
{
  (void)in_sizes; (void)n_in; (void)out_size; (void)ws_size;
  const float* x      = (const float*)d_in[0];
  const float* gate_w = (const float*)d_in[1];   // [2,16,1024]
  const float* temp   = (const float*)d_in[2];   // [2]
  const float* w1     = (const float*)d_in[3];   // [16,1024,4096]
  const float* b1     = (const float*)d_in[4];
  const float* w2     = (const float*)d_in[5];   // [16,4096,1024]
  const float* b2     = (const float*)d_in[6];
  const float* cw     = (const float*)d_in[7];   // [1024,1024]
  const float* cb     = (const float*)d_in[8];
  const void*  mask1  = d_in[9];
  const void*  mask2  = d_in[10];
  const void*  cmask  = d_in[11];
  float* out = (float*)d_out;
  char* ws = (char*)d_ws;

  size_t off = 0;
  auto walloc = [&](size_t b) { size_t r = off; off = (off + b + 255) & ~(size_t)255; return r; };
  size_t o_meta = walloc(4096);
  size_t o_t2i  = walloc((size_t)NTOK * 2 * 4);
  size_t o_t2w  = walloc((size_t)NTOK * 2 * 4);
  size_t o_t2r  = walloc((size_t)NTOK * 2 * 4);
  size_t o_tok  = walloc((size_t)ROWS_CAP * 4);
  size_t o_x8   = walloc((size_t)NTOK * DIM);            // 8 MB (fp8)
  size_t o_y    = walloc((size_t)ROWS_CAP * DIM * 2);    // 40 MB (bf16)
  size_t o_hc   = walloc((size_t)ROWS_CAP * HID);        // 84 MB (fp8)
  size_t o_w1p  = walloc((size_t)16384 * 4096);          // 64 MB
  size_t o_w2p  = walloc((size_t)16384 * 4096);          // 64 MB

  int*                meta = (int*)(ws + o_meta);
  int*                t2i  = (int*)(ws + o_t2i);
  float*              t2w  = (float*)(ws + o_t2w);
  int*                t2r  = (int*)(ws + o_t2r);
  int*                tok  = (int*)(ws + o_tok);
  unsigned char*      x8   = (unsigned char*)(ws + o_x8);
  unsigned short*     yb   = (unsigned short*)(ws + o_y);
  unsigned char*      h8   = (unsigned char*)(ws + o_hc);
  unsigned char*      w1p  = (unsigned char*)(ws + o_w1p);
  unsigned char*      w2p  = (unsigned char*)(ws + o_w2p);

  hipMemsetAsync(ws + o_meta, 0, 4096, stream);

  k_route  <<<NTOK / 32, 256, 0, stream>>>(x, gate_w + (size_t)1 * NEXP * DIM, temp + 1,
                                           (const unsigned int*)mask1, t2i, t2w, meta, x8);
  k_wcast  <<<32768, 256, 0, stream>>>(w1, w2, mask1, mask2, meta, w1p, w2p);
  k_offsets<<<1, 256, 0, stream>>>(meta, tok);
  k_assign <<<NTOK / 256, 256, 0, stream>>>(t2i, t2w, meta, tok, t2r);

  const int NRT = ROWS_CAP / BM;   // 80
  k_gemm1<<<NRT * 64, 256, 0, stream>>>(x8, w1p, b1, mask1, meta, tok, h8);
  k_gemm2<<<NRT * 16, 256, 0, stream>>>(h8, w2p, b2, mask2, meta, yb);
  k_cross<<<(NTOK / 128) * 16, 256, 0, stream>>>(yb, x, cw, cb, cmask, meta, t2r, t2w, out);
}

// Round 15
// 322.096 us; speedup vs baseline: 2.4084x; 1.0445x over previous
//
#include <hip/hip_runtime.h>

// ---------------------------------------------------------------------------
// HierarchicalSparseLayer: top-2 MoE with block-sparse (64x64) masked weights
// B=8192 tokens, D=1024, H=4096, E=16 experts, K=2, + block-sparse cross proj.
// R15: R14 + k_offsets eliminated (k_assign computes offsets locally; GEMMs
//      compute expert/region from counts in-prologue; pad validity via range
//      test instead of -1 sentinel -> no pad init at all).
// ---------------------------------------------------------------------------

#define NTOK 8192
#define DIM  1024
#define HID  4096
#define NEXP 16
#define BM   256
#define ROWS_CAP (NTOK*2 + NEXP*256)   // 20480

typedef __attribute__((ext_vector_type(4))) float fx4;
typedef __attribute__((ext_vector_type(4))) unsigned int ux4;
typedef __attribute__((ext_vector_type(2))) unsigned int ux2;
typedef __attribute__((ext_vector_type(8))) short s8v;
union V16 { ux4 u; s8v s; };

__device__ __forceinline__ unsigned int f2bf(float f) {
  unsigned int u = __float_as_uint(f);
  return (u + 0x7fffu + ((u >> 16) & 1u)) >> 16;   // RNE, inputs finite
}

__device__ __forceinline__ unsigned int cvt_pk(float lo, float hi) {
  unsigned int r;
  asm("v_cvt_pk_bf16_f32 %0, %1, %2" : "=v"(r) : "v"(lo), "v"(hi));
  return r;
}

__device__ __forceinline__ unsigned int f2fp8(float v) {
  return (unsigned int)__builtin_amdgcn_cvt_pk_fp8_f32(v, v, 0, false) & 0xFFu;
}

// pack 4 f32 (scaled) into one u32 of 4 fp8 e4m3
__device__ __forceinline__ unsigned int pk4fp8(float a, float b, float c, float d) {
  unsigned int u = (unsigned int)__builtin_amdgcn_cvt_pk_fp8_f32(a, b, 0, false);
  u = (unsigned int)__builtin_amdgcn_cvt_pk_fp8_f32(c, d, (int)u, true);
  return u;
}

// Mask dtype detected at runtime: flag 0=u8, 1=i32, 2=f32
__device__ __forceinline__ bool mask_at(const void* m, int flag, size_t idx) {
  if (flag == 0) return ((const unsigned char*)m)[idx] != 0;
  if (flag == 1) return ((const int*)m)[idx] != 0;
  return ((const float*)m)[idx] != 0.0f;
}

__device__ __forceinline__ int flag_of(int ev) {
  return (ev & 2) ? 2 : ((ev & 1) ? 0 : 1);
}

// XCD-aware swizzle (grid % 8 == 0)
__device__ __forceinline__ int xcd_swz() {
  const int b = blockIdx.x, cpx = gridDim.x >> 3;
  return (b & 7) * cpx + (b >> 3);
}

// Region lookup from counts: returns expert e, region start, raw count, total.
__device__ __forceinline__ void region_of(const int* __restrict__ meta, int base,
                                          int& e, int& rstart, int& ecnt, int& total) {
  e = 15; rstart = 0; ecnt = 0; total = 0;
  #pragma unroll
  for (int i = 0; i < 16; i++) {
    const int craw = meta[8 + i];
    const int c = (craw + 255) & ~255;
    if (base >= total && base < total + c) { e = i; rstart = total; ecnt = craw; }
    total += c;
  }
}

// --------------------------- routing (+ detect + x->fp8 pack) ---------------
// meta: [1]=detect bits [8..23]=counts [64..79]=slot counters
__global__ void k_route(const float* __restrict__ x,
                        const float* __restrict__ gw,    // gate_w[-1] [16,1024]
                        const float* __restrict__ temp,
                        const unsigned int* __restrict__ m1raw,
                        int* __restrict__ top2i, float* __restrict__ top2w,
                        int* __restrict__ meta, unsigned char* __restrict__ x8)
{
  if (blockIdx.x < 64) {     // fold k_detect
    int bits = 0;
    size_t base = (size_t)blockIdx.x * 4096 + threadIdx.x;
    for (int j = 0; j < 16; j++) {
      unsigned int v = m1raw[base + 256 * j];
      if (v == 0x3f800000u) bits |= 2;
      else if (v > 1u)      bits |= 1;
    }
    if (bits) atomicOr(&meta[1], bits);
  }

  __shared__ float gwsh[NEXP * DIM];
  for (int i = threadIdx.x; i < NEXP * DIM; i += 256) gwsh[i] = gw[i];
  __syncthreads();

  const int wv = threadIdx.x >> 6;
  const int l = threadIdx.x & 63;
  #pragma unroll
  for (int tt = 0; tt < 8; tt++) {
    const int t = blockIdx.x * 32 + wv * 8 + tt;
    const float* xr = x + (size_t)t * DIM;
    float xv[16];
    #pragma unroll
    for (int j = 0; j < 16; j++) xv[j] = xr[l + 64 * j];
    float logit[16];
    #pragma unroll
    for (int e = 0; e < 16; e++) {
      const float* g = gwsh + e * DIM;
      float s = 0.f;
      #pragma unroll
      for (int j = 0; j < 16; j++) s += xv[j] * g[l + 64 * j];
      #pragma unroll
      for (int o = 32; o >= 1; o >>= 1) s += __shfl_xor(s, o);
      logit[e] = s;
    }
    if (l == 0) {
      const float tinv = 1.0f / temp[0];
      int i0 = 0; float v0 = logit[0] * tinv;
      #pragma unroll
      for (int e = 1; e < 16; e++) { float v = logit[e] * tinv; if (v > v0) { v0 = v; i0 = e; } }
      int i1 = -1; float v1 = 0.f; bool first = true;
      #pragma unroll
      for (int e = 0; e < 16; e++) {
        if (e == i0) continue;
        float v = logit[e] * tinv;
        if (first || v > v1) { v1 = v; i1 = e; first = false; }
      }
      float ex = __expf(v1 - v0);
      float den = 1.0f + ex;
      top2i[2 * t] = i0; top2i[2 * t + 1] = i1;
      top2w[2 * t] = 1.0f / den; top2w[2 * t + 1] = ex / den;
      atomicAdd(&meta[8 + i0], 1);
      atomicAdd(&meta[8 + i1], 1);
    }
  }

  // pack this block's 32 tokens to fp8 (x16 scale); slab is L1/L2-hot
  {
    const size_t be = (size_t)blockIdx.x * 32 * DIM;
    const fx4* src = (const fx4*)(x + be);
    ux4* dst = (ux4*)(x8 + be);          // 2048 ux4 per block
    #pragma unroll
    for (int i = 0; i < 8; i++) {
      const int idx = i * 256 + threadIdx.x;
      fx4 a = src[4 * idx], b = src[4 * idx + 1];
      fx4 c = src[4 * idx + 2], d = src[4 * idx + 3];
      ux4 o;
      o[0] = pk4fp8(a[0] * 16.f, a[1] * 16.f, a[2] * 16.f, a[3] * 16.f);
      o[1] = pk4fp8(b[0] * 16.f, b[1] * 16.f, b[2] * 16.f, b[3] * 16.f);
      o[2] = pk4fp8(c[0] * 16.f, c[1] * 16.f, c[2] * 16.f, c[3] * 16.f);
      o[3] = pk4fp8(d[0] * 16.f, d[1] * 16.f, d[2] * 16.f, d[3] * 16.f);
      dst[idx] = o;
    }
  }
}

// --------------------------- weight pre-cast to fp8 B-images ----------------
// Active 64x64 block -> 4 KB image == the compute loop's swizzled LDS B
// layout: chunk c (k bytes c*16..c*16+15) of col at col*64+((c^((col>>1)&3))<<4).
__global__ void k_wcast(const float* __restrict__ w1, const float* __restrict__ w2,
                        const void* __restrict__ mask1, const void* __restrict__ mask2,
                        const int* __restrict__ meta,
                        unsigned char* __restrict__ w1p, unsigned char* __restrict__ w2p)
{
  const int flag = flag_of(meta[1]);
  const int gid = blockIdx.x;
  const int tid = threadIdx.x;
  const int c = tid >> 6, col = tid & 63;

  if (gid < 16384) {                 // w1: panel p = gid>>4 (= e*64+ct), kb = gid&15
    const int p = gid >> 4, kb = gid & 15;
    const int e = p >> 6, ct = p & 63;
    if (!mask_at(mask1, flag, (size_t)e * DIM * HID + (size_t)kb * 64 * HID + ct * 64)) return;
    const float* src = w1 + ((size_t)e * DIM + kb * 64 + c * 16) * HID + ct * 64 + col;
    ux4 v;
    #pragma unroll
    for (int q = 0; q < 4; q++) {
      float f0 = src[(size_t)(q * 4 + 0) * HID], f1 = src[(size_t)(q * 4 + 1) * HID];
      float f2 = src[(size_t)(q * 4 + 2) * HID], f3 = src[(size_t)(q * 4 + 3) * HID];
      v[q] = pk4fp8(f0 * 16.f, f1 * 16.f, f2 * 16.f, f3 * 16.f);
    }
    *(ux4*)(w1p + ((size_t)gid << 12) + col * 64 + ((c ^ ((col >> 1) & 3)) << 4)) = v;
  } else {                           // w2: g2 = gid-16384; p = g2>>6 (= e*16+ct), kb = g2&63
    const int g2 = gid - 16384;
    const int p = g2 >> 6, kb = g2 & 63;
    const int e = p >> 4, ct = p & 15;
    if (!mask_at(mask2, flag, (size_t)e * HID * DIM + (size_t)kb * 64 * DIM + ct * 64)) return;
    const float* src = w2 + ((size_t)e * HID + kb * 64 + c * 16) * DIM + ct * 64 + col;
    ux4 v;
    #pragma unroll
    for (int q = 0; q < 4; q++) {
      float f0 = src[(size_t)(q * 4 + 0) * DIM], f1 = src[(size_t)(q * 4 + 1) * DIM];
      float f2 = src[(size_t)(q * 4 + 2) * DIM], f3 = src[(size_t)(q * 4 + 3) * DIM];
      v[q] = pk4fp8(f0 * 16.f, f1 * 16.f, f2 * 16.f, f3 * 16.f);
    }
    *(ux4*)(w2p + ((size_t)g2 << 12) + col * 64 + ((c ^ ((col >> 1) & 3)) << 4)) = v;
  }
}

// --------------------------- assign (offsets computed locally) --------------
__global__ void k_assign(const int* __restrict__ top2i,
                         const float* __restrict__ top2w,
                         int* __restrict__ meta, int* __restrict__ tok_of_row,
                         int* __restrict__ t2row)
{
  __shared__ int offs[16];
  if (threadIdx.x < 16) {
    int o = 0;
    for (int i = 0; i < (int)threadIdx.x; i++) o += (meta[8 + i] + 255) & ~255;
    offs[threadIdx.x] = o;
  }
  __syncthreads();
  int t = blockIdx.x * 256 + threadIdx.x;
  if (t >= NTOK) return;
  #pragma unroll
  for (int k = 0; k < 2; k++) {
    int e = top2i[2 * t + k];
    int slot = atomicAdd(&meta[64 + e], 1);
    int row = offs[e] + slot;
    tok_of_row[row] = t;
    t2row[2 * t + k] = row;
  }
}

// --------------------------- GEMM 1: h8 = fp8(8*silu(x8 @ w1p/256 + b1)) ----
// Full fp8, both operands DMA'd: A gathered x8 rows, B packed w1p images.
__global__ __launch_bounds__(256, 4)
void k_gemm1(const unsigned char* __restrict__ x8,
             const unsigned char* __restrict__ w1p, const float* __restrict__ b1,
             const void* __restrict__ mask1,
             const int* __restrict__ meta, const int* __restrict__ tok_of_row,
             unsigned char* __restrict__ h8)
{
  __shared__ ux4 Ash[2][1024];                        // 2 x 16 KB (256 rows x 64 B)
  __shared__ __align__(16) unsigned int Bsh[2][1024]; // 2 x 4 KB

  const int bid = xcd_swz();
  const int rt = bid >> 6, ct = bid & 63;       // NCT = 64
  const int base = rt * BM;
  int e, rstart, ecnt, total;
  region_of(meta, base, e, rstart, ecnt, total);
  if (base >= total) return;

  const int tid = threadIdx.x;
  const int wv = tid >> 6;
  const int jg0 = ct * 64;
  const int l = tid & 63, l16 = l & 15, lhi = l >> 4;

  unsigned int bits;
  {
    const int flag = flag_of(meta[1]);
    bool on = false;
    if (l < 16)
      on = mask_at(mask1, flag, (size_t)e * DIM * HID + (size_t)l * 64 * HID + jg0);
    bits = (unsigned int)(__ballot(on) & 0xFFFFull);
  }

  // A source offsets: row = i*64 + (tid>>2), gathered; stored chunk
  // (tid&3) ^ ((row>>1)&3) pre-applied on source. Pad rows (range test) -> tok 0.
  const unsigned int sw = (unsigned int)((tid & 3) ^ ((tid >> 3) & 3));
  const int vlimit = rstart + ecnt;
  unsigned int aoff[4];
  #pragma unroll
  for (int i = 0; i < 4; i++) {
    const int r = base + i * 64 + (tid >> 2);
    int tok = tok_of_row[r];
    if (r >= vlimit) tok = 0;                   // pad rows: finite garbage, unused
    aoff[i] = (unsigned int)tok * (unsigned int)DIM + sw * 16;
  }

  fx4 acc[4][4] = {};

  auto STAGE_A = [&](int b, int d0) {
    const char* gp = (const char*)x8 + d0;
    #pragma unroll
    for (int i = 0; i < 4; i++)
      __builtin_amdgcn_global_load_lds(
        (const __attribute__((address_space(1))) unsigned int*)(gp + aoff[i]),
        (__attribute__((address_space(3))) unsigned int*)&Ash[b][i * 256 + wv * 64],
        16, 0, 0);
  };
  auto STAGE_B = [&](int b, int kb) {
    const char* src = (const char*)w1p + (((size_t)(e * 64 + ct) * 16 + kb) << 12) + tid * 16;
    __builtin_amdgcn_global_load_lds(
      (const __attribute__((address_space(1))) unsigned int*)src,
      (__attribute__((address_space(3))) unsigned int*)&Bsh[b][wv * 256],
      16, 0, 0);
  };
  auto COMPUTE = [&](int b) {
    const char* Ab = (const char*)&Ash[b][0];
    const char* Bb = (const char*)&Bsh[b][0];
    #pragma unroll
    for (int ks = 0; ks < 2; ks++) {
      const int c = ks * 2 + (lhi >> 1);
      const int sub = (lhi & 1) << 3;
      long long a[4], bb[4];
      #pragma unroll
      for (int m = 0; m < 4; m++) {
        const int row = wv * 64 + m * 16 + l16;
        a[m] = *(const long long*)(Ab + row * 64 + ((c ^ ((row >> 1) & 3)) << 4) + sub);
      }
      #pragma unroll
      for (int n = 0; n < 4; n++) {
        const int col = n * 16 + l16;
        bb[n] = *(const long long*)(Bb + col * 64 + ((c ^ ((col >> 1) & 3)) << 4) + sub);
      }
      #pragma unroll
      for (int m = 0; m < 4; m++)
        #pragma unroll
        for (int n = 0; n < 4; n++)
          acc[m][n] = __builtin_amdgcn_mfma_f32_16x16x32_fp8_fp8(a[m], bb[n], acc[m][n], 0, 0, 0);
    }
  };

  if (bits) {
    int kb0 = __ffs(bits) - 1; bits &= bits - 1;
    STAGE_A(0, kb0 << 6); STAGE_B(0, kb0);
    __syncthreads();
    int cur = 0;
    for (;;) {
      int nkb = -1;
      if (bits) { nkb = __ffs(bits) - 1; bits &= bits - 1; }
      if (nkb >= 0) { STAGE_A(cur ^ 1, nkb << 6); STAGE_B(cur ^ 1, nkb); }
      COMPUTE(cur);
      __syncthreads();
      cur ^= 1;
      if (nkb < 0) break;
    }
  }

  // epilogue: h = fp8(8 * silu(acc/256 + b1)) -> LDS byte tile -> 16B dump
  unsigned char* hs = (unsigned char*)&Ash[0][0];   // 16 KB tile
  __syncthreads();
  #pragma unroll
  for (int m = 0; m < 4; m++)
    #pragma unroll
    for (int n = 0; n < 4; n++) {
      const int gcol = jg0 + n * 16 + l16;
      const float bbv = b1[e * HID + gcol];
      #pragma unroll
      for (int i = 0; i < 4; i++) {
        const int row = wv * 64 + m * 16 + lhi * 4 + i;
        float v = acc[m][n][i] * 0.00390625f + bbv;
        float hval = v / (1.0f + __expf(-v));
        hs[row * 64 + n * 16 + l16] = (unsigned char)f2fp8(hval * 8.0f);
      }
    }
  __syncthreads();
  {
    const ux4* s = (const ux4*)hs;
    #pragma unroll
    for (int j = 0; j < 4; j++) {
      const int c2 = j * 256 + tid;
      const int row = c2 >> 2;
      *(ux4*)(h8 + (size_t)(base + row) * HID + ct * 64 + (c2 & 3) * 16) = s[c2];
    }
  }
}

// --------------------------- GEMM 2: y = bf16(h8 @ w2p / 128 + b2) ----------
__global__ __launch_bounds__(256, 4)
void k_gemm2(const unsigned char* __restrict__ h8,
             const unsigned char* __restrict__ w2p, const float* __restrict__ b2,
             const void* __restrict__ mask2,
             const int* __restrict__ meta, unsigned short* __restrict__ yb)
{
  __shared__ ux4 Ash[2][1024];                       // 2 x 16 KB (256 rows x 64 B)
  __shared__ __align__(16) unsigned int Bsh[2][1024]; // 2 x 4 KB (64 cols x 64 B)

  const int bid = xcd_swz();
  const int rt = bid >> 4, ct = bid & 15;       // NCT = 16
  const int base = rt * BM;
  int e, rstart, ecnt, total;
  region_of(meta, base, e, rstart, ecnt, total);
  if (base >= total) return;

  const int tid = threadIdx.x;
  const int wv = tid >> 6;
  const int jg0 = ct * 64;

  const int l = tid & 63, l16 = l & 15, lhi = l >> 4;
  unsigned long long bits;
  {
    const int flag = flag_of(meta[1]);
    bits = __ballot(mask_at(mask2, flag,
             (size_t)e * HID * DIM + (size_t)l * 64 * DIM + jg0));
  }

  const unsigned int sw = (unsigned int)((tid & 3) ^ ((tid >> 3) & 3));
  unsigned int aoff[4];
  #pragma unroll
  for (int i = 0; i < 4; i++)
    aoff[i] = (unsigned int)(base + i * 64 + (tid >> 2)) * (unsigned int)HID + sw * 16;

  fx4 acc[4][4] = {};

  auto STAGE_A = [&](int b, int d0) {
    const char* gp = (const char*)h8 + d0;
    #pragma unroll
    for (int i = 0; i < 4; i++)
      __builtin_amdgcn_global_load_lds(
        (const __attribute__((address_space(1))) unsigned int*)(gp + aoff[i]),
        (__attribute__((address_space(3))) unsigned int*)&Ash[b][i * 256 + wv * 64],
        16, 0, 0);
  };
  auto STAGE_B = [&](int b, int kb) {
    const char* src = (const char*)w2p + (((size_t)(e * 16 + ct) * 64 + kb) << 12) + tid * 16;
    __builtin_amdgcn_global_load_lds(
      (const __attribute__((address_space(1))) unsigned int*)src,
      (__attribute__((address_space(3))) unsigned int*)&Bsh[b][wv * 256],
      16, 0, 0);
  };
  auto COMPUTE = [&](int b) {
    const char* Ab = (const char*)&Ash[b][0];
    const char* Bb = (const char*)&Bsh[b][0];
    #pragma unroll
    for (int ks = 0; ks < 2; ks++) {
      const int c = ks * 2 + (lhi >> 1);
      const int sub = (lhi & 1) << 3;
      long long a[4], bb[4];
      #pragma unroll
      for (int m = 0; m < 4; m++) {
        const int row = wv * 64 + m * 16 + l16;
        a[m] = *(const long long*)(Ab + row * 64 + ((c ^ ((row >> 1) & 3)) << 4) + sub);
      }
      #pragma unroll
      for (int n = 0; n < 4; n++) {
        const int col = n * 16 + l16;
        bb[n] = *(const long long*)(Bb + col * 64 + ((c ^ ((col >> 1) & 3)) << 4) + sub);
      }
      #pragma unroll
      for (int m = 0; m < 4; m++)
        #pragma unroll
        for (int n = 0; n < 4; n++)
          acc[m][n] = __builtin_amdgcn_mfma_f32_16x16x32_fp8_fp8(a[m], bb[n], acc[m][n], 0, 0, 0);
    }
  };

  if (bits) {
    int kb0 = __ffsll(bits) - 1; bits &= bits - 1;
    STAGE_A(0, kb0 << 6); STAGE_B(0, kb0);
    __syncthreads();
    int cur = 0;
    for (;;) {
      int nkb = -1;
      if (bits) { nkb = __ffsll(bits) - 1; bits &= bits - 1; }
      if (nkb >= 0) { STAGE_A(cur ^ 1, nkb << 6); STAGE_B(cur ^ 1, nkb); }
      COMPUTE(cur);
      __syncthreads();
      cur ^= 1;
      if (nkb < 0) break;
    }
  }

  // epilogue: y = bf16(acc/128 + b2), restaged via LDS (Ash = 32 KB)
  unsigned short* hs = (unsigned short*)&Ash[0][0];
  __syncthreads();
  #pragma unroll
  for (int m = 0; m < 4; m++)
    #pragma unroll
    for (int n = 0; n < 4; n++) {
      const int gcol = jg0 + n * 16 + l16;
      const float bbv = b2[e * DIM + gcol];
      #pragma unroll
      for (int i = 0; i < 4; i++) {
        const int row = wv * 64 + m * 16 + lhi * 4 + i;
        hs[row * 64 + n * 16 + l16] =
            (unsigned short)f2bf(acc[m][n][i] * 0.0078125f + bbv);
      }
    }
  __syncthreads();
  {
    const ux4* s = (const ux4*)hs;
    #pragma unroll
    for (int j = 0; j < 8; j++) {
      const int c2 = j * 256 + tid;
      const int row = c2 >> 3;
      *(ux4*)(yb + (size_t)(base + row) * DIM + ct * 64 + (c2 & 7) * 8) = s[c2];
    }
  }
}

// --------------------------- cross: out = x + eo @ cwm + cb -----------------
// BM=128 (R5 structure): 4 waves in 2x2 grid, acc[4][2], 24 KB LDS, grid 1024.
// eo rows formed on the fly from bf16 y: eo[tok] = w0*y[r0] + w1*y[r1]
__global__ __launch_bounds__(256, 4)
void k_cross(const unsigned short* __restrict__ yb, const float* __restrict__ x,
             const float* __restrict__ cw, const float* __restrict__ cb,
             const void* __restrict__ cmask, const int* __restrict__ meta,
             const int* __restrict__ t2row, const float* __restrict__ t2w,
             float* __restrict__ out)
{
  __shared__ ux4 Ash[1024];                  // 128 rows x 64 k bf16 = 16 KB
  __shared__ __align__(16) ux2 Bsh[1024];    // 8 KB

  const int bid = xcd_swz();
  const int rt = bid >> 4, ct = bid & 15;    // 64 row tiles x 16 col tiles
  const int base = rt * 128;
  const int tid = threadIdx.x;
  const int wv = tid >> 6;
  const int wr = wv >> 1, wc = wv & 1;
  const int jg0 = ct * 64;

  const int l = tid & 63, l16 = l & 15, lhi = l >> 4;

  unsigned int bits;
  {
    const int flag = flag_of(meta[1]);
    bool on = false;
    if (l < 16)
      on = mask_at(cmask, flag, (size_t)l * 64 * DIM + jg0);
    bits = (unsigned int)(__ballot(on) & 0xFFFFull);
  }

  const int arow = tid >> 1, sub = tid & 1;
  const int r0 = t2row[2 * (base + arow)], r1 = t2row[2 * (base + arow) + 1];
  const float w0 = t2w[2 * (base + arow)], w1 = t2w[2 * (base + arow) + 1];

  fx4 acc[4][2] = {};

  while (bits) {
    const int kbx = __ffs(bits) - 1; bits &= bits - 1;
    const int d0 = kbx * 64;
    {   // stage A: combine two bf16 pair rows -> bf16 (swizzled ds_write)
      const ux4* s0 = (const ux4*)(yb + (size_t)r0 * DIM + d0);
      const ux4* s1 = (const ux4*)(yb + (size_t)r1 * DIM + d0);
      #pragma unroll
      for (int s = 0; s < 4; s++) {
        const int seg = sub * 4 + s;
        ux4 v0 = s0[seg], v1 = s1[seg], o;
        #pragma unroll
        for (int j = 0; j < 4; j++) {
          float alo = __uint_as_float(v0[j] << 16);
          float ahi = __uint_as_float(v0[j] & 0xFFFF0000u);
          float blo = __uint_as_float(v1[j] << 16);
          float bhi = __uint_as_float(v1[j] & 0xFFFF0000u);
          o[j] = cvt_pk(w0 * alo + w1 * blo, w0 * ahi + w1 * bhi);
        }
        Ash[arow * 8 + (seg ^ (arow & 7))] = o;
      }
    }
    {   // stage B from cross_w (f32 reg-staged)
      const int kbt = tid >> 4, jb = tid & 15;
      const float* bp = cw + (size_t)(d0 + kbt * 4) * DIM + jg0 + jb * 4;
      fx4 r0v = *(const fx4*)bp;
      fx4 r1v = *(const fx4*)(bp + DIM);
      fx4 r2v = *(const fx4*)(bp + 2 * DIM);
      fx4 r3v = *(const fx4*)(bp + 3 * DIM);
      #pragma unroll
      for (int jj = 0; jj < 4; jj++) {
        ux2 val;
        val[0] = cvt_pk(r0v[jj], r1v[jj]);
        val[1] = cvt_pk(r2v[jj], r3v[jj]);
        const int col = jb * 4 + jj;
        Bsh[(col * 8 + ((kbt >> 1) ^ (col & 7))) * 2 + (kbt & 1)] = val;
      }
    }
    __syncthreads();
    #pragma unroll
    for (int ks = 0; ks < 2; ks++) {
      s8v a[4], b[2];
      const int seg = ks * 4 + lhi;
      #pragma unroll
      for (int m = 0; m < 4; m++) {
        const int row = wr * 64 + m * 16 + l16;
        V16 v; v.u = Ash[row * 8 + (seg ^ (row & 7))]; a[m] = v.s;
      }
      #pragma unroll
      for (int n = 0; n < 2; n++) {
        const int col = wc * 32 + n * 16 + l16;
        V16 v; v.u = ((const ux4*)Bsh)[col * 8 + (seg ^ (col & 7))]; b[n] = v.s;
      }
      #pragma unroll
      for (int m = 0; m < 4; m++)
        #pragma unroll
        for (int n = 0; n < 2; n++)
          acc[m][n] = __builtin_amdgcn_mfma_f32_16x16x32_bf16(a[m], b[n], acc[m][n], 0, 0, 0);
    }
    __syncthreads();
  }

  #pragma unroll
  for (int m = 0; m < 4; m++)
    #pragma unroll
    for (int n = 0; n < 2; n++) {
      const int gcol = jg0 + wc * 32 + n * 16 + l16;
      #pragma unroll
      for (int i = 0; i < 4; i++) {
        const int row = wr * 64 + m * 16 + lhi * 4 + i;
        const size_t idx = (size_t)(base + row) * DIM + gcol;
        out[idx] = acc[m][n][i] + x[idx] + cb[gcol];
      }
    }
}

// ---------------------------------------------------------------------------
extern "C" void kernel_launch(void* const* d_in, const int* in_sizes, int n_in,
                              void* d_out, int out_size, void* d_ws, size_t ws_size,
                              hipStream_t stream)
{
  (void)in_sizes; (void)n_in; (void)out_size; (void)ws_size;
  const float* x      = (const float*)d_in[0];
  const float* gate_w = (const float*)d_in[1];   // [2,16,1024]
  const float* temp   = (const float*)d_in[2];   // [2]
  const float* w1     = (const float*)d_in[3];   // [16,1024,4096]
  const float* b1     = (const float*)d_in[4];
  const float* w2     = (const float*)d_in[5];   // [16,4096,1024]
  const float* b2     = (const float*)d_in[6];
  const float* cw     = (const float*)d_in[7];   // [1024,1024]
  const float* cb     = (const float*)d_in[8];
  const void*  mask1  = d_in[9];
  const void*  mask2  = d_in[10];
  const void*  cmask  = d_in[11];
  float* out = (float*)d_out;
  char* ws = (char*)d_ws;

  size_t off = 0;
  auto walloc = [&](size_t b) { size_t r = off; off = (off + b + 255) & ~(size_t)255; return r; };
  size_t o_meta = walloc(4096);
  size_t o_t2i  = walloc((size_t)NTOK * 2 * 4);
  size_t o_t2w  = walloc((size_t)NTOK * 2 * 4);
  size_t o_t2r  = walloc((size_t)NTOK * 2 * 4);
  size_t o_tok  = walloc((size_t)ROWS_CAP * 4);
  size_t o_x8   = walloc((size_t)NTOK * DIM);            // 8 MB (fp8)
  size_t o_y    = walloc((size_t)ROWS_CAP * DIM * 2);    // 40 MB (bf16)
  size_t o_hc   = walloc((size_t)ROWS_CAP * HID);        // 84 MB (fp8)
  size_t o_w1p  = walloc((size_t)16384 * 4096);          // 64 MB
  size_t o_w2p  = walloc((size_t)16384 * 4096);          // 64 MB

  int*                meta = (int*)(ws + o_meta);
  int*                t2i  = (int*)(ws + o_t2i);
  float*              t2w  = (float*)(ws + o_t2w);
  int*                t2r  = (int*)(ws + o_t2r);
  int*                tok  = (int*)(ws + o_tok);
  unsigned char*      x8   = (unsigned char*)(ws + o_x8);
  unsigned short*     yb   = (unsigned short*)(ws + o_y);
  unsigned char*      h8   = (unsigned char*)(ws + o_hc);
  unsigned char*      w1p  = (unsigned char*)(ws + o_w1p);
  unsigned char*      w2p  = (unsigned char*)(ws + o_w2p);

  hipMemsetAsync(ws + o_meta, 0, 4096, stream);

  k_route  <<<NTOK / 32, 256, 0, stream>>>(x, gate_w + (size_t)1 * NEXP * DIM, temp + 1,
                                           (const unsigned int*)mask1, t2i, t2w, meta, x8);
  k_wcast  <<<32768, 256, 0, stream>>>(w1, w2, mask1, mask2, meta, w1p, w2p);
  k_assign <<<NTOK / 256, 256, 0, stream>>>(t2i, t2w, meta, tok, t2r);

  const int NRT = ROWS_CAP / BM;   // 80
  k_gemm1<<<NRT * 64, 256, 0, stream>>>(x8, w1p, b1, mask1, meta, tok, h8);
  k_gemm2<<<NRT * 16, 256, 0, stream>>>(h8, w2p, b2, mask2, meta, yb);
  k_cross<<<(NTOK / 128) * 16, 256, 0, stream>>>(yb, x, cw, cb, cmask, meta, t2r, t2w, out);
}

// Round 16
// 314.420 us; speedup vs baseline: 2.4672x; 1.0244x over previous
//
#include <hip/hip_runtime.h>

// ---------------------------------------------------------------------------
// HierarchicalSparseLayer: top-2 MoE with block-sparse (64x64) masked weights
// B=8192 tokens, D=1024, H=4096, E=16 experts, K=2, + block-sparse cross proj.
// R16: R15 + (1) wcast/assign/cross-image merged into one k_prep launch;
//      (2) cross full fp8 (packed cw images, fp8 A combine, fp8 MFMA, 12 KB LDS).
// ---------------------------------------------------------------------------

#define NTOK 8192
#define DIM  1024
#define HID  4096
#define NEXP 16
#define BM   256
#define ROWS_CAP (NTOK*2 + NEXP*256)   // 20480

typedef __attribute__((ext_vector_type(4))) float fx4;
typedef __attribute__((ext_vector_type(4))) unsigned int ux4;
typedef __attribute__((ext_vector_type(2))) unsigned int ux2;
typedef __attribute__((ext_vector_type(8))) short s8v;
union V16 { ux4 u; s8v s; };

__device__ __forceinline__ unsigned int f2bf(float f) {
  unsigned int u = __float_as_uint(f);
  return (u + 0x7fffu + ((u >> 16) & 1u)) >> 16;   // RNE, inputs finite
}

__device__ __forceinline__ unsigned int cvt_pk(float lo, float hi) {
  unsigned int r;
  asm("v_cvt_pk_bf16_f32 %0, %1, %2" : "=v"(r) : "v"(lo), "v"(hi));
  return r;
}

__device__ __forceinline__ unsigned int f2fp8(float v) {
  return (unsigned int)__builtin_amdgcn_cvt_pk_fp8_f32(v, v, 0, false) & 0xFFu;
}

// pack 4 f32 (scaled) into one u32 of 4 fp8 e4m3
__device__ __forceinline__ unsigned int pk4fp8(float a, float b, float c, float d) {
  unsigned int u = (unsigned int)__builtin_amdgcn_cvt_pk_fp8_f32(a, b, 0, false);
  u = (unsigned int)__builtin_amdgcn_cvt_pk_fp8_f32(c, d, (int)u, true);
  return u;
}

// Mask dtype detected at runtime: flag 0=u8, 1=i32, 2=f32
__device__ __forceinline__ bool mask_at(const void* m, int flag, size_t idx) {
  if (flag == 0) return ((const unsigned char*)m)[idx] != 0;
  if (flag == 1) return ((const int*)m)[idx] != 0;
  return ((const float*)m)[idx] != 0.0f;
}

__device__ __forceinline__ int flag_of(int ev) {
  return (ev & 2) ? 2 : ((ev & 1) ? 0 : 1);
}

// XCD-aware swizzle (grid % 8 == 0)
__device__ __forceinline__ int xcd_swz() {
  const int b = blockIdx.x, cpx = gridDim.x >> 3;
  return (b & 7) * cpx + (b >> 3);
}

// Region lookup from counts: returns expert e, region start, raw count, total.
__device__ __forceinline__ void region_of(const int* __restrict__ meta, int base,
                                          int& e, int& rstart, int& ecnt, int& total) {
  e = 15; rstart = 0; ecnt = 0; total = 0;
  #pragma unroll
  for (int i = 0; i < 16; i++) {
    const int craw = meta[8 + i];
    const int c = (craw + 255) & ~255;
    if (base >= total && base < total + c) { e = i; rstart = total; ecnt = craw; }
    total += c;
  }
}

// --------------------------- routing (+ detect + x->fp8 pack) ---------------
// meta: [1]=detect bits [8..23]=counts [64..79]=slot counters
__global__ void k_route(const float* __restrict__ x,
                        const float* __restrict__ gw,    // gate_w[-1] [16,1024]
                        const float* __restrict__ temp,
                        const unsigned int* __restrict__ m1raw,
                        int* __restrict__ top2i, float* __restrict__ top2w,
                        int* __restrict__ meta, unsigned char* __restrict__ x8)
{
  if (blockIdx.x < 64) {     // fold k_detect
    int bits = 0;
    size_t base = (size_t)blockIdx.x * 4096 + threadIdx.x;
    for (int j = 0; j < 16; j++) {
      unsigned int v = m1raw[base + 256 * j];
      if (v == 0x3f800000u) bits |= 2;
      else if (v > 1u)      bits |= 1;
    }
    if (bits) atomicOr(&meta[1], bits);
  }

  __shared__ float gwsh[NEXP * DIM];
  for (int i = threadIdx.x; i < NEXP * DIM; i += 256) gwsh[i] = gw[i];
  __syncthreads();

  const int wv = threadIdx.x >> 6;
  const int l = threadIdx.x & 63;
  #pragma unroll
  for (int tt = 0; tt < 8; tt++) {
    const int t = blockIdx.x * 32 + wv * 8 + tt;
    const float* xr = x + (size_t)t * DIM;
    float xv[16];
    #pragma unroll
    for (int j = 0; j < 16; j++) xv[j] = xr[l + 64 * j];
    float logit[16];
    #pragma unroll
    for (int e = 0; e < 16; e++) {
      const float* g = gwsh + e * DIM;
      float s = 0.f;
      #pragma unroll
      for (int j = 0; j < 16; j++) s += xv[j] * g[l + 64 * j];
      #pragma unroll
      for (int o = 32; o >= 1; o >>= 1) s += __shfl_xor(s, o);
      logit[e] = s;
    }
    if (l == 0) {
      const float tinv = 1.0f / temp[0];
      int i0 = 0; float v0 = logit[0] * tinv;
      #pragma unroll
      for (int e = 1; e < 16; e++) { float v = logit[e] * tinv; if (v > v0) { v0 = v; i0 = e; } }
      int i1 = -1; float v1 = 0.f; bool first = true;
      #pragma unroll
      for (int e = 0; e < 16; e++) {
        if (e == i0) continue;
        float v = logit[e] * tinv;
        if (first || v > v1) { v1 = v; i1 = e; first = false; }
      }
      float ex = __expf(v1 - v0);
      float den = 1.0f + ex;
      top2i[2 * t] = i0; top2i[2 * t + 1] = i1;
      top2w[2 * t] = 1.0f / den; top2w[2 * t + 1] = ex / den;
      atomicAdd(&meta[8 + i0], 1);
      atomicAdd(&meta[8 + i1], 1);
    }
  }

  // pack this block's 32 tokens to fp8 (x16 scale); slab is L1/L2-hot
  {
    const size_t be = (size_t)blockIdx.x * 32 * DIM;
    const fx4* src = (const fx4*)(x + be);
    ux4* dst = (ux4*)(x8 + be);          // 2048 ux4 per block
    #pragma unroll
    for (int i = 0; i < 8; i++) {
      const int idx = i * 256 + threadIdx.x;
      fx4 a = src[4 * idx], b = src[4 * idx + 1];
      fx4 c = src[4 * idx + 2], d = src[4 * idx + 3];
      ux4 o;
      o[0] = pk4fp8(a[0] * 16.f, a[1] * 16.f, a[2] * 16.f, a[3] * 16.f);
      o[1] = pk4fp8(b[0] * 16.f, b[1] * 16.f, b[2] * 16.f, b[3] * 16.f);
      o[2] = pk4fp8(c[0] * 16.f, c[1] * 16.f, c[2] * 16.f, c[3] * 16.f);
      o[3] = pk4fp8(d[0] * 16.f, d[1] * 16.f, d[2] * 16.f, d[3] * 16.f);
      dst[idx] = o;
    }
  }
}

// --------------------------- prep: weight fp8 images + assign ----------------
// gid [0,16384): w1 images; [16384,32768): w2; [32768,33024): cross; rest assign.
// Image layout == compute loop's swizzled LDS B: chunk c of col at
// col*64 + ((c ^ ((col>>1)&3)) << 4).
__global__ void k_prep(const float* __restrict__ w1, const float* __restrict__ w2,
                       const float* __restrict__ cw,
                       const void* __restrict__ mask1, const void* __restrict__ mask2,
                       const void* __restrict__ cmask,
                       const int* __restrict__ top2i, const float* __restrict__ top2w,
                       int* __restrict__ meta, int* __restrict__ tok_of_row,
                       int* __restrict__ t2row,
                       unsigned char* __restrict__ w1p, unsigned char* __restrict__ w2p,
                       unsigned char* __restrict__ cwp)
{
  const int gid = blockIdx.x;
  const int tid = threadIdx.x;

  if (gid >= 33024) {                // assign (32 blocks)
    __shared__ int offs[16];
    if (tid < 16) {
      int o = 0;
      for (int i = 0; i < tid; i++) o += (meta[8 + i] + 255) & ~255;
      offs[tid] = o;
    }
    __syncthreads();
    const int t = (gid - 33024) * 256 + tid;
    if (t < NTOK) {
      #pragma unroll
      for (int k = 0; k < 2; k++) {
        int e = top2i[2 * t + k];
        int slot = atomicAdd(&meta[64 + e], 1);
        int row = offs[e] + slot;
        tok_of_row[row] = t;
        t2row[2 * t + k] = row;
      }
    }
    return;
  }

  const int flag = flag_of(meta[1]);
  const int c = tid >> 6, col = tid & 63;

  if (gid < 16384) {                 // w1: panel p = gid>>4 (= e*64+ct), kb = gid&15
    const int p = gid >> 4, kb = gid & 15;
    const int e = p >> 6, ct = p & 63;
    if (!mask_at(mask1, flag, (size_t)e * DIM * HID + (size_t)kb * 64 * HID + ct * 64)) return;
    const float* src = w1 + ((size_t)e * DIM + kb * 64 + c * 16) * HID + ct * 64 + col;
    ux4 v;
    #pragma unroll
    for (int q = 0; q < 4; q++) {
      float f0 = src[(size_t)(q * 4 + 0) * HID], f1 = src[(size_t)(q * 4 + 1) * HID];
      float f2 = src[(size_t)(q * 4 + 2) * HID], f3 = src[(size_t)(q * 4 + 3) * HID];
      v[q] = pk4fp8(f0 * 16.f, f1 * 16.f, f2 * 16.f, f3 * 16.f);
    }
    *(ux4*)(w1p + ((size_t)gid << 12) + col * 64 + ((c ^ ((col >> 1) & 3)) << 4)) = v;
  } else if (gid < 32768) {          // w2
    const int g2 = gid - 16384;
    const int p = g2 >> 6, kb = g2 & 63;
    const int e = p >> 4, ct = p & 15;
    if (!mask_at(mask2, flag, (size_t)e * HID * DIM + (size_t)kb * 64 * DIM + ct * 64)) return;
    const float* src = w2 + ((size_t)e * HID + kb * 64 + c * 16) * DIM + ct * 64 + col;
    ux4 v;
    #pragma unroll
    for (int q = 0; q < 4; q++) {
      float f0 = src[(size_t)(q * 4 + 0) * DIM], f1 = src[(size_t)(q * 4 + 1) * DIM];
      float f2 = src[(size_t)(q * 4 + 2) * DIM], f3 = src[(size_t)(q * 4 + 3) * DIM];
      v[q] = pk4fp8(f0 * 16.f, f1 * 16.f, f2 * 16.f, f3 * 16.f);
    }
    *(ux4*)(w2p + ((size_t)g2 << 12) + col * 64 + ((c ^ ((col >> 1) & 3)) << 4)) = v;
  } else {                           // cross: g3 = gid-32768; ct = g3>>4, kb = g3&15
    const int g3 = gid - 32768;
    const int ct = g3 >> 4, kb = g3 & 15;
    if (!mask_at(cmask, flag, (size_t)kb * 64 * DIM + ct * 64)) return;
    const float* src = cw + (size_t)(kb * 64 + c * 16) * DIM + ct * 64 + col;
    ux4 v;
    #pragma unroll
    for (int q = 0; q < 4; q++) {
      float f0 = src[(size_t)(q * 4 + 0) * DIM], f1 = src[(size_t)(q * 4 + 1) * DIM];
      float f2 = src[(size_t)(q * 4 + 2) * DIM], f3 = src[(size_t)(q * 4 + 3) * DIM];
      v[q] = pk4fp8(f0 * 16.f, f1 * 16.f, f2 * 16.f, f3 * 16.f);
    }
    *(ux4*)(cwp + ((size_t)g3 << 12) + col * 64 + ((c ^ ((col >> 1) & 3)) << 4)) = v;
  }
}

// --------------------------- GEMM 1: h8 = fp8(8*silu(x8 @ w1p/256 + b1)) ----
__global__ __launch_bounds__(256, 4)
void k_gemm1(const unsigned char* __restrict__ x8,
             const unsigned char* __restrict__ w1p, const float* __restrict__ b1,
             const void* __restrict__ mask1,
             const int* __restrict__ meta, const int* __restrict__ tok_of_row,
             unsigned char* __restrict__ h8)
{
  __shared__ ux4 Ash[2][1024];                        // 2 x 16 KB (256 rows x 64 B)
  __shared__ __align__(16) unsigned int Bsh[2][1024]; // 2 x 4 KB

  const int bid = xcd_swz();
  const int rt = bid >> 6, ct = bid & 63;       // NCT = 64
  const int base = rt * BM;
  int e, rstart, ecnt, total;
  region_of(meta, base, e, rstart, ecnt, total);
  if (base >= total) return;

  const int tid = threadIdx.x;
  const int wv = tid >> 6;
  const int jg0 = ct * 64;
  const int l = tid & 63, l16 = l & 15, lhi = l >> 4;

  unsigned int bits;
  {
    const int flag = flag_of(meta[1]);
    bool on = false;
    if (l < 16)
      on = mask_at(mask1, flag, (size_t)e * DIM * HID + (size_t)l * 64 * HID + jg0);
    bits = (unsigned int)(__ballot(on) & 0xFFFFull);
  }

  const unsigned int sw = (unsigned int)((tid & 3) ^ ((tid >> 3) & 3));
  const int vlimit = rstart + ecnt;
  unsigned int aoff[4];
  #pragma unroll
  for (int i = 0; i < 4; i++) {
    const int r = base + i * 64 + (tid >> 2);
    int tok = tok_of_row[r];
    if (r >= vlimit) tok = 0;                   // pad rows: finite garbage, unused
    aoff[i] = (unsigned int)tok * (unsigned int)DIM + sw * 16;
  }

  fx4 acc[4][4] = {};

  auto STAGE_A = [&](int b, int d0) {
    const char* gp = (const char*)x8 + d0;
    #pragma unroll
    for (int i = 0; i < 4; i++)
      __builtin_amdgcn_global_load_lds(
        (const __attribute__((address_space(1))) unsigned int*)(gp + aoff[i]),
        (__attribute__((address_space(3))) unsigned int*)&Ash[b][i * 256 + wv * 64],
        16, 0, 0);
  };
  auto STAGE_B = [&](int b, int kb) {
    const char* src = (const char*)w1p + (((size_t)(e * 64 + ct) * 16 + kb) << 12) + tid * 16;
    __builtin_amdgcn_global_load_lds(
      (const __attribute__((address_space(1))) unsigned int*)src,
      (__attribute__((address_space(3))) unsigned int*)&Bsh[b][wv * 256],
      16, 0, 0);
  };
  auto COMPUTE = [&](int b) {
    const char* Ab = (const char*)&Ash[b][0];
    const char* Bb = (const char*)&Bsh[b][0];
    #pragma unroll
    for (int ks = 0; ks < 2; ks++) {
      const int c = ks * 2 + (lhi >> 1);
      const int sub = (lhi & 1) << 3;
      long long a[4], bb[4];
      #pragma unroll
      for (int m = 0; m < 4; m++) {
        const int row = wv * 64 + m * 16 + l16;
        a[m] = *(const long long*)(Ab + row * 64 + ((c ^ ((row >> 1) & 3)) << 4) + sub);
      }
      #pragma unroll
      for (int n = 0; n < 4; n++) {
        const int col = n * 16 + l16;
        bb[n] = *(const long long*)(Bb + col * 64 + ((c ^ ((col >> 1) & 3)) << 4) + sub);
      }
      #pragma unroll
      for (int m = 0; m < 4; m++)
        #pragma unroll
        for (int n = 0; n < 4; n++)
          acc[m][n] = __builtin_amdgcn_mfma_f32_16x16x32_fp8_fp8(a[m], bb[n], acc[m][n], 0, 0, 0);
    }
  };

  if (bits) {
    int kb0 = __ffs(bits) - 1; bits &= bits - 1;
    STAGE_A(0, kb0 << 6); STAGE_B(0, kb0);
    __syncthreads();
    int cur = 0;
    for (;;) {
      int nkb = -1;
      if (bits) { nkb = __ffs(bits) - 1; bits &= bits - 1; }
      if (nkb >= 0) { STAGE_A(cur ^ 1, nkb << 6); STAGE_B(cur ^ 1, nkb); }
      COMPUTE(cur);
      __syncthreads();
      cur ^= 1;
      if (nkb < 0) break;
    }
  }

  // epilogue: h = fp8(8 * silu(acc/256 + b1)) -> LDS byte tile -> 16B dump
  unsigned char* hs = (unsigned char*)&Ash[0][0];   // 16 KB tile
  __syncthreads();
  #pragma unroll
  for (int m = 0; m < 4; m++)
    #pragma unroll
    for (int n = 0; n < 4; n++) {
      const int gcol = jg0 + n * 16 + l16;
      const float bbv = b1[e * HID + gcol];
      #pragma unroll
      for (int i = 0; i < 4; i++) {
        const int row = wv * 64 + m * 16 + lhi * 4 + i;
        float v = acc[m][n][i] * 0.00390625f + bbv;
        float hval = v / (1.0f + __expf(-v));
        hs[row * 64 + n * 16 + l16] = (unsigned char)f2fp8(hval * 8.0f);
      }
    }
  __syncthreads();
  {
    const ux4* s = (const ux4*)hs;
    #pragma unroll
    for (int j = 0; j < 4; j++) {
      const int c2 = j * 256 + tid;
      const int row = c2 >> 2;
      *(ux4*)(h8 + (size_t)(base + row) * HID + ct * 64 + (c2 & 3) * 16) = s[c2];
    }
  }
}

// --------------------------- GEMM 2: y = bf16(h8 @ w2p / 128 + b2) ----------
__global__ __launch_bounds__(256, 4)
void k_gemm2(const unsigned char* __restrict__ h8,
             const unsigned char* __restrict__ w2p, const float* __restrict__ b2,
             const void* __restrict__ mask2,
             const int* __restrict__ meta, unsigned short* __restrict__ yb)
{
  __shared__ ux4 Ash[2][1024];                       // 2 x 16 KB (256 rows x 64 B)
  __shared__ __align__(16) unsigned int Bsh[2][1024]; // 2 x 4 KB (64 cols x 64 B)

  const int bid = xcd_swz();
  const int rt = bid >> 4, ct = bid & 15;       // NCT = 16
  const int base = rt * BM;
  int e, rstart, ecnt, total;
  region_of(meta, base, e, rstart, ecnt, total);
  if (base >= total) return;

  const int tid = threadIdx.x;
  const int wv = tid >> 6;
  const int jg0 = ct * 64;

  const int l = tid & 63, l16 = l & 15, lhi = l >> 4;
  unsigned long long bits;
  {
    const int flag = flag_of(meta[1]);
    bits = __ballot(mask_at(mask2, flag,
             (size_t)e * HID * DIM + (size_t)l * 64 * DIM + jg0));
  }

  const unsigned int sw = (unsigned int)((tid & 3) ^ ((tid >> 3) & 3));
  unsigned int aoff[4];
  #pragma unroll
  for (int i = 0; i < 4; i++)
    aoff[i] = (unsigned int)(base + i * 64 + (tid >> 2)) * (unsigned int)HID + sw * 16;

  fx4 acc[4][4] = {};

  auto STAGE_A = [&](int b, int d0) {
    const char* gp = (const char*)h8 + d0;
    #pragma unroll
    for (int i = 0; i < 4; i++)
      __builtin_amdgcn_global_load_lds(
        (const __attribute__((address_space(1))) unsigned int*)(gp + aoff[i]),
        (__attribute__((address_space(3))) unsigned int*)&Ash[b][i * 256 + wv * 64],
        16, 0, 0);
  };
  auto STAGE_B = [&](int b, int kb) {
    const char* src = (const char*)w2p + (((size_t)(e * 16 + ct) * 64 + kb) << 12) + tid * 16;
    __builtin_amdgcn_global_load_lds(
      (const __attribute__((address_space(1))) unsigned int*)src,
      (__attribute__((address_space(3))) unsigned int*)&Bsh[b][wv * 256],
      16, 0, 0);
  };
  auto COMPUTE = [&](int b) {
    const char* Ab = (const char*)&Ash[b][0];
    const char* Bb = (const char*)&Bsh[b][0];
    #pragma unroll
    for (int ks = 0; ks < 2; ks++) {
      const int c = ks * 2 + (lhi >> 1);
      const int sub = (lhi & 1) << 3;
      long long a[4], bb[4];
      #pragma unroll
      for (int m = 0; m < 4; m++) {
        const int row = wv * 64 + m * 16 + l16;
        a[m] = *(const long long*)(Ab + row * 64 + ((c ^ ((row >> 1) & 3)) << 4) + sub);
      }
      #pragma unroll
      for (int n = 0; n < 4; n++) {
        const int col = n * 16 + l16;
        bb[n] = *(const long long*)(Bb + col * 64 + ((c ^ ((col >> 1) & 3)) << 4) + sub);
      }
      #pragma unroll
      for (int m = 0; m < 4; m++)
        #pragma unroll
        for (int n = 0; n < 4; n++)
          acc[m][n] = __builtin_amdgcn_mfma_f32_16x16x32_fp8_fp8(a[m], bb[n], acc[m][n], 0, 0, 0);
    }
  };

  if (bits) {
    int kb0 = __ffsll(bits) - 1; bits &= bits - 1;
    STAGE_A(0, kb0 << 6); STAGE_B(0, kb0);
    __syncthreads();
    int cur = 0;
    for (;;) {
      int nkb = -1;
      if (bits) { nkb = __ffsll(bits) - 1; bits &= bits - 1; }
      if (nkb >= 0) { STAGE_A(cur ^ 1, nkb << 6); STAGE_B(cur ^ 1, nkb); }
      COMPUTE(cur);
      __syncthreads();
      cur ^= 1;
      if (nkb < 0) break;
    }
  }

  // epilogue: y = bf16(acc/128 + b2), restaged via LDS (Ash = 32 KB)
  unsigned short* hs = (unsigned short*)&Ash[0][0];
  __syncthreads();
  #pragma unroll
  for (int m = 0; m < 4; m++)
    #pragma unroll
    for (int n = 0; n < 4; n++) {
      const int gcol = jg0 + n * 16 + l16;
      const float bbv = b2[e * DIM + gcol];
      #pragma unroll
      for (int i = 0; i < 4; i++) {
        const int row = wv * 64 + m * 16 + lhi * 4 + i;
        hs[row * 64 + n * 16 + l16] =
            (unsigned short)f2bf(acc[m][n][i] * 0.0078125f + bbv);
      }
    }
  __syncthreads();
  {
    const ux4* s = (const ux4*)hs;
    #pragma unroll
    for (int j = 0; j < 8; j++) {
      const int c2 = j * 256 + tid;
      const int row = c2 >> 3;
      *(ux4*)(yb + (size_t)(base + row) * DIM + ct * 64 + (c2 & 7) * 8) = s[c2];
    }
  }
}

// --------------------------- cross: out = x + eo @ cwm + cb (full fp8) ------
// BM=128, 4 waves (2x2), acc[4][2]; A = fp8(16*(w0*y0+w1*y1)) chunk-swizzled;
// B = packed cwp image via 1 DMA; fp8 MFMA; acc/256 in epilogue. 12 KB LDS.
__global__ __launch_bounds__(256, 4)
void k_cross(const unsigned short* __restrict__ yb, const float* __restrict__ x,
             const unsigned char* __restrict__ cwp, const float* __restrict__ cb,
             const void* __restrict__ cmask, const int* __restrict__ meta,
             const int* __restrict__ t2row, const float* __restrict__ t2w,
             float* __restrict__ out)
{
  __shared__ ux4 Ash[512];                        // 128 rows x 64 B fp8 = 8 KB
  __shared__ __align__(16) unsigned int Bsh[1024]; // 4 KB

  const int bid = xcd_swz();
  const int rt = bid >> 4, ct = bid & 15;    // 64 row tiles x 16 col tiles
  const int base = rt * 128;
  const int tid = threadIdx.x;
  const int wv = tid >> 6;
  const int wr = wv >> 1, wc = wv & 1;
  const int jg0 = ct * 64;

  const int l = tid & 63, l16 = l & 15, lhi = l >> 4;

  unsigned int bits;
  {
    const int flag = flag_of(meta[1]);
    bool on = false;
    if (l < 16)
      on = mask_at(cmask, flag, (size_t)l * 64 * DIM + jg0);
    bits = (unsigned int)(__ballot(on) & 0xFFFFull);
  }

  const int arow = tid >> 1, sub = tid & 1;
  const int r0 = t2row[2 * (base + arow)], r1 = t2row[2 * (base + arow) + 1];
  const float w0 = t2w[2 * (base + arow)], w1 = t2w[2 * (base + arow) + 1];

  fx4 acc[4][2] = {};

  // combine two u32 word-pairs (2 bf16 each) -> u32 of 4 fp8 (x16 scale)
  auto pack4 = [&](unsigned int a0, unsigned int b0, unsigned int a1, unsigned int b1) {
    float v0 = w0 * __uint_as_float(a0 << 16)        + w1 * __uint_as_float(b0 << 16);
    float v1 = w0 * __uint_as_float(a0 & 0xFFFF0000u) + w1 * __uint_as_float(b0 & 0xFFFF0000u);
    float v2 = w0 * __uint_as_float(a1 << 16)        + w1 * __uint_as_float(b1 << 16);
    float v3 = w0 * __uint_as_float(a1 & 0xFFFF0000u) + w1 * __uint_as_float(b1 & 0xFFFF0000u);
    return pk4fp8(v0 * 16.f, v1 * 16.f, v2 * 16.f, v3 * 16.f);
  };

  while (bits) {
    const int kbx = __ffs(bits) - 1; bits &= bits - 1;
    const int d0 = kbx * 64;
    {   // stage A: combine -> fp8, 2 chunk-swizzled 16B ds_writes per thread
      const ux4* s0 = (const ux4*)(yb + (size_t)r0 * DIM + d0);
      const ux4* s1 = (const ux4*)(yb + (size_t)r1 * DIM + d0);
      #pragma unroll
      for (int cc = 0; cc < 2; cc++) {
        const int chunk = sub * 2 + cc;         // values chunk*16 .. +15
        ux4 va0 = s0[2 * chunk], va1 = s0[2 * chunk + 1];
        ux4 vb0 = s1[2 * chunk], vb1 = s1[2 * chunk + 1];
        ux4 o;
        o[0] = pack4(va0[0], vb0[0], va0[1], vb0[1]);
        o[1] = pack4(va0[2], vb0[2], va0[3], vb0[3]);
        o[2] = pack4(va1[0], vb1[0], va1[1], vb1[1]);
        o[3] = pack4(va1[2], vb1[2], va1[3], vb1[3]);
        *(ux4*)((char*)&Ash[0] + arow * 64 + ((chunk ^ ((arow >> 1) & 3)) << 4)) = o;
      }
    }
    {   // stage B: packed cwp image, one DMA issue
      const char* src = (const char*)cwp + (((size_t)(ct * 16 + kbx)) << 12) + tid * 16;
      __builtin_amdgcn_global_load_lds(
        (const __attribute__((address_space(1))) unsigned int*)src,
        (__attribute__((address_space(3))) unsigned int*)&Bsh[wv * 256],
        16, 0, 0);
    }
    __syncthreads();
    {
      const char* Ab = (const char*)&Ash[0];
      const char* Bb = (const char*)&Bsh[0];
      #pragma unroll
      for (int ks = 0; ks < 2; ks++) {
        const int c = ks * 2 + (lhi >> 1);
        const int sub2 = (lhi & 1) << 3;
        long long a[4], b[2];
        #pragma unroll
        for (int m = 0; m < 4; m++) {
          const int row = wr * 64 + m * 16 + l16;
          a[m] = *(const long long*)(Ab + row * 64 + ((c ^ ((row >> 1) & 3)) << 4) + sub2);
        }
        #pragma unroll
        for (int n = 0; n < 2; n++) {
          const int col = wc * 32 + n * 16 + l16;
          b[n] = *(const long long*)(Bb + col * 64 + ((c ^ ((col >> 1) & 3)) << 4) + sub2);
        }
        #pragma unroll
        for (int m = 0; m < 4; m++)
          #pragma unroll
          for (int n = 0; n < 2; n++)
            acc[m][n] = __builtin_amdgcn_mfma_f32_16x16x32_fp8_fp8(a[m], b[n], acc[m][n], 0, 0, 0);
      }
    }
    __syncthreads();
  }

  #pragma unroll
  for (int m = 0; m < 4; m++)
    #pragma unroll
    for (int n = 0; n < 2; n++) {
      const int gcol = jg0 + wc * 32 + n * 16 + l16;
      #pragma unroll
      for (int i = 0; i < 4; i++) {
        const int row = wr * 64 + m * 16 + lhi * 4 + i;
        const size_t idx = (size_t)(base + row) * DIM + gcol;
        out[idx] = acc[m][n][i] * 0.00390625f + x[idx] + cb[gcol];
      }
    }
}

// ---------------------------------------------------------------------------
extern "C" void kernel_launch(void* const* d_in, const int* in_sizes, int n_in,
                              void* d_out, int out_size, void* d_ws, size_t ws_size,
                              hipStream_t stream)
{
  (void)in_sizes; (void)n_in; (void)out_size; (void)ws_size;
  const float* x      = (const float*)d_in[0];
  const float* gate_w = (const float*)d_in[1];   // [2,16,1024]
  const float* temp   = (const float*)d_in[2];   // [2]
  const float* w1     = (const float*)d_in[3];   // [16,1024,4096]
  const float* b1     = (const float*)d_in[4];
  const float* w2     = (const float*)d_in[5];   // [16,4096,1024]
  const float* b2     = (const float*)d_in[6];
  const float* cw     = (const float*)d_in[7];   // [1024,1024]
  const float* cb     = (const float*)d_in[8];
  const void*  mask1  = d_in[9];
  const void*  mask2  = d_in[10];
  const void*  cmask  = d_in[11];
  float* out = (float*)d_out;
  char* ws = (char*)d_ws;

  size_t off = 0;
  auto walloc = [&](size_t b) { size_t r = off; off = (off + b + 255) & ~(size_t)255; return r; };
  size_t o_meta = walloc(4096);
  size_t o_t2i  = walloc((size_t)NTOK * 2 * 4);
  size_t o_t2w  = walloc((size_t)NTOK * 2 * 4);
  size_t o_t2r  = walloc((size_t)NTOK * 2 * 4);
  size_t o_tok  = walloc((size_t)ROWS_CAP * 4);
  size_t o_x8   = walloc((size_t)NTOK * DIM);            // 8 MB (fp8)
  size_t o_y    = walloc((size_t)ROWS_CAP * DIM * 2);    // 40 MB (bf16)
  size_t o_hc   = walloc((size_t)ROWS_CAP * HID);        // 84 MB (fp8)
  size_t o_w1p  = walloc((size_t)16384 * 4096);          // 64 MB
  size_t o_w2p  = walloc((size_t)16384 * 4096);          // 64 MB
  size_t o_cwp  = walloc((size_t)256 * 4096);            // 1 MB

  int*                meta = (int*)(ws + o_meta);
  int*                t2i  = (int*)(ws + o_t2i);
  float*              t2w  = (float*)(ws + o_t2w);
  int*                t2r  = (int*)(ws + o_t2r);
  int*                tok  = (int*)(ws + o_tok);
  unsigned char*      x8   = (unsigned char*)(ws + o_x8);
  unsigned short*     yb   = (unsigned short*)(ws + o_y);
  unsigned char*      h8   = (unsigned char*)(ws + o_hc);
  unsigned char*      w1p  = (unsigned char*)(ws + o_w1p);
  unsigned char*      w2p  = (unsigned char*)(ws + o_w2p);
  unsigned char*      cwp  = (unsigned char*)(ws + o_cwp);

  hipMemsetAsync(ws + o_meta, 0, 4096, stream);

  k_route <<<NTOK / 32, 256, 0, stream>>>(x, gate_w + (size_t)1 * NEXP * DIM, temp + 1,
                                          (const unsigned int*)mask1, t2i, t2w, meta, x8);
  k_prep  <<<33056, 256, 0, stream>>>(w1, w2, cw, mask1, mask2, cmask,
                                      t2i, t2w, meta, tok, t2r, w1p, w2p, cwp);

  const int NRT = ROWS_CAP / BM;   // 80
  k_gemm1<<<NRT * 64, 256, 0, stream>>>(x8, w1p, b1, mask1, meta, tok, h8);
  k_gemm2<<<NRT * 16, 256, 0, stream>>>(h8, w2p, b2, mask2, meta, yb);
  k_cross<<<(NTOK / 128) * 16, 256, 0, stream>>>(yb, x, cwp, cb, cmask, meta, t2r, t2w, out);
}